// Round 6
// baseline (1852.338 us; speedup 1.0000x reference)
//
#include <hip/hip_runtime.h>
#include <hip/hip_bf16.h>

typedef unsigned short u16;
typedef unsigned int u32;
typedef __bf16 bf16x8 __attribute__((ext_vector_type(8)));
typedef float f32x4 __attribute__((ext_vector_type(4)));

__device__ __forceinline__ float bf2f(u16 v) {
    u32 x = (u32)v << 16;
    return __builtin_bit_cast(float, x);
}
__device__ __forceinline__ u16 f2bf(float f) {
    return __builtin_bit_cast(u16, (__bf16)f);
}

// ---------------- block reduction (256 threads = 4 waves) ----------------
__device__ __forceinline__ float block_sum_256(float v, float* red) {
    #pragma unroll
    for (int o = 32; o > 0; o >>= 1) v += __shfl_xor(v, o);
    int w = threadIdx.x >> 6;
    if ((threadIdx.x & 63) == 0) red[w] = v;
    __syncthreads();
    return red[0] + red[1] + red[2] + red[3];
}

// ---------------- f32 -> bf16 conversions ----------------
__global__ void k_cvt(const float* __restrict__ s, u16* __restrict__ d, int n) {
    int i = blockIdx.x * 256 + threadIdx.x;
    if (i < n) d[i] = f2bf(s[i]);
}

__global__ void k_cvt_pad_inw(const float* __restrict__ s, u16* __restrict__ d) {
    int i = blockIdx.x * 256 + threadIdx.x;  // < 2304*512
    int n = i >> 9;
    d[i] = (n < 2192) ? f2bf(s[i]) : (u16)0;
}

// ---------------- si = rms(x)*w + pos_emb -> bf16 ----------------
__global__ __launch_bounds__(256) void k_rms_pos(const float* __restrict__ x,
                                                 const float* __restrict__ pe,
                                                 const float* __restrict__ wrms,
                                                 u16* __restrict__ sib) {
    __shared__ float red[4];
    int row = blockIdx.x, t = threadIdx.x;
    size_t base = (size_t)row * 512 + t * 2;
    float2 xv = *(const float2*)(x + base);
    float ss = block_sum_256(xv.x * xv.x + xv.y * xv.y, red);
    float sc = rsqrtf(ss * (1.f / 512.f) + 1.1920929e-07f);
    float2 pv = *(const float2*)(pe + base);
    float2 wv = *(const float2*)(wrms + t * 2);
    sib[base] = f2bf(xv.x * sc * wv.x + pv.x);
    sib[base + 1] = f2bf(xv.y * sc * wv.y + pv.y);
}

// ---------------- in_proj GEMM with split epilogue ----------------
// A: sib (4096x512 bf16), W: inw[z] (2304x512 bf16, padded). Output:
// cols [0,1024) -> Z[z] stride 1024; cols [1024,2192) -> XB[z] stride 1184.
// bwd (z=1) reads A row-flipped within each batch of 2048.
__global__ __launch_bounds__(256) void k_gemm_in(
    const u16* __restrict__ A, const u16* __restrict__ W0, const u16* __restrict__ W1,
    u16* __restrict__ Z0, u16* __restrict__ Z1,
    u16* __restrict__ XB0, u16* __restrict__ XB1) {
    const int z = blockIdx.z;
    const u16* W = z ? W1 : W0;
    u16* Z = z ? Z1 : Z0;
    u16* XB = z ? XB1 : XB0;
    const int K = 512;

    __shared__ __align__(16) u16 As[128 * 32];
    __shared__ __align__(16) u16 Bs[128 * 32];

    const int t = threadIdx.x;
    const int lane = t & 63;
    const int w = t >> 6;
    const int m0 = blockIdx.y * 128;
    const int n0 = blockIdx.x * 128;
    const int wm = (w >> 1) * 64;
    const int wn = (w & 1) * 64;
    const int fr = lane & 15;
    const int fk = (lane >> 4) * 8;

    f32x4 acc[4][4];
    #pragma unroll
    for (int i = 0; i < 4; ++i)
        #pragma unroll
        for (int j = 0; j < 4; ++j) acc[i][j] = (f32x4){0.f, 0.f, 0.f, 0.f};

    for (int kt = 0; kt < K; kt += 32) {
        #pragma unroll
        for (int j = 0; j < 2; ++j) {
            int off16 = j * 256 + t;
            int row = off16 >> 2;
            int kc = (off16 & 3) * 8;
            int gm = m0 + row;
            if (z) gm = (gm & ~2047) | (2047 - (gm & 2047));
            *(uint4*)(As + row * 32 + kc) = *(const uint4*)(A + (size_t)gm * K + kt + kc);
            int gn = n0 + row;
            *(uint4*)(Bs + row * 32 + kc) = *(const uint4*)(W + (size_t)gn * K + kt + kc);
        }
        __syncthreads();
        bf16x8 af[4], bfr[4];
        #pragma unroll
        for (int i = 0; i < 4; ++i) af[i] = *(const bf16x8*)(As + (wm + i * 16 + fr) * 32 + fk);
        #pragma unroll
        for (int i = 0; i < 4; ++i) bfr[i] = *(const bf16x8*)(Bs + (wn + i * 16 + fr) * 32 + fk);
        #pragma unroll
        for (int i = 0; i < 4; ++i)
            #pragma unroll
            for (int j = 0; j < 4; ++j)
                acc[i][j] = __builtin_amdgcn_mfma_f32_16x16x32_bf16(af[i], bfr[j], acc[i][j], 0, 0, 0);
        __syncthreads();
    }
    #pragma unroll
    for (int i = 0; i < 4; ++i) {
        int rbase = m0 + wm + i * 16 + (lane >> 4) * 4;
        #pragma unroll
        for (int j = 0; j < 4; ++j) {
            int c = n0 + wn + j * 16 + fr;
            #pragma unroll
            for (int r = 0; r < 4; ++r) {
                u16 v = f2bf(acc[i][j][r]);
                int m = rbase + r;
                if (c < 1024) Z[(size_t)m * 1024 + c] = v;
                else if (c < 2192) XB[(size_t)m * 1184 + (c - 1024)] = v;
            }
        }
    }
}

// ---------------- generic bf16 GEMM: C[m][n] = sum_k A[m][k]*W[n][k], bf16 out ----------------
__global__ __launch_bounds__(256) void k_gemm2(
    const u16* __restrict__ A0, const u16* __restrict__ A1,
    const u16* __restrict__ W0, const u16* __restrict__ W1,
    u16* __restrict__ C0, u16* __restrict__ C1, int N, int K) {
    const int z = blockIdx.z;
    const u16* A = z ? A1 : A0;
    const u16* W = z ? W1 : W0;
    u16* C = z ? C1 : C0;

    __shared__ __align__(16) u16 As[128 * 32];
    __shared__ __align__(16) u16 Bs[128 * 32];

    const int t = threadIdx.x;
    const int lane = t & 63;
    const int w = t >> 6;
    const int m0 = blockIdx.y * 128;
    const int n0 = blockIdx.x * 128;
    const int wm = (w >> 1) * 64;
    const int wn = (w & 1) * 64;
    const int fr = lane & 15;
    const int fk = (lane >> 4) * 8;

    f32x4 acc[4][4];
    #pragma unroll
    for (int i = 0; i < 4; ++i)
        #pragma unroll
        for (int j = 0; j < 4; ++j) acc[i][j] = (f32x4){0.f, 0.f, 0.f, 0.f};

    for (int kt = 0; kt < K; kt += 32) {
        #pragma unroll
        for (int j = 0; j < 2; ++j) {
            int off16 = j * 256 + t;
            int row = off16 >> 2;
            int kc = (off16 & 3) * 8;
            *(uint4*)(As + row * 32 + kc) = *(const uint4*)(A + (size_t)(m0 + row) * K + kt + kc);
            *(uint4*)(Bs + row * 32 + kc) = *(const uint4*)(W + (size_t)(n0 + row) * K + kt + kc);
        }
        __syncthreads();
        bf16x8 af[4], bfr[4];
        #pragma unroll
        for (int i = 0; i < 4; ++i) af[i] = *(const bf16x8*)(As + (wm + i * 16 + fr) * 32 + fk);
        #pragma unroll
        for (int i = 0; i < 4; ++i) bfr[i] = *(const bf16x8*)(Bs + (wn + i * 16 + fr) * 32 + fk);
        #pragma unroll
        for (int i = 0; i < 4; ++i)
            #pragma unroll
            for (int j = 0; j < 4; ++j)
                acc[i][j] = __builtin_amdgcn_mfma_f32_16x16x32_bf16(af[i], bfr[j], acc[i][j], 0, 0, 0);
        __syncthreads();
    }
    #pragma unroll
    for (int i = 0; i < 4; ++i) {
        int rbase = m0 + wm + i * 16 + (lane >> 4) * 4;
        #pragma unroll
        for (int j = 0; j < 4; ++j) {
            int col = n0 + wn + j * 16 + fr;
            #pragma unroll
            for (int r = 0; r < 4; ++r)
                C[(size_t)(rbase + r) * N + col] = f2bf(acc[i][j][r]);
        }
    }
}

// ---------------- causal conv4 + silu over xBC; softplus dt; dA ----------------
__global__ __launch_bounds__(256) void k_conv(
    const u16* __restrict__ xb0, const u16* __restrict__ xb1,
    const float* __restrict__ cw0, const float* __restrict__ cb0,
    const float* __restrict__ dtb0, const float* __restrict__ al0,
    const float* __restrict__ cw1, const float* __restrict__ cb1,
    const float* __restrict__ dtb1, const float* __restrict__ al1,
    u16* __restrict__ xc0, u16* __restrict__ xc1,
    float* __restrict__ dtO0, float* __restrict__ dAO0,
    float* __restrict__ dtO1, float* __restrict__ dAO1) {
    int col = blockIdx.x * 256 + threadIdx.x;
    int r = blockIdx.y;
    int dir = r >> 12, row = r & 4095;
    const u16* xb = dir ? xb1 : xb0;
    const float* cw = dir ? cw1 : cw0;
    const float* cb = dir ? cb1 : cb0;
    const float* dtb = dir ? dtb1 : dtb0;
    const float* al = dir ? al1 : al0;
    u16* xc = dir ? xc1 : xc0;
    float* dtO = dir ? dtO1 : dtO0;
    float* dAO = dir ? dAO1 : dAO0;
    int bb = row >> 11, tl = row & 2047;
    if (col < 1152) {
        float acc = cb[col];
        #pragma unroll
        for (int i = 0; i < 4; ++i) {
            int tt = tl + i - 3;
            if (tt >= 0)
                acc += bf2f(xb[(size_t)((bb << 11) + tt) * 1184 + col]) * cw[col * 4 + i];
        }
        acc = acc / (1.f + expf(-acc));  // silu
        xc[(size_t)row * 1152 + col] = f2bf(acc);
    } else if (col < 1168) {
        int hh = col - 1152;
        float v = bf2f(xb[(size_t)row * 1184 + 1152 + hh]) + dtb[hh];
        float sp = (v > 20.f) ? v : log1pf(expf(v));  // softplus
        dtO[row * 16 + hh] = sp;
        dAO[row * 16 + hh] = expf(-expf(al[hh]) * sp);
    }
}

// ---------------- sequential SSM scan: one block per (dir,b,h) ----------------
__global__ __launch_bounds__(256) void k_scan(
    const u16* __restrict__ xc0, const float* __restrict__ dt0,
    const float* __restrict__ dA0, const float* __restrict__ Dv0, u16* __restrict__ y0,
    const u16* __restrict__ xc1, const float* __restrict__ dt1,
    const float* __restrict__ dA1, const float* __restrict__ Dv1, u16* __restrict__ y1) {
    int blk = blockIdx.x;  // 0..63
    int dir = blk >> 5;
    int b = (blk >> 4) & 1;
    int h = blk & 15;
    const u16* xc = dir ? xc1 : xc0;
    const float* dtp = dir ? dt1 : dt0;
    const float* dAp = dir ? dA1 : dA0;
    u16* y = dir ? y1 : y0;
    const float Dh = (dir ? Dv1 : Dv0)[h];

    const int t = threadIdx.x;
    const int p = t >> 2, q = t & 3;

    __shared__ float sbuf[194];  // [0,64) x, [64,128) B, [128,192) C, 192 dt, 193 dA
    float hs[16];
    #pragma unroll
    for (int j = 0; j < 16; ++j) hs[j] = 0.f;

    float ld = 0.f;
    {
        size_t row = (size_t)b * 2048;
        if (t < 64) ld = bf2f(xc[row * 1152 + h * 64 + t]);
        else if (t < 192) ld = bf2f(xc[row * 1152 + 960 + t]);
        else if (t == 192) ld = dtp[row * 16 + h];
        else if (t == 193) ld = dAp[row * 16 + h];
    }

    for (int s = 0; s < 2048; ++s) {
        if (t < 194) sbuf[t] = ld;
        __syncthreads();
        if (s + 1 < 2048) {
            size_t row = (size_t)b * 2048 + s + 1;
            if (t < 64) ld = bf2f(xc[row * 1152 + h * 64 + t]);
            else if (t < 192) ld = bf2f(xc[row * 1152 + 960 + t]);
            else if (t == 192) ld = dtp[row * 16 + h];
            else if (t == 193) ld = dAp[row * 16 + h];
        }
        float dtv = sbuf[192], dAv = sbuf[193];
        float xv = sbuf[p];
        float coef = dtv * xv;
        float yp = 0.f;
        #pragma unroll
        for (int j = 0; j < 16; ++j) {
            int n = q * 16 + j;
            hs[j] = hs[j] * dAv + coef * sbuf[64 + n];
            yp += hs[j] * sbuf[128 + n];
        }
        yp += __shfl_down(yp, 1);
        yp += __shfl_down(yp, 2);
        if (q == 0) {
            size_t row = (size_t)b * 2048 + s;
            y[row * 1024 + h * 64 + p] = f2bf(yp + xv * Dh);
        }
        __syncthreads();
    }
}

// ---------------- gated RMS norm: y*silu(z) -> rms(1024, eps 1e-5)*gw -> bf16 ----------------
__global__ __launch_bounds__(256) void k_gnorm(
    const u16* __restrict__ y0, const u16* __restrict__ z0,
    const float* __restrict__ gw0, u16* __restrict__ o0,
    const u16* __restrict__ y1, const u16* __restrict__ z1,
    const float* __restrict__ gw1, u16* __restrict__ o1) {
    __shared__ float red[4];
    int r = blockIdx.x;
    int dir = r >> 12, row = r & 4095;
    int t = threadIdx.x;
    const u16* y = dir ? y1 : y0;
    const u16* zp = dir ? z1 : z0;
    const float* gw = dir ? gw1 : gw0;
    u16* o = dir ? o1 : o0;
    ushort4 yv = *(const ushort4*)(y + (size_t)row * 1024 + t * 4);
    ushort4 zr = *(const ushort4*)(zp + (size_t)row * 1024 + t * 4);
    float z0f = bf2f(zr.x), z1f = bf2f(zr.y), z2f = bf2f(zr.z), z3f = bf2f(zr.w);
    float v0 = bf2f(yv.x) * (z0f / (1.f + expf(-z0f)));
    float v1 = bf2f(yv.y) * (z1f / (1.f + expf(-z1f)));
    float v2 = bf2f(yv.z) * (z2f / (1.f + expf(-z2f)));
    float v3 = bf2f(yv.w) * (z3f / (1.f + expf(-z3f)));
    float ss = block_sum_256(v0 * v0 + v1 * v1 + v2 * v2 + v3 * v3, red);
    float sc = rsqrtf(ss * (1.f / 1024.f) + 1e-5f);
    float4 gv = *(const float4*)(gw + t * 4);
    size_t ob = (size_t)row * 1024 + t * 4;
    o[ob + 0] = f2bf(v0 * sc * gv.x);
    o[ob + 1] = f2bf(v1 * sc * gv.y);
    o[ob + 2] = f2bf(v2 * sc * gv.z);
    o[ob + 3] = f2bf(v3 * sc * gv.w);
}

// ---------------- x2 = x + (fwd + flip(bwd)) * mask (f32 out) ----------------
__global__ void k_add(const float* __restrict__ x, const u16* __restrict__ of,
                      const u16* __restrict__ ob, const float* __restrict__ mask,
                      float* __restrict__ x2) {
    int i = blockIdx.x * 256 + threadIdx.x;  // 4096*512
    int row = i >> 9, d = i & 511;
    int bb = row >> 11, tl = row & 2047;
    size_t fi = (size_t)((bb << 11) + (2047 - tl)) * 512 + d;
    x2[i] = x[i] + (bf2f(of[i]) + bf2f(ob[fi])) * mask[row];
}

// ---------------- rms(x2)*norm_ffn_w -> bf16 ----------------
__global__ __launch_bounds__(256) void k_rms2(const float* __restrict__ x2,
                                              const float* __restrict__ wrms,
                                              u16* __restrict__ o) {
    __shared__ float red[4];
    int row = blockIdx.x, t = threadIdx.x;
    size_t base = (size_t)row * 512 + t * 2;
    float2 v = *(const float2*)(x2 + base);
    float ss = block_sum_256(v.x * v.x + v.y * v.y, red);
    float sc = rsqrtf(ss * (1.f / 512.f) + 1.1920929e-07f);
    float2 wv = *(const float2*)(wrms + t * 2);
    o[base] = f2bf(v.x * sc * wv.x);
    o[base + 1] = f2bf(v.y * sc * wv.y);
}

// ---------------- gelu(v + b1) -> bf16 ----------------
__global__ void k_gelu(const u16* __restrict__ v, const float* __restrict__ b1,
                       u16* __restrict__ o) {
    int i = blockIdx.x * 256 + threadIdx.x;  // 4096*2048
    int c = i & 2047;
    float x = bf2f(v[i]) + b1[c];
    float g = 0.5f * x * (1.f + erff(x * 0.70710678118654752f));
    o[i] = f2bf(g);
}

// ---------------- out = x2 + ffn2 + b2 -> f32 (reference output dtype) ----------------
__global__ void k_final(const float* __restrict__ x2, const u16* __restrict__ f2,
                        const float* __restrict__ b2, float* __restrict__ out) {
    int i = blockIdx.x * 256 + threadIdx.x;  // 4096*512
    int c = i & 511;
    out[i] = x2[i] + bf2f(f2[i]) + b2[c];
}

extern "C" void kernel_launch(void* const* d_in, const int* in_sizes, int n_in,
                              void* d_out, int out_size, void* d_ws, size_t ws_size,
                              hipStream_t stream) {
    const float* x = (const float*)d_in[0];
    const float* pe = (const float*)d_in[1];
    const float* mask = (const float*)d_in[2];
    const float* nsw = (const float*)d_in[3];
    const float* nfw = (const float*)d_in[4];
    const float* w1 = (const float*)d_in[5];
    const float* b1 = (const float*)d_in[6];
    const float* w2 = (const float*)d_in[7];
    const float* b2 = (const float*)d_in[8];
    const float* f_inw = (const float*)d_in[9];
    const float* f_cw = (const float*)d_in[10];
    const float* f_cb = (const float*)d_in[11];
    const float* f_dtb = (const float*)d_in[12];
    const float* f_al = (const float*)d_in[13];
    const float* f_D = (const float*)d_in[14];
    const float* f_gw = (const float*)d_in[15];
    const float* f_ow = (const float*)d_in[16];
    const float* b_inw = (const float*)d_in[17];
    const float* b_cw = (const float*)d_in[18];
    const float* b_cb = (const float*)d_in[19];
    const float* b_dtb = (const float*)d_in[20];
    const float* b_al = (const float*)d_in[21];
    const float* b_D = (const float*)d_in[22];
    const float* b_gw = (const float*)d_in[23];
    const float* b_ow = (const float*)d_in[24];
    float* out = (float*)d_out;

    char* ws = (char*)d_ws;
    // Activation overlays (liveness-checked, round-3 scheme), [0, 56,098,816):
    u16* Z0   = (u16*)(ws + 0);
    u16* Z1   = (u16*)(ws + 8388608);
    u16* XB0  = (u16*)(ws + 16777216);
    u16* XB1  = (u16*)(ws + 26476544);
    u16* INWF = (u16*)(ws + 36175872);
    u16* INWB = (u16*)(ws + 38535168);
    u16* SIB  = (u16*)(ws + 40894464);
    u16* XC0  = (u16*)(ws + 36175872);
    u16* XC1  = (u16*)(ws + 45613056);
    float* dtF = (float*)(ws + 55050240);
    float* dAF = (float*)(ws + 55312384);
    float* dtB = (float*)(ws + 55574528);
    float* dAB = (float*)(ws + 55836672);
    u16* Y0   = (u16*)(ws + 16777216);
    u16* Y1   = (u16*)(ws + 25165824);
    u16* YG0  = (u16*)(ws + 36175872);
    u16* YG1  = (u16*)(ws + 44564480);
    u16* OP0  = (u16*)(ws + 0);
    u16* OP1  = (u16*)(ws + 4194304);
    float* X2 = (float*)(ws + 8388608);
    u16* X2B  = (u16*)(ws + 0);
    u16* FFN1 = (u16*)(ws + 36175872);
    u16* HACT = (u16*)(ws + 16777216);
    u16* FFN2 = (u16*)(ws + 4194304);
    // Pinned bf16 weights [56,098,816, 62,390,272):
    u16* OWF = (u16*)(ws + 56098816);
    u16* OWB = (u16*)(ws + 57147392);
    u16* W1B = (u16*)(ws + 58195968);
    u16* W2B = (u16*)(ws + 60293120);

    k_cvt_pad_inw<<<2304 * 512 / 256, 256, 0, stream>>>(f_inw, INWF);
    k_cvt_pad_inw<<<2304 * 512 / 256, 256, 0, stream>>>(b_inw, INWB);
    k_cvt<<<2048, 256, 0, stream>>>(f_ow, OWF, 524288);
    k_cvt<<<2048, 256, 0, stream>>>(b_ow, OWB, 524288);
    k_cvt<<<4096, 256, 0, stream>>>(w1, W1B, 1048576);
    k_cvt<<<4096, 256, 0, stream>>>(w2, W2B, 1048576);
    k_rms_pos<<<4096, 256, 0, stream>>>(x, pe, nsw, SIB);
    k_gemm_in<<<dim3(18, 32, 2), 256, 0, stream>>>(SIB, INWF, INWB, Z0, Z1, XB0, XB1);
    k_conv<<<dim3(5, 8192), 256, 0, stream>>>(XB0, XB1, f_cw, f_cb, f_dtb, f_al,
                                              b_cw, b_cb, b_dtb, b_al,
                                              XC0, XC1, dtF, dAF, dtB, dAB);
    k_scan<<<64, 256, 0, stream>>>(XC0, dtF, dAF, f_D, Y0, XC1, dtB, dAB, b_D, Y1);
    k_gnorm<<<8192, 256, 0, stream>>>(Y0, Z0, f_gw, YG0, Y1, Z1, b_gw, YG1);
    k_gemm2<<<dim3(4, 32, 2), 256, 0, stream>>>(YG0, YG1, OWF, OWB, OP0, OP1, 512, 1024);
    k_add<<<8192, 256, 0, stream>>>(x, OP0, OP1, mask, X2);
    k_rms2<<<4096, 256, 0, stream>>>(X2, nfw, X2B);
    k_gemm2<<<dim3(16, 32, 1), 256, 0, stream>>>(X2B, X2B, W1B, W1B, FFN1, FFN1, 2048, 512);
    k_gelu<<<32768, 256, 0, stream>>>(FFN1, b1, HACT);
    k_gemm2<<<dim3(4, 32, 1), 256, 0, stream>>>(HACT, HACT, W2B, W2B, FFN2, FFN2, 512, 2048);
    k_final<<<8192, 256, 0, stream>>>(X2, FFN2, b2, out);
}

// Round 7
// 477.033 us; speedup vs baseline: 3.8830x; 3.8830x over previous
//
#include <hip/hip_runtime.h>
#include <hip/hip_bf16.h>

typedef unsigned short u16;
typedef unsigned int u32;
typedef __bf16 bf16x8 __attribute__((ext_vector_type(8)));
typedef float f32x4 __attribute__((ext_vector_type(4)));

__device__ __forceinline__ float bf2f(u16 v) {
    u32 x = (u32)v << 16;
    return __builtin_bit_cast(float, x);
}
__device__ __forceinline__ u16 f2bf(float f) {
    return __builtin_bit_cast(u16, (__bf16)f);
}

// ---------------- block reduction (256 threads = 4 waves) ----------------
__device__ __forceinline__ float block_sum_256(float v, float* red) {
    #pragma unroll
    for (int o = 32; o > 0; o >>= 1) v += __shfl_xor(v, o);
    int w = threadIdx.x >> 6;
    if ((threadIdx.x & 63) == 0) red[w] = v;
    __syncthreads();
    return red[0] + red[1] + red[2] + red[3];
}

// ---------------- f32 -> bf16 conversions ----------------
__global__ void k_cvt(const float* __restrict__ s, u16* __restrict__ d, int n) {
    int i = blockIdx.x * 256 + threadIdx.x;
    if (i < n) d[i] = f2bf(s[i]);
}

__global__ void k_cvt_pad_inw(const float* __restrict__ s, u16* __restrict__ d) {
    int i = blockIdx.x * 256 + threadIdx.x;  // < 2304*512
    int n = i >> 9;
    d[i] = (n < 2192) ? f2bf(s[i]) : (u16)0;
}

// ---------------- si = rms(x)*w + pos_emb -> bf16 ----------------
__global__ __launch_bounds__(256) void k_rms_pos(const float* __restrict__ x,
                                                 const float* __restrict__ pe,
                                                 const float* __restrict__ wrms,
                                                 u16* __restrict__ sib) {
    __shared__ float red[4];
    int row = blockIdx.x, t = threadIdx.x;
    size_t base = (size_t)row * 512 + t * 2;
    float2 xv = *(const float2*)(x + base);
    float ss = block_sum_256(xv.x * xv.x + xv.y * xv.y, red);
    float sc = rsqrtf(ss * (1.f / 512.f) + 1.1920929e-07f);
    float2 pv = *(const float2*)(pe + base);
    float2 wv = *(const float2*)(wrms + t * 2);
    sib[base] = f2bf(xv.x * sc * wv.x + pv.x);
    sib[base + 1] = f2bf(xv.y * sc * wv.y + pv.y);
}

// ---------------- in_proj GEMM with split epilogue ----------------
__global__ __launch_bounds__(256) void k_gemm_in(
    const u16* __restrict__ A, const u16* __restrict__ W0, const u16* __restrict__ W1,
    u16* __restrict__ Z0, u16* __restrict__ Z1,
    u16* __restrict__ XB0, u16* __restrict__ XB1) {
    const int z = blockIdx.z;
    const u16* W = z ? W1 : W0;
    u16* Z = z ? Z1 : Z0;
    u16* XB = z ? XB1 : XB0;
    const int K = 512;

    __shared__ __align__(16) u16 As[128 * 32];
    __shared__ __align__(16) u16 Bs[128 * 32];

    const int t = threadIdx.x;
    const int lane = t & 63;
    const int w = t >> 6;
    const int m0 = blockIdx.y * 128;
    const int n0 = blockIdx.x * 128;
    const int wm = (w >> 1) * 64;
    const int wn = (w & 1) * 64;
    const int fr = lane & 15;
    const int fk = (lane >> 4) * 8;

    f32x4 acc[4][4];
    #pragma unroll
    for (int i = 0; i < 4; ++i)
        #pragma unroll
        for (int j = 0; j < 4; ++j) acc[i][j] = (f32x4){0.f, 0.f, 0.f, 0.f};

    for (int kt = 0; kt < K; kt += 32) {
        #pragma unroll
        for (int j = 0; j < 2; ++j) {
            int off16 = j * 256 + t;
            int row = off16 >> 2;
            int kc = (off16 & 3) * 8;
            int gm = m0 + row;
            if (z) gm = (gm & ~2047) | (2047 - (gm & 2047));
            *(uint4*)(As + row * 32 + kc) = *(const uint4*)(A + (size_t)gm * K + kt + kc);
            int gn = n0 + row;
            *(uint4*)(Bs + row * 32 + kc) = *(const uint4*)(W + (size_t)gn * K + kt + kc);
        }
        __syncthreads();
        bf16x8 af[4], bfr[4];
        #pragma unroll
        for (int i = 0; i < 4; ++i) af[i] = *(const bf16x8*)(As + (wm + i * 16 + fr) * 32 + fk);
        #pragma unroll
        for (int i = 0; i < 4; ++i) bfr[i] = *(const bf16x8*)(Bs + (wn + i * 16 + fr) * 32 + fk);
        #pragma unroll
        for (int i = 0; i < 4; ++i)
            #pragma unroll
            for (int j = 0; j < 4; ++j)
                acc[i][j] = __builtin_amdgcn_mfma_f32_16x16x32_bf16(af[i], bfr[j], acc[i][j], 0, 0, 0);
        __syncthreads();
    }
    #pragma unroll
    for (int i = 0; i < 4; ++i) {
        int rbase = m0 + wm + i * 16 + (lane >> 4) * 4;
        #pragma unroll
        for (int j = 0; j < 4; ++j) {
            int c = n0 + wn + j * 16 + fr;
            #pragma unroll
            for (int r = 0; r < 4; ++r) {
                u16 v = f2bf(acc[i][j][r]);
                int m = rbase + r;
                if (c < 1024) Z[(size_t)m * 1024 + c] = v;
                else if (c < 2192) XB[(size_t)m * 1184 + (c - 1024)] = v;
            }
        }
    }
}

// ---------------- generic bf16 GEMM ----------------
__global__ __launch_bounds__(256) void k_gemm2(
    const u16* __restrict__ A0, const u16* __restrict__ A1,
    const u16* __restrict__ W0, const u16* __restrict__ W1,
    u16* __restrict__ C0, u16* __restrict__ C1, int N, int K) {
    const int z = blockIdx.z;
    const u16* A = z ? A1 : A0;
    const u16* W = z ? W1 : W0;
    u16* C = z ? C1 : C0;

    __shared__ __align__(16) u16 As[128 * 32];
    __shared__ __align__(16) u16 Bs[128 * 32];

    const int t = threadIdx.x;
    const int lane = t & 63;
    const int w = t >> 6;
    const int m0 = blockIdx.y * 128;
    const int n0 = blockIdx.x * 128;
    const int wm = (w >> 1) * 64;
    const int wn = (w & 1) * 64;
    const int fr = lane & 15;
    const int fk = (lane >> 4) * 8;

    f32x4 acc[4][4];
    #pragma unroll
    for (int i = 0; i < 4; ++i)
        #pragma unroll
        for (int j = 0; j < 4; ++j) acc[i][j] = (f32x4){0.f, 0.f, 0.f, 0.f};

    for (int kt = 0; kt < K; kt += 32) {
        #pragma unroll
        for (int j = 0; j < 2; ++j) {
            int off16 = j * 256 + t;
            int row = off16 >> 2;
            int kc = (off16 & 3) * 8;
            *(uint4*)(As + row * 32 + kc) = *(const uint4*)(A + (size_t)(m0 + row) * K + kt + kc);
            *(uint4*)(Bs + row * 32 + kc) = *(const uint4*)(W + (size_t)(n0 + row) * K + kt + kc);
        }
        __syncthreads();
        bf16x8 af[4], bfr[4];
        #pragma unroll
        for (int i = 0; i < 4; ++i) af[i] = *(const bf16x8*)(As + (wm + i * 16 + fr) * 32 + fk);
        #pragma unroll
        for (int i = 0; i < 4; ++i) bfr[i] = *(const bf16x8*)(Bs + (wn + i * 16 + fr) * 32 + fk);
        #pragma unroll
        for (int i = 0; i < 4; ++i)
            #pragma unroll
            for (int j = 0; j < 4; ++j)
                acc[i][j] = __builtin_amdgcn_mfma_f32_16x16x32_bf16(af[i], bfr[j], acc[i][j], 0, 0, 0);
        __syncthreads();
    }
    #pragma unroll
    for (int i = 0; i < 4; ++i) {
        int rbase = m0 + wm + i * 16 + (lane >> 4) * 4;
        #pragma unroll
        for (int j = 0; j < 4; ++j) {
            int col = n0 + wn + j * 16 + fr;
            #pragma unroll
            for (int r = 0; r < 4; ++r)
                C[(size_t)(rbase + r) * N + col] = f2bf(acc[i][j][r]);
        }
    }
}

// ---------------- causal conv4 + silu over xBC; softplus dt; dA ----------------
__global__ __launch_bounds__(256) void k_conv(
    const u16* __restrict__ xb0, const u16* __restrict__ xb1,
    const float* __restrict__ cw0, const float* __restrict__ cb0,
    const float* __restrict__ dtb0, const float* __restrict__ al0,
    const float* __restrict__ cw1, const float* __restrict__ cb1,
    const float* __restrict__ dtb1, const float* __restrict__ al1,
    u16* __restrict__ xc0, u16* __restrict__ xc1,
    float* __restrict__ dtO0, float* __restrict__ dAO0,
    float* __restrict__ dtO1, float* __restrict__ dAO1) {
    int col = blockIdx.x * 256 + threadIdx.x;
    int r = blockIdx.y;
    int dir = r >> 12, row = r & 4095;
    const u16* xb = dir ? xb1 : xb0;
    const float* cw = dir ? cw1 : cw0;
    const float* cb = dir ? cb1 : cb0;
    const float* dtb = dir ? dtb1 : dtb0;
    const float* al = dir ? al1 : al0;
    u16* xc = dir ? xc1 : xc0;
    float* dtO = dir ? dtO1 : dtO0;
    float* dAO = dir ? dAO1 : dAO0;
    int bb = row >> 11, tl = row & 2047;
    if (col < 1152) {
        float acc = cb[col];
        #pragma unroll
        for (int i = 0; i < 4; ++i) {
            int tt = tl + i - 3;
            if (tt >= 0)
                acc += bf2f(xb[(size_t)((bb << 11) + tt) * 1184 + col]) * cw[col * 4 + i];
        }
        acc = acc / (1.f + expf(-acc));  // silu
        xc[(size_t)row * 1152 + col] = f2bf(acc);
    } else if (col < 1168) {
        int hh = col - 1152;
        float v = bf2f(xb[(size_t)row * 1184 + 1152 + hh]) + dtb[hh];
        float sp = (v > 20.f) ? v : log1pf(expf(v));  // softplus
        dtO[row * 16 + hh] = sp;
        dAO[row * 16 + hh] = expf(-expf(al[hh]) * sp);
    }
}

// ======== chunked scan: L=2048 -> 32 chunks of 64 ========
// thread t: p = t>>2 (headdim), q = t&3 owns n = q*16..q*16+15.
// blk layout pass A/C: (((dir*2+b)*16+h)*32 + c)

// ---- Pass A: per-chunk local state from h=0; store S_c (4096 f32) + Aprod ----
__global__ __launch_bounds__(256) void k_scan_state(
    const u16* __restrict__ xc0, const float* __restrict__ dt0, const float* __restrict__ dA0,
    const u16* __restrict__ xc1, const float* __restrict__ dt1, const float* __restrict__ dA1,
    float* __restrict__ S, float* __restrict__ Aprod) {
    int blk = blockIdx.x;
    int c = blk & 31, h = (blk >> 5) & 15, b = (blk >> 9) & 1, dir = blk >> 10;
    const u16* xc = dir ? xc1 : xc0;
    const float* dtp = dir ? dt1 : dt0;
    const float* dAp = dir ? dA1 : dA0;
    const int t = threadIdx.x;
    const int p = t >> 2, q = t & 3;

    __shared__ float sx[4096], sB[4096];
    __shared__ float sdt[64], sdA[64];
    size_t row0 = (size_t)b * 2048 + c * 64;
    for (int i = t; i < 4096; i += 256) {
        int s = i >> 6, e = i & 63;
        size_t rb = (row0 + s) * 1152;
        sx[i] = bf2f(xc[rb + h * 64 + e]);
        sB[i] = bf2f(xc[rb + 1024 + e]);
    }
    if (t < 64) {
        sdt[t] = dtp[(row0 + t) * 16 + h];
        sdA[t] = dAp[(row0 + t) * 16 + h];
    }
    __syncthreads();

    float hs[16];
    #pragma unroll
    for (int j = 0; j < 16; ++j) hs[j] = 0.f;
    float ap = 1.f;
    for (int s = 0; s < 64; ++s) {
        float dAv = sdA[s];
        float coef = sdt[s] * sx[s * 64 + p];
        ap *= dAv;
        const float4* Bp = (const float4*)&sB[s * 64 + q * 16];
        #pragma unroll
        for (int j4 = 0; j4 < 4; ++j4) {
            float4 Bv = Bp[j4];
            hs[j4 * 4 + 0] = hs[j4 * 4 + 0] * dAv + coef * Bv.x;
            hs[j4 * 4 + 1] = hs[j4 * 4 + 1] * dAv + coef * Bv.y;
            hs[j4 * 4 + 2] = hs[j4 * 4 + 2] * dAv + coef * Bv.z;
            hs[j4 * 4 + 3] = hs[j4 * 4 + 3] * dAv + coef * Bv.w;
        }
    }
    float* Sp = S + (size_t)blk * 4096 + t * 16;
    #pragma unroll
    for (int j4 = 0; j4 < 4; ++j4)
        *(float4*)(Sp + j4 * 4) = make_float4(hs[j4 * 4], hs[j4 * 4 + 1], hs[j4 * 4 + 2], hs[j4 * 4 + 3]);
    if (t == 0) Aprod[blk] = ap;
}

// ---- Pass B: 64 blocks (dir,b,h); in-place S_c -> carry-in H_c ----
__global__ __launch_bounds__(256) void k_scan_carry(float* __restrict__ S,
                                                    const float* __restrict__ Aprod) {
    int blk = blockIdx.x;  // (dir*2+b)*16+h
    int t = threadIdx.x;
    float h[16];
    #pragma unroll
    for (int j = 0; j < 16; ++j) h[j] = 0.f;
    for (int c = 0; c < 32; ++c) {
        float a = Aprod[blk * 32 + c];
        float* Sp = S + ((size_t)blk * 32 + c) * 4096 + t * 16;
        float4 s0 = *(float4*)(Sp + 0), s1 = *(float4*)(Sp + 4);
        float4 s2 = *(float4*)(Sp + 8), s3 = *(float4*)(Sp + 12);
        *(float4*)(Sp + 0) = make_float4(h[0], h[1], h[2], h[3]);
        *(float4*)(Sp + 4) = make_float4(h[4], h[5], h[6], h[7]);
        *(float4*)(Sp + 8) = make_float4(h[8], h[9], h[10], h[11]);
        *(float4*)(Sp + 12) = make_float4(h[12], h[13], h[14], h[15]);
        h[0] = a * h[0] + s0.x; h[1] = a * h[1] + s0.y; h[2] = a * h[2] + s0.z; h[3] = a * h[3] + s0.w;
        h[4] = a * h[4] + s1.x; h[5] = a * h[5] + s1.y; h[6] = a * h[6] + s1.z; h[7] = a * h[7] + s1.w;
        h[8] = a * h[8] + s2.x; h[9] = a * h[9] + s2.y; h[10] = a * h[10] + s2.z; h[11] = a * h[11] + s2.w;
        h[12] = a * h[12] + s3.x; h[13] = a * h[13] + s3.y; h[14] = a * h[14] + s3.z; h[15] = a * h[15] + s3.w;
    }
}

// ---- Pass C: rescan chunk with carry-in; produce y ----
__global__ __launch_bounds__(256) void k_scan_y(
    const u16* __restrict__ xc0, const float* __restrict__ dt0, const float* __restrict__ dA0,
    const float* __restrict__ Dv0, u16* __restrict__ y0,
    const u16* __restrict__ xc1, const float* __restrict__ dt1, const float* __restrict__ dA1,
    const float* __restrict__ Dv1, u16* __restrict__ y1,
    const float* __restrict__ S) {
    int blk = blockIdx.x;
    int c = blk & 31, h = (blk >> 5) & 15, b = (blk >> 9) & 1, dir = blk >> 10;
    const u16* xc = dir ? xc1 : xc0;
    const float* dtp = dir ? dt1 : dt0;
    const float* dAp = dir ? dA1 : dA0;
    u16* y = dir ? y1 : y0;
    const float Dh = (dir ? Dv1 : Dv0)[h];
    const int t = threadIdx.x;
    const int p = t >> 2, q = t & 3;

    __shared__ float sx[4096], sB[4096], sC[4096];
    __shared__ float sdt[64], sdA[64];
    size_t row0 = (size_t)b * 2048 + c * 64;
    for (int i = t; i < 4096; i += 256) {
        int s = i >> 6, e = i & 63;
        size_t rb = (row0 + s) * 1152;
        sx[i] = bf2f(xc[rb + h * 64 + e]);
        sB[i] = bf2f(xc[rb + 1024 + e]);
        sC[i] = bf2f(xc[rb + 1088 + e]);
    }
    if (t < 64) {
        sdt[t] = dtp[(row0 + t) * 16 + h];
        sdA[t] = dAp[(row0 + t) * 16 + h];
    }
    __syncthreads();

    float hs[16];
    const float* Sp = S + (size_t)blk * 4096 + t * 16;
    #pragma unroll
    for (int j4 = 0; j4 < 4; ++j4) {
        float4 v = *(const float4*)(Sp + j4 * 4);
        hs[j4 * 4 + 0] = v.x; hs[j4 * 4 + 1] = v.y; hs[j4 * 4 + 2] = v.z; hs[j4 * 4 + 3] = v.w;
    }
    for (int s = 0; s < 64; ++s) {
        float dAv = sdA[s];
        float xv = sx[s * 64 + p];
        float coef = sdt[s] * xv;
        const float4* Bp = (const float4*)&sB[s * 64 + q * 16];
        const float4* Cp = (const float4*)&sC[s * 64 + q * 16];
        float yp = 0.f;
        #pragma unroll
        for (int j4 = 0; j4 < 4; ++j4) {
            float4 Bv = Bp[j4], Cv = Cp[j4];
            hs[j4 * 4 + 0] = hs[j4 * 4 + 0] * dAv + coef * Bv.x; yp += hs[j4 * 4 + 0] * Cv.x;
            hs[j4 * 4 + 1] = hs[j4 * 4 + 1] * dAv + coef * Bv.y; yp += hs[j4 * 4 + 1] * Cv.y;
            hs[j4 * 4 + 2] = hs[j4 * 4 + 2] * dAv + coef * Bv.z; yp += hs[j4 * 4 + 2] * Cv.z;
            hs[j4 * 4 + 3] = hs[j4 * 4 + 3] * dAv + coef * Bv.w; yp += hs[j4 * 4 + 3] * Cv.w;
        }
        yp += __shfl_down(yp, 1);
        yp += __shfl_down(yp, 2);
        if (q == 0)
            y[(row0 + s) * 1024 + h * 64 + p] = f2bf(yp + xv * Dh);
    }
}

// ---------------- gated RMS norm ----------------
__global__ __launch_bounds__(256) void k_gnorm(
    const u16* __restrict__ y0, const u16* __restrict__ z0,
    const float* __restrict__ gw0, u16* __restrict__ o0,
    const u16* __restrict__ y1, const u16* __restrict__ z1,
    const float* __restrict__ gw1, u16* __restrict__ o1) {
    __shared__ float red[4];
    int r = blockIdx.x;
    int dir = r >> 12, row = r & 4095;
    int t = threadIdx.x;
    const u16* y = dir ? y1 : y0;
    const u16* zp = dir ? z1 : z0;
    const float* gw = dir ? gw1 : gw0;
    u16* o = dir ? o1 : o0;
    ushort4 yv = *(const ushort4*)(y + (size_t)row * 1024 + t * 4);
    ushort4 zr = *(const ushort4*)(zp + (size_t)row * 1024 + t * 4);
    float z0f = bf2f(zr.x), z1f = bf2f(zr.y), z2f = bf2f(zr.z), z3f = bf2f(zr.w);
    float v0 = bf2f(yv.x) * (z0f / (1.f + expf(-z0f)));
    float v1 = bf2f(yv.y) * (z1f / (1.f + expf(-z1f)));
    float v2 = bf2f(yv.z) * (z2f / (1.f + expf(-z2f)));
    float v3 = bf2f(yv.w) * (z3f / (1.f + expf(-z3f)));
    float ss = block_sum_256(v0 * v0 + v1 * v1 + v2 * v2 + v3 * v3, red);
    float sc = rsqrtf(ss * (1.f / 1024.f) + 1e-5f);
    float4 gv = *(const float4*)(gw + t * 4);
    size_t ob = (size_t)row * 1024 + t * 4;
    o[ob + 0] = f2bf(v0 * sc * gv.x);
    o[ob + 1] = f2bf(v1 * sc * gv.y);
    o[ob + 2] = f2bf(v2 * sc * gv.z);
    o[ob + 3] = f2bf(v3 * sc * gv.w);
}

// ---------------- x2 = x + (fwd + flip(bwd)) * mask (f32 out) ----------------
__global__ void k_add(const float* __restrict__ x, const u16* __restrict__ of,
                      const u16* __restrict__ ob, const float* __restrict__ mask,
                      float* __restrict__ x2) {
    int i = blockIdx.x * 256 + threadIdx.x;  // 4096*512
    int row = i >> 9, d = i & 511;
    int bb = row >> 11, tl = row & 2047;
    size_t fi = (size_t)((bb << 11) + (2047 - tl)) * 512 + d;
    x2[i] = x[i] + (bf2f(of[i]) + bf2f(ob[fi])) * mask[row];
}

// ---------------- rms(x2)*norm_ffn_w -> bf16 ----------------
__global__ __launch_bounds__(256) void k_rms2(const float* __restrict__ x2,
                                              const float* __restrict__ wrms,
                                              u16* __restrict__ o) {
    __shared__ float red[4];
    int row = blockIdx.x, t = threadIdx.x;
    size_t base = (size_t)row * 512 + t * 2;
    float2 v = *(const float2*)(x2 + base);
    float ss = block_sum_256(v.x * v.x + v.y * v.y, red);
    float sc = rsqrtf(ss * (1.f / 512.f) + 1.1920929e-07f);
    float2 wv = *(const float2*)(wrms + t * 2);
    o[base] = f2bf(v.x * sc * wv.x);
    o[base + 1] = f2bf(v.y * sc * wv.y);
}

// ---------------- gelu(v + b1) -> bf16 ----------------
__global__ void k_gelu(const u16* __restrict__ v, const float* __restrict__ b1,
                       u16* __restrict__ o) {
    int i = blockIdx.x * 256 + threadIdx.x;  // 4096*2048
    int c = i & 2047;
    float x = bf2f(v[i]) + b1[c];
    float g = 0.5f * x * (1.f + erff(x * 0.70710678118654752f));
    o[i] = f2bf(g);
}

// ---------------- out = x2 + ffn2 + b2 -> f32 ----------------
__global__ void k_final(const float* __restrict__ x2, const u16* __restrict__ f2,
                        const float* __restrict__ b2, float* __restrict__ out) {
    int i = blockIdx.x * 256 + threadIdx.x;  // 4096*512
    int c = i & 511;
    out[i] = x2[i] + bf2f(f2[i]) + b2[c];
}

extern "C" void kernel_launch(void* const* d_in, const int* in_sizes, int n_in,
                              void* d_out, int out_size, void* d_ws, size_t ws_size,
                              hipStream_t stream) {
    const float* x = (const float*)d_in[0];
    const float* pe = (const float*)d_in[1];
    const float* mask = (const float*)d_in[2];
    const float* nsw = (const float*)d_in[3];
    const float* nfw = (const float*)d_in[4];
    const float* w1 = (const float*)d_in[5];
    const float* b1 = (const float*)d_in[6];
    const float* w2 = (const float*)d_in[7];
    const float* b2 = (const float*)d_in[8];
    const float* f_inw = (const float*)d_in[9];
    const float* f_cw = (const float*)d_in[10];
    const float* f_cb = (const float*)d_in[11];
    const float* f_dtb = (const float*)d_in[12];
    const float* f_al = (const float*)d_in[13];
    const float* f_D = (const float*)d_in[14];
    const float* f_gw = (const float*)d_in[15];
    const float* f_ow = (const float*)d_in[16];
    const float* b_inw = (const float*)d_in[17];
    const float* b_cw = (const float*)d_in[18];
    const float* b_cb = (const float*)d_in[19];
    const float* b_dtb = (const float*)d_in[20];
    const float* b_al = (const float*)d_in[21];
    const float* b_D = (const float*)d_in[22];
    const float* b_gw = (const float*)d_in[23];
    const float* b_ow = (const float*)d_in[24];
    float* out = (float*)d_out;

    char* ws = (char*)d_ws;
    // Activation overlays (liveness-checked), [0, 56,098,816):
    u16* Z0   = (u16*)(ws + 0);
    u16* Z1   = (u16*)(ws + 8388608);
    u16* XB0  = (u16*)(ws + 16777216);
    u16* XB1  = (u16*)(ws + 26476544);
    u16* INWF = (u16*)(ws + 36175872);
    u16* INWB = (u16*)(ws + 38535168);
    u16* SIB  = (u16*)(ws + 40894464);
    u16* XC0  = (u16*)(ws + 36175872);
    u16* XC1  = (u16*)(ws + 45613056);
    float* dtF = (float*)(ws + 55050240);
    float* dAF = (float*)(ws + 55312384);
    float* dtB = (float*)(ws + 55574528);
    float* dAB = (float*)(ws + 55836672);
    u16* Y0   = (u16*)(ws + 16777216);
    u16* Y1   = (u16*)(ws + 25165824);
    u16* YG0  = (u16*)(ws + 36175872);
    u16* YG1  = (u16*)(ws + 44564480);
    u16* OP0  = (u16*)(ws + 0);
    u16* OP1  = (u16*)(ws + 4194304);
    float* X2 = (float*)(ws + 8388608);
    u16* X2B  = (u16*)(ws + 0);
    u16* FFN1 = (u16*)(ws + 36175872);
    u16* HACT = (u16*)(ws + 16777216);
    u16* FFN2 = (u16*)(ws + 4194304);
    // Pinned bf16 weights [56,098,816, 62,390,272):
    u16* OWF = (u16*)(ws + 56098816);
    u16* OWB = (u16*)(ws + 57147392);
    u16* W1B = (u16*)(ws + 58195968);
    u16* W2B = (u16*)(ws + 60293120);
    // Chunked-scan state [62,390,272, 95,952,896):
    float* SBUF = (float*)(ws + 62390272);   // 2048 x 4096 f32 = 32 MB
    float* APR  = (float*)(ws + 95944704);   // 2048 f32

    k_cvt_pad_inw<<<2304 * 512 / 256, 256, 0, stream>>>(f_inw, INWF);
    k_cvt_pad_inw<<<2304 * 512 / 256, 256, 0, stream>>>(b_inw, INWB);
    k_cvt<<<2048, 256, 0, stream>>>(f_ow, OWF, 524288);
    k_cvt<<<2048, 256, 0, stream>>>(b_ow, OWB, 524288);
    k_cvt<<<4096, 256, 0, stream>>>(w1, W1B, 1048576);
    k_cvt<<<4096, 256, 0, stream>>>(w2, W2B, 1048576);
    k_rms_pos<<<4096, 256, 0, stream>>>(x, pe, nsw, SIB);
    k_gemm_in<<<dim3(18, 32, 2), 256, 0, stream>>>(SIB, INWF, INWB, Z0, Z1, XB0, XB1);
    k_conv<<<dim3(5, 8192), 256, 0, stream>>>(XB0, XB1, f_cw, f_cb, f_dtb, f_al,
                                              b_cw, b_cb, b_dtb, b_al,
                                              XC0, XC1, dtF, dAF, dtB, dAB);
    k_scan_state<<<2048, 256, 0, stream>>>(XC0, dtF, dAF, XC1, dtB, dAB, SBUF, APR);
    k_scan_carry<<<64, 256, 0, stream>>>(SBUF, APR);
    k_scan_y<<<2048, 256, 0, stream>>>(XC0, dtF, dAF, f_D, Y0,
                                       XC1, dtB, dAB, b_D, Y1, SBUF);
    k_gnorm<<<8192, 256, 0, stream>>>(Y0, Z0, f_gw, YG0, Y1, Z1, b_gw, YG1);
    k_gemm2<<<dim3(4, 32, 2), 256, 0, stream>>>(YG0, YG1, OWF, OWB, OP0, OP1, 512, 1024);
    k_add<<<8192, 256, 0, stream>>>(x, OP0, OP1, mask, X2);
    k_rms2<<<4096, 256, 0, stream>>>(X2, nfw, X2B);
    k_gemm2<<<dim3(16, 32, 1), 256, 0, stream>>>(X2B, X2B, W1B, W1B, FFN1, FFN1, 2048, 512);
    k_gelu<<<32768, 256, 0, stream>>>(FFN1, b1, HACT);
    k_gemm2<<<dim3(4, 32, 1), 256, 0, stream>>>(HACT, HACT, W2B, W2B, FFN2, FFN2, 512, 2048);
    k_final<<<8192, 256, 0, stream>>>(X2, FFN2, b2, out);
}

// Round 8
// 428.135 us; speedup vs baseline: 4.3265x; 1.1142x over previous
//
#include <hip/hip_runtime.h>
#include <hip/hip_bf16.h>

typedef unsigned short u16;
typedef unsigned int u32;
typedef __bf16 bf16x8 __attribute__((ext_vector_type(8)));
typedef float f32x4 __attribute__((ext_vector_type(4)));

__device__ __forceinline__ float bf2f(u16 v) {
    u32 x = (u32)v << 16;
    return __builtin_bit_cast(float, x);
}
__device__ __forceinline__ u16 f2bf(float f) {
    return __builtin_bit_cast(u16, (__bf16)f);
}

// ---------------- block reduction (256 threads = 4 waves) ----------------
__device__ __forceinline__ float block_sum_256(float v, float* red) {
    #pragma unroll
    for (int o = 32; o > 0; o >>= 1) v += __shfl_xor(v, o);
    int w = threadIdx.x >> 6;
    if ((threadIdx.x & 63) == 0) red[w] = v;
    __syncthreads();
    return red[0] + red[1] + red[2] + red[3];
}

// ---------------- f32 -> bf16 conversions ----------------
__global__ void k_cvt(const float* __restrict__ s, u16* __restrict__ d, int n) {
    int i = blockIdx.x * 256 + threadIdx.x;
    if (i < n) d[i] = f2bf(s[i]);
}

__global__ void k_cvt_pad_inw(const float* __restrict__ s, u16* __restrict__ d) {
    int i = blockIdx.x * 256 + threadIdx.x;  // < 2304*512
    int n = i >> 9;
    d[i] = (n < 2192) ? f2bf(s[i]) : (u16)0;
}

// ---------------- si = rms(x)*w + pos_emb -> bf16 ----------------
__global__ __launch_bounds__(256) void k_rms_pos(const float* __restrict__ x,
                                                 const float* __restrict__ pe,
                                                 const float* __restrict__ wrms,
                                                 u16* __restrict__ sib) {
    __shared__ float red[4];
    int row = blockIdx.x, t = threadIdx.x;
    size_t base = (size_t)row * 512 + t * 2;
    float2 xv = *(const float2*)(x + base);
    float ss = block_sum_256(xv.x * xv.x + xv.y * xv.y, red);
    float sc = rsqrtf(ss * (1.f / 512.f) + 1.1920929e-07f);
    float2 pv = *(const float2*)(pe + base);
    float2 wv = *(const float2*)(wrms + t * 2);
    sib[base] = f2bf(xv.x * sc * wv.x + pv.x);
    sib[base + 1] = f2bf(xv.y * sc * wv.y + pv.y);
}

// ---------------- in_proj GEMM with split epilogue ----------------
__global__ __launch_bounds__(256) void k_gemm_in(
    const u16* __restrict__ A, const u16* __restrict__ W0, const u16* __restrict__ W1,
    u16* __restrict__ Z0, u16* __restrict__ Z1,
    u16* __restrict__ XB0, u16* __restrict__ XB1) {
    const int z = blockIdx.z;
    const u16* W = z ? W1 : W0;
    u16* Z = z ? Z1 : Z0;
    u16* XB = z ? XB1 : XB0;
    const int K = 512;

    __shared__ __align__(16) u16 As[128 * 32];
    __shared__ __align__(16) u16 Bs[128 * 32];

    const int t = threadIdx.x;
    const int lane = t & 63;
    const int w = t >> 6;
    const int m0 = blockIdx.y * 128;
    const int n0 = blockIdx.x * 128;
    const int wm = (w >> 1) * 64;
    const int wn = (w & 1) * 64;
    const int fr = lane & 15;
    const int fk = (lane >> 4) * 8;

    f32x4 acc[4][4];
    #pragma unroll
    for (int i = 0; i < 4; ++i)
        #pragma unroll
        for (int j = 0; j < 4; ++j) acc[i][j] = (f32x4){0.f, 0.f, 0.f, 0.f};

    for (int kt = 0; kt < K; kt += 32) {
        #pragma unroll
        for (int j = 0; j < 2; ++j) {
            int off16 = j * 256 + t;
            int row = off16 >> 2;
            int kc = (off16 & 3) * 8;
            int gm = m0 + row;
            if (z) gm = (gm & ~2047) | (2047 - (gm & 2047));
            *(uint4*)(As + row * 32 + kc) = *(const uint4*)(A + (size_t)gm * K + kt + kc);
            int gn = n0 + row;
            *(uint4*)(Bs + row * 32 + kc) = *(const uint4*)(W + (size_t)gn * K + kt + kc);
        }
        __syncthreads();
        bf16x8 af[4], bfr[4];
        #pragma unroll
        for (int i = 0; i < 4; ++i) af[i] = *(const bf16x8*)(As + (wm + i * 16 + fr) * 32 + fk);
        #pragma unroll
        for (int i = 0; i < 4; ++i) bfr[i] = *(const bf16x8*)(Bs + (wn + i * 16 + fr) * 32 + fk);
        #pragma unroll
        for (int i = 0; i < 4; ++i)
            #pragma unroll
            for (int j = 0; j < 4; ++j)
                acc[i][j] = __builtin_amdgcn_mfma_f32_16x16x32_bf16(af[i], bfr[j], acc[i][j], 0, 0, 0);
        __syncthreads();
    }
    #pragma unroll
    for (int i = 0; i < 4; ++i) {
        int rbase = m0 + wm + i * 16 + (lane >> 4) * 4;
        #pragma unroll
        for (int j = 0; j < 4; ++j) {
            int c = n0 + wn + j * 16 + fr;
            #pragma unroll
            for (int r = 0; r < 4; ++r) {
                u16 v = f2bf(acc[i][j][r]);
                int m = rbase + r;
                if (c < 1024) Z[(size_t)m * 1024 + c] = v;
                else if (c < 2192) XB[(size_t)m * 1184 + (c - 1024)] = v;
            }
        }
    }
}

// ---------------- generic bf16 GEMM ----------------
__global__ __launch_bounds__(256) void k_gemm2(
    const u16* __restrict__ A0, const u16* __restrict__ A1,
    const u16* __restrict__ W0, const u16* __restrict__ W1,
    u16* __restrict__ C0, u16* __restrict__ C1, int N, int K) {
    const int z = blockIdx.z;
    const u16* A = z ? A1 : A0;
    const u16* W = z ? W1 : W0;
    u16* C = z ? C1 : C0;

    __shared__ __align__(16) u16 As[128 * 32];
    __shared__ __align__(16) u16 Bs[128 * 32];

    const int t = threadIdx.x;
    const int lane = t & 63;
    const int w = t >> 6;
    const int m0 = blockIdx.y * 128;
    const int n0 = blockIdx.x * 128;
    const int wm = (w >> 1) * 64;
    const int wn = (w & 1) * 64;
    const int fr = lane & 15;
    const int fk = (lane >> 4) * 8;

    f32x4 acc[4][4];
    #pragma unroll
    for (int i = 0; i < 4; ++i)
        #pragma unroll
        for (int j = 0; j < 4; ++j) acc[i][j] = (f32x4){0.f, 0.f, 0.f, 0.f};

    for (int kt = 0; kt < K; kt += 32) {
        #pragma unroll
        for (int j = 0; j < 2; ++j) {
            int off16 = j * 256 + t;
            int row = off16 >> 2;
            int kc = (off16 & 3) * 8;
            *(uint4*)(As + row * 32 + kc) = *(const uint4*)(A + (size_t)(m0 + row) * K + kt + kc);
            *(uint4*)(Bs + row * 32 + kc) = *(const uint4*)(W + (size_t)(n0 + row) * K + kt + kc);
        }
        __syncthreads();
        bf16x8 af[4], bfr[4];
        #pragma unroll
        for (int i = 0; i < 4; ++i) af[i] = *(const bf16x8*)(As + (wm + i * 16 + fr) * 32 + fk);
        #pragma unroll
        for (int i = 0; i < 4; ++i) bfr[i] = *(const bf16x8*)(Bs + (wn + i * 16 + fr) * 32 + fk);
        #pragma unroll
        for (int i = 0; i < 4; ++i)
            #pragma unroll
            for (int j = 0; j < 4; ++j)
                acc[i][j] = __builtin_amdgcn_mfma_f32_16x16x32_bf16(af[i], bfr[j], acc[i][j], 0, 0, 0);
        __syncthreads();
    }
    #pragma unroll
    for (int i = 0; i < 4; ++i) {
        int rbase = m0 + wm + i * 16 + (lane >> 4) * 4;
        #pragma unroll
        for (int j = 0; j < 4; ++j) {
            int col = n0 + wn + j * 16 + fr;
            #pragma unroll
            for (int r = 0; r < 4; ++r)
                C[(size_t)(rbase + r) * N + col] = f2bf(acc[i][j][r]);
        }
    }
}

// ---------------- causal conv4 + silu over xBC; softplus dt; LOG-decay ----------------
// dAO now stores log(dA) = -exp(A_log)*dt (<= 0); scan kernels exponentiate.
__global__ __launch_bounds__(256) void k_conv(
    const u16* __restrict__ xb0, const u16* __restrict__ xb1,
    const float* __restrict__ cw0, const float* __restrict__ cb0,
    const float* __restrict__ dtb0, const float* __restrict__ al0,
    const float* __restrict__ cw1, const float* __restrict__ cb1,
    const float* __restrict__ dtb1, const float* __restrict__ al1,
    u16* __restrict__ xc0, u16* __restrict__ xc1,
    float* __restrict__ dtO0, float* __restrict__ dAO0,
    float* __restrict__ dtO1, float* __restrict__ dAO1) {
    int col = blockIdx.x * 256 + threadIdx.x;
    int r = blockIdx.y;
    int dir = r >> 12, row = r & 4095;
    const u16* xb = dir ? xb1 : xb0;
    const float* cw = dir ? cw1 : cw0;
    const float* cb = dir ? cb1 : cb0;
    const float* dtb = dir ? dtb1 : dtb0;
    const float* al = dir ? al1 : al0;
    u16* xc = dir ? xc1 : xc0;
    float* dtO = dir ? dtO1 : dtO0;
    float* dAO = dir ? dAO1 : dAO0;
    int bb = row >> 11, tl = row & 2047;
    if (col < 1152) {
        float acc = cb[col];
        #pragma unroll
        for (int i = 0; i < 4; ++i) {
            int tt = tl + i - 3;
            if (tt >= 0)
                acc += bf2f(xb[(size_t)((bb << 11) + tt) * 1184 + col]) * cw[col * 4 + i];
        }
        acc = acc / (1.f + expf(-acc));  // silu
        xc[(size_t)row * 1152 + col] = f2bf(acc);
    } else if (col < 1168) {
        int hh = col - 1152;
        float v = bf2f(xb[(size_t)row * 1184 + 1152 + hh]) + dtb[hh];
        float sp = (v > 20.f) ? v : log1pf(expf(v));  // softplus
        dtO[row * 16 + hh] = sp;
        dAO[row * 16 + hh] = -expf(al[hh]) * sp;      // LOG decay
    }
}

// ======== SSD chunked scan: L=2048 -> 32 chunks of 64, all-MFMA ========
// blk = (((dir*2+b)*16+h)*32 + c). S layout: S[blk][p*64+n] (f32).
// Fragment convention (verified in k_gemm2): A-row load at (row, k): fr=lane&15,
// fk=(lane>>4)*8; D: row = (lane>>4)*4 + reg, col = lane&15 within 16x16 tile.

// ---- Pass A: S_local[n][p] = sum_r exp(acum63-acum[r])*dt[r]*x[r][p]*B[r][n] ----
__global__ __launch_bounds__(256) void k_ssd_state(
    const u16* __restrict__ xc0, const float* __restrict__ dt0, const float* __restrict__ ld0,
    const u16* __restrict__ xc1, const float* __restrict__ dt1, const float* __restrict__ ld1,
    float* __restrict__ S, float* __restrict__ Aprod) {
    int blk = blockIdx.x;
    int c = blk & 31, h = (blk >> 5) & 15, b = (blk >> 9) & 1, dir = blk >> 10;
    const u16* xc = dir ? xc1 : xc0;
    const float* dtp = dir ? dt1 : dt0;
    const float* ldp = dir ? ld1 : ld0;
    const int t = threadIdx.x, w = t >> 6, lane = t & 63;
    const int fr = lane & 15, fk = (lane >> 4) * 8;

    __shared__ __align__(16) u16 sBt[64 * 72];  // B^T: [n][r]
    __shared__ __align__(16) u16 sXp[64 * 72];  // X~ : [p][r]
    __shared__ float ssc[64];
    size_t row0 = (size_t)b * 2048 + c * 64;

    if (t < 64) {
        float v = ldp[(row0 + t) * 16 + h];
        float dtv = dtp[(row0 + t) * 16 + h];
        #pragma unroll
        for (int o = 1; o < 64; o <<= 1) {
            float u = __shfl_up(v, o);
            if (lane >= o) v += u;
        }
        float last = __shfl(v, 63);
        ssc[t] = dtv * expf(last - v);
        if (t == 63) Aprod[blk] = expf(v);
    }
    __syncthreads();
    for (int i = t; i < 4096; i += 256) {
        int r = i >> 6, e = i & 63;
        size_t rb = (row0 + r) * 1152;
        sBt[e * 72 + r] = xc[rb + 1024 + e];
        sXp[e * 72 + r] = f2bf(bf2f(xc[rb + h * 64 + e]) * ssc[r]);
    }
    __syncthreads();

    f32x4 acc[4];
    #pragma unroll
    for (int j = 0; j < 4; ++j) acc[j] = (f32x4){0.f, 0.f, 0.f, 0.f};
    #pragma unroll
    for (int k0 = 0; k0 < 64; k0 += 32) {
        bf16x8 a = *(const bf16x8*)(sBt + (w * 16 + fr) * 72 + k0 + fk);
        #pragma unroll
        for (int j = 0; j < 4; ++j) {
            bf16x8 bb = *(const bf16x8*)(sXp + (j * 16 + fr) * 72 + k0 + fk);
            acc[j] = __builtin_amdgcn_mfma_f32_16x16x32_bf16(a, bb, acc[j], 0, 0, 0);
        }
    }
    float* Sb = S + (size_t)blk * 4096;
    int nb = w * 16 + (lane >> 4) * 4;
    #pragma unroll
    for (int j = 0; j < 4; ++j) {
        int p = j * 16 + fr;
        *(f32x4*)(Sb + p * 64 + nb) = acc[j];
    }
}

// ---- Pass B: 64 blocks (dir,b,h); in-place S_c -> carry-in H_c (layout-agnostic) ----
__global__ __launch_bounds__(256) void k_scan_carry(float* __restrict__ S,
                                                    const float* __restrict__ Aprod) {
    int blk = blockIdx.x;
    int t = threadIdx.x;
    float h[16];
    #pragma unroll
    for (int j = 0; j < 16; ++j) h[j] = 0.f;
    for (int c = 0; c < 32; ++c) {
        float a = Aprod[blk * 32 + c];
        float* Sp = S + ((size_t)blk * 32 + c) * 4096 + t * 16;
        float4 s0 = *(float4*)(Sp + 0), s1 = *(float4*)(Sp + 4);
        float4 s2 = *(float4*)(Sp + 8), s3 = *(float4*)(Sp + 12);
        *(float4*)(Sp + 0) = make_float4(h[0], h[1], h[2], h[3]);
        *(float4*)(Sp + 4) = make_float4(h[4], h[5], h[6], h[7]);
        *(float4*)(Sp + 8) = make_float4(h[8], h[9], h[10], h[11]);
        *(float4*)(Sp + 12) = make_float4(h[12], h[13], h[14], h[15]);
        h[0] = a * h[0] + s0.x; h[1] = a * h[1] + s0.y; h[2] = a * h[2] + s0.z; h[3] = a * h[3] + s0.w;
        h[4] = a * h[4] + s1.x; h[5] = a * h[5] + s1.y; h[6] = a * h[6] + s1.z; h[7] = a * h[7] + s1.w;
        h[8] = a * h[8] + s2.x; h[9] = a * h[9] + s2.y; h[10] = a * h[10] + s2.z; h[11] = a * h[11] + s2.w;
        h[12] = a * h[12] + s3.x; h[13] = a * h[13] + s3.y; h[14] = a * h[14] + s3.z; h[15] = a * h[15] + s3.w;
    }
}

// ---- Pass C: y = (G.L)(x*dt) + exp(acum)*C*Hin + x*D via 3 MFMA GEMMs ----
__global__ __launch_bounds__(256) void k_ssd_y(
    const u16* __restrict__ xc0, const float* __restrict__ dt0, const float* __restrict__ ld0,
    const float* __restrict__ Dv0, u16* __restrict__ y0,
    const u16* __restrict__ xc1, const float* __restrict__ dt1, const float* __restrict__ ld1,
    const float* __restrict__ Dv1, u16* __restrict__ y1,
    const float* __restrict__ S) {
    int blk = blockIdx.x;
    int c = blk & 31, h = (blk >> 5) & 15, b = (blk >> 9) & 1, dir = blk >> 10;
    const u16* xc = dir ? xc1 : xc0;
    const float* dtp = dir ? dt1 : dt0;
    const float* ldp = dir ? ld1 : ld0;
    u16* y = dir ? y1 : y0;
    const float Dh = (dir ? Dv1 : Dv0)[h];
    const int t = threadIdx.x, w = t >> 6, lane = t & 63;
    const int fr = lane & 15, fk = (lane >> 4) * 8;

    __shared__ __align__(16) u16 sB[64 * 72];   // [r][n]
    __shared__ __align__(16) u16 sC[64 * 72];   // [s][n]
    __shared__ __align__(16) u16 sXp[64 * 72];  // [p][r] = x[r][p]*dt[r]
    __shared__ __align__(16) u16 sHi[64 * 72];  // [p][n] carry hi
    __shared__ __align__(16) u16 sLo[64 * 72];  // [p][n] carry lo
    __shared__ __align__(16) u16 sGl[64 * 72];  // [s][r] = G*L
    __shared__ float scl[64], sdt[64];
    size_t row0 = (size_t)b * 2048 + c * 64;

    if (t < 64) {
        float v = ldp[(row0 + t) * 16 + h];
        float dtv = dtp[(row0 + t) * 16 + h];
        #pragma unroll
        for (int o = 1; o < 64; o <<= 1) {
            float u = __shfl_up(v, o);
            if (lane >= o) v += u;
        }
        scl[t] = v;
        sdt[t] = dtv;
    }
    __syncthreads();
    for (int i = t; i < 4096; i += 256) {
        int r = i >> 6, e = i & 63;
        size_t rb = (row0 + r) * 1152;
        sB[r * 72 + e] = xc[rb + 1024 + e];
        sC[r * 72 + e] = xc[rb + 1088 + e];
        sXp[e * 72 + r] = f2bf(bf2f(xc[rb + h * 64 + e]) * sdt[r]);
        float hv = S[(size_t)blk * 4096 + i];
        u16 hi = f2bf(hv);
        sHi[r * 72 + e] = hi;                 // here r==p, e==n
        sLo[r * 72 + e] = f2bf(hv - bf2f(hi));
    }
    __syncthreads();

    // GEMM1: G = C.B^T (rows s, cols r); GEMM3: acc2 = C.Hin (rows s, cols p)
    f32x4 g[4], acc2[4];
    #pragma unroll
    for (int j = 0; j < 4; ++j) { g[j] = (f32x4){0.f,0.f,0.f,0.f}; acc2[j] = (f32x4){0.f,0.f,0.f,0.f}; }
    #pragma unroll
    for (int k0 = 0; k0 < 64; k0 += 32) {
        bf16x8 a = *(const bf16x8*)(sC + (w * 16 + fr) * 72 + k0 + fk);
        #pragma unroll
        for (int j = 0; j < 4; ++j) {
            bf16x8 bb = *(const bf16x8*)(sB + (j * 16 + fr) * 72 + k0 + fk);
            g[j] = __builtin_amdgcn_mfma_f32_16x16x32_bf16(a, bb, g[j], 0, 0, 0);
            bf16x8 bh = *(const bf16x8*)(sHi + (j * 16 + fr) * 72 + k0 + fk);
            acc2[j] = __builtin_amdgcn_mfma_f32_16x16x32_bf16(a, bh, acc2[j], 0, 0, 0);
            bf16x8 bl = *(const bf16x8*)(sLo + (j * 16 + fr) * 72 + k0 + fk);
            acc2[j] = __builtin_amdgcn_mfma_f32_16x16x32_bf16(a, bl, acc2[j], 0, 0, 0);
        }
    }
    // write Gl = G * exp(scl[s]-scl[r]) masked r<=s
    #pragma unroll
    for (int j = 0; j < 4; ++j) {
        int r = j * 16 + fr;
        #pragma unroll
        for (int reg = 0; reg < 4; ++reg) {
            int s = w * 16 + (lane >> 4) * 4 + reg;
            float val = (r <= s) ? expf(scl[s] - scl[r]) * g[j][reg] : 0.f;
            sGl[s * 72 + r] = f2bf(val);
        }
    }
    __syncthreads();

    // GEMM2: acc1 = Gl . Xs (rows s, cols p)
    f32x4 acc1[4];
    #pragma unroll
    for (int j = 0; j < 4; ++j) acc1[j] = (f32x4){0.f, 0.f, 0.f, 0.f};
    #pragma unroll
    for (int k0 = 0; k0 < 64; k0 += 32) {
        bf16x8 a = *(const bf16x8*)(sGl + (w * 16 + fr) * 72 + k0 + fk);
        #pragma unroll
        for (int j = 0; j < 4; ++j) {
            bf16x8 bb = *(const bf16x8*)(sXp + (j * 16 + fr) * 72 + k0 + fk);
            acc1[j] = __builtin_amdgcn_mfma_f32_16x16x32_bf16(a, bb, acc1[j], 0, 0, 0);
        }
    }
    // epilogue: y = acc1 + exp(scl[s])*acc2 + x*Dh
    #pragma unroll
    for (int reg = 0; reg < 4; ++reg) {
        int s = w * 16 + (lane >> 4) * 4 + reg;
        float es = expf(scl[s]);
        size_t yrb = (row0 + s) * 1024 + h * 64;
        size_t xrb = (row0 + s) * 1152 + h * 64;
        #pragma unroll
        for (int j = 0; j < 4; ++j) {
            int p = j * 16 + fr;
            float xv = bf2f(xc[xrb + p]);
            y[yrb + p] = f2bf(acc1[j][reg] + es * acc2[j][reg] + xv * Dh);
        }
    }
}

// ---------------- gated RMS norm ----------------
__global__ __launch_bounds__(256) void k_gnorm(
    const u16* __restrict__ y0, const u16* __restrict__ z0,
    const float* __restrict__ gw0, u16* __restrict__ o0,
    const u16* __restrict__ y1, const u16* __restrict__ z1,
    const float* __restrict__ gw1, u16* __restrict__ o1) {
    __shared__ float red[4];
    int r = blockIdx.x;
    int dir = r >> 12, row = r & 4095;
    int t = threadIdx.x;
    const u16* y = dir ? y1 : y0;
    const u16* zp = dir ? z1 : z0;
    const float* gw = dir ? gw1 : gw0;
    u16* o = dir ? o1 : o0;
    ushort4 yv = *(const ushort4*)(y + (size_t)row * 1024 + t * 4);
    ushort4 zr = *(const ushort4*)(zp + (size_t)row * 1024 + t * 4);
    float z0f = bf2f(zr.x), z1f = bf2f(zr.y), z2f = bf2f(zr.z), z3f = bf2f(zr.w);
    float v0 = bf2f(yv.x) * (z0f / (1.f + expf(-z0f)));
    float v1 = bf2f(yv.y) * (z1f / (1.f + expf(-z1f)));
    float v2 = bf2f(yv.z) * (z2f / (1.f + expf(-z2f)));
    float v3 = bf2f(yv.w) * (z3f / (1.f + expf(-z3f)));
    float ss = block_sum_256(v0 * v0 + v1 * v1 + v2 * v2 + v3 * v3, red);
    float sc = rsqrtf(ss * (1.f / 1024.f) + 1e-5f);
    float4 gv = *(const float4*)(gw + t * 4);
    size_t ob = (size_t)row * 1024 + t * 4;
    o[ob + 0] = f2bf(v0 * sc * gv.x);
    o[ob + 1] = f2bf(v1 * sc * gv.y);
    o[ob + 2] = f2bf(v2 * sc * gv.z);
    o[ob + 3] = f2bf(v3 * sc * gv.w);
}

// ---------------- x2 = x + (fwd + flip(bwd)) * mask (f32 out) ----------------
__global__ void k_add(const float* __restrict__ x, const u16* __restrict__ of,
                      const u16* __restrict__ ob, const float* __restrict__ mask,
                      float* __restrict__ x2) {
    int i = blockIdx.x * 256 + threadIdx.x;  // 4096*512
    int row = i >> 9, d = i & 511;
    int bb = row >> 11, tl = row & 2047;
    size_t fi = (size_t)((bb << 11) + (2047 - tl)) * 512 + d;
    x2[i] = x[i] + (bf2f(of[i]) + bf2f(ob[fi])) * mask[row];
}

// ---------------- rms(x2)*norm_ffn_w -> bf16 ----------------
__global__ __launch_bounds__(256) void k_rms2(const float* __restrict__ x2,
                                              const float* __restrict__ wrms,
                                              u16* __restrict__ o) {
    __shared__ float red[4];
    int row = blockIdx.x, t = threadIdx.x;
    size_t base = (size_t)row * 512 + t * 2;
    float2 v = *(const float2*)(x2 + base);
    float ss = block_sum_256(v.x * v.x + v.y * v.y, red);
    float sc = rsqrtf(ss * (1.f / 512.f) + 1.1920929e-07f);
    float2 wv = *(const float2*)(wrms + t * 2);
    o[base] = f2bf(v.x * sc * wv.x);
    o[base + 1] = f2bf(v.y * sc * wv.y);
}

// ---------------- gelu(v + b1) -> bf16 ----------------
__global__ void k_gelu(const u16* __restrict__ v, const float* __restrict__ b1,
                       u16* __restrict__ o) {
    int i = blockIdx.x * 256 + threadIdx.x;  // 4096*2048
    int c = i & 2047;
    float x = bf2f(v[i]) + b1[c];
    float g = 0.5f * x * (1.f + erff(x * 0.70710678118654752f));
    o[i] = f2bf(g);
}

// ---------------- out = x2 + ffn2 + b2 -> f32 ----------------
__global__ void k_final(const float* __restrict__ x2, const u16* __restrict__ f2,
                        const float* __restrict__ b2, float* __restrict__ out) {
    int i = blockIdx.x * 256 + threadIdx.x;  // 4096*512
    int c = i & 511;
    out[i] = x2[i] + bf2f(f2[i]) + b2[c];
}

extern "C" void kernel_launch(void* const* d_in, const int* in_sizes, int n_in,
                              void* d_out, int out_size, void* d_ws, size_t ws_size,
                              hipStream_t stream) {
    const float* x = (const float*)d_in[0];
    const float* pe = (const float*)d_in[1];
    const float* mask = (const float*)d_in[2];
    const float* nsw = (const float*)d_in[3];
    const float* nfw = (const float*)d_in[4];
    const float* w1 = (const float*)d_in[5];
    const float* b1 = (const float*)d_in[6];
    const float* w2 = (const float*)d_in[7];
    const float* b2 = (const float*)d_in[8];
    const float* f_inw = (const float*)d_in[9];
    const float* f_cw = (const float*)d_in[10];
    const float* f_cb = (const float*)d_in[11];
    const float* f_dtb = (const float*)d_in[12];
    const float* f_al = (const float*)d_in[13];
    const float* f_D = (const float*)d_in[14];
    const float* f_gw = (const float*)d_in[15];
    const float* f_ow = (const float*)d_in[16];
    const float* b_inw = (const float*)d_in[17];
    const float* b_cw = (const float*)d_in[18];
    const float* b_cb = (const float*)d_in[19];
    const float* b_dtb = (const float*)d_in[20];
    const float* b_al = (const float*)d_in[21];
    const float* b_D = (const float*)d_in[22];
    const float* b_gw = (const float*)d_in[23];
    const float* b_ow = (const float*)d_in[24];
    float* out = (float*)d_out;

    char* ws = (char*)d_ws;
    // Activation overlays (liveness-checked), [0, 56,098,816):
    u16* Z0   = (u16*)(ws + 0);
    u16* Z1   = (u16*)(ws + 8388608);
    u16* XB0  = (u16*)(ws + 16777216);
    u16* XB1  = (u16*)(ws + 26476544);
    u16* INWF = (u16*)(ws + 36175872);
    u16* INWB = (u16*)(ws + 38535168);
    u16* SIB  = (u16*)(ws + 40894464);
    u16* XC0  = (u16*)(ws + 36175872);
    u16* XC1  = (u16*)(ws + 45613056);
    float* dtF = (float*)(ws + 55050240);
    float* dAF = (float*)(ws + 55312384);
    float* dtB = (float*)(ws + 55574528);
    float* dAB = (float*)(ws + 55836672);
    u16* Y0   = (u16*)(ws + 16777216);
    u16* Y1   = (u16*)(ws + 25165824);
    u16* YG0  = (u16*)(ws + 36175872);
    u16* YG1  = (u16*)(ws + 44564480);
    u16* OP0  = (u16*)(ws + 0);
    u16* OP1  = (u16*)(ws + 4194304);
    float* X2 = (float*)(ws + 8388608);
    u16* X2B  = (u16*)(ws + 0);
    u16* FFN1 = (u16*)(ws + 36175872);
    u16* HACT = (u16*)(ws + 16777216);
    u16* FFN2 = (u16*)(ws + 4194304);
    // Pinned bf16 weights [56,098,816, 62,390,272):
    u16* OWF = (u16*)(ws + 56098816);
    u16* OWB = (u16*)(ws + 57147392);
    u16* W1B = (u16*)(ws + 58195968);
    u16* W2B = (u16*)(ws + 60293120);
    // Chunked-scan state [62,390,272, 95,952,896):
    float* SBUF = (float*)(ws + 62390272);   // 2048 x 4096 f32 = 32 MB
    float* APR  = (float*)(ws + 95944704);   // 2048 f32

    k_cvt_pad_inw<<<2304 * 512 / 256, 256, 0, stream>>>(f_inw, INWF);
    k_cvt_pad_inw<<<2304 * 512 / 256, 256, 0, stream>>>(b_inw, INWB);
    k_cvt<<<2048, 256, 0, stream>>>(f_ow, OWF, 524288);
    k_cvt<<<2048, 256, 0, stream>>>(b_ow, OWB, 524288);
    k_cvt<<<4096, 256, 0, stream>>>(w1, W1B, 1048576);
    k_cvt<<<4096, 256, 0, stream>>>(w2, W2B, 1048576);
    k_rms_pos<<<4096, 256, 0, stream>>>(x, pe, nsw, SIB);
    k_gemm_in<<<dim3(18, 32, 2), 256, 0, stream>>>(SIB, INWF, INWB, Z0, Z1, XB0, XB1);
    k_conv<<<dim3(5, 8192), 256, 0, stream>>>(XB0, XB1, f_cw, f_cb, f_dtb, f_al,
                                              b_cw, b_cb, b_dtb, b_al,
                                              XC0, XC1, dtF, dAF, dtB, dAB);
    k_ssd_state<<<2048, 256, 0, stream>>>(XC0, dtF, dAF, XC1, dtB, dAB, SBUF, APR);
    k_scan_carry<<<64, 256, 0, stream>>>(SBUF, APR);
    k_ssd_y<<<2048, 256, 0, stream>>>(XC0, dtF, dAF, f_D, Y0,
                                      XC1, dtB, dAB, b_D, Y1, SBUF);
    k_gnorm<<<8192, 256, 0, stream>>>(Y0, Z0, f_gw, YG0, Y1, Z1, b_gw, YG1);
    k_gemm2<<<dim3(4, 32, 2), 256, 0, stream>>>(YG0, YG1, OWF, OWB, OP0, OP1, 512, 1024);
    k_add<<<8192, 256, 0, stream>>>(x, OP0, OP1, mask, X2);
    k_rms2<<<4096, 256, 0, stream>>>(X2, nfw, X2B);
    k_gemm2<<<dim3(16, 32, 1), 256, 0, stream>>>(X2B, X2B, W1B, W1B, FFN1, FFN1, 2048, 512);
    k_gelu<<<32768, 256, 0, stream>>>(FFN1, b1, HACT);
    k_gemm2<<<dim3(4, 32, 1), 256, 0, stream>>>(HACT, HACT, W2B, W2B, FFN2, FFN2, 512, 2048);
    k_final<<<8192, 256, 0, stream>>>(X2, FFN2, b2, out);
}

// Round 9
// 421.382 us; speedup vs baseline: 4.3959x; 1.0160x over previous
//
#include <hip/hip_runtime.h>
#include <hip/hip_bf16.h>

typedef unsigned short u16;
typedef unsigned int u32;
typedef __bf16 bf16x8 __attribute__((ext_vector_type(8)));
typedef float f32x4 __attribute__((ext_vector_type(4)));

typedef __attribute__((address_space(1))) void gvoid_t;
typedef __attribute__((address_space(3))) void lvoid_t;
// async global->LDS 16B copy; LDS dest must be wave-uniform-base + lane*16 (it is:
// lds offset = off16*16 with off16 consecutive per lane).
__device__ __forceinline__ void lds_cp16(void* lds, const void* g) {
    __builtin_amdgcn_global_load_lds((gvoid_t*)g, (lvoid_t*)lds, 16, 0, 0);
}

__device__ __forceinline__ float bf2f(u16 v) {
    u32 x = (u32)v << 16;
    return __builtin_bit_cast(float, x);
}
__device__ __forceinline__ u16 f2bf(float f) {
    return __builtin_bit_cast(u16, (__bf16)f);
}

// ---------------- block reduction (256 threads = 4 waves) ----------------
__device__ __forceinline__ float block_sum_256(float v, float* red) {
    #pragma unroll
    for (int o = 32; o > 0; o >>= 1) v += __shfl_xor(v, o);
    int w = threadIdx.x >> 6;
    if ((threadIdx.x & 63) == 0) red[w] = v;
    __syncthreads();
    return red[0] + red[1] + red[2] + red[3];
}

// ---------------- f32 -> bf16 conversions ----------------
__global__ void k_cvt(const float* __restrict__ s, u16* __restrict__ d, int n) {
    int i = blockIdx.x * 256 + threadIdx.x;
    if (i < n) d[i] = f2bf(s[i]);
}

__global__ void k_cvt_pad_inw(const float* __restrict__ s, u16* __restrict__ d) {
    int i = blockIdx.x * 256 + threadIdx.x;  // < 2304*512
    int n = i >> 9;
    d[i] = (n < 2192) ? f2bf(s[i]) : (u16)0;
}

// ---------------- si = rms(x)*w + pos_emb -> bf16 ----------------
__global__ __launch_bounds__(256) void k_rms_pos(const float* __restrict__ x,
                                                 const float* __restrict__ pe,
                                                 const float* __restrict__ wrms,
                                                 u16* __restrict__ sib) {
    __shared__ float red[4];
    int row = blockIdx.x, t = threadIdx.x;
    size_t base = (size_t)row * 512 + t * 2;
    float2 xv = *(const float2*)(x + base);
    float ss = block_sum_256(xv.x * xv.x + xv.y * xv.y, red);
    float sc = rsqrtf(ss * (1.f / 512.f) + 1.1920929e-07f);
    float2 pv = *(const float2*)(pe + base);
    float2 wv = *(const float2*)(wrms + t * 2);
    sib[base] = f2bf(xv.x * sc * wv.x + pv.x);
    sib[base + 1] = f2bf(xv.y * sc * wv.y + pv.y);
}

// ---------------- in_proj GEMM with split epilogue (async LDS staging) ----------------
__global__ __launch_bounds__(256) void k_gemm_in(
    const u16* __restrict__ A, const u16* __restrict__ W0, const u16* __restrict__ W1,
    u16* __restrict__ Z0, u16* __restrict__ Z1,
    u16* __restrict__ XB0, u16* __restrict__ XB1) {
    const int z = blockIdx.z;
    const u16* W = z ? W1 : W0;
    u16* Z = z ? Z1 : Z0;
    u16* XB = z ? XB1 : XB0;
    const int K = 512;

    __shared__ __align__(16) u16 As[128 * 32];
    __shared__ __align__(16) u16 Bs[128 * 32];

    const int t = threadIdx.x;
    const int lane = t & 63;
    const int w = t >> 6;
    const int m0 = blockIdx.y * 128;
    const int n0 = blockIdx.x * 128;
    const int wm = (w >> 1) * 64;
    const int wn = (w & 1) * 64;
    const int fr = lane & 15;
    const int fk = (lane >> 4) * 8;

    f32x4 acc[4][4];
    #pragma unroll
    for (int i = 0; i < 4; ++i)
        #pragma unroll
        for (int j = 0; j < 4; ++j) acc[i][j] = (f32x4){0.f, 0.f, 0.f, 0.f};

    for (int kt = 0; kt < K; kt += 32) {
        #pragma unroll
        for (int j = 0; j < 2; ++j) {
            int off16 = j * 256 + t;
            int row = off16 >> 2;
            int kc = (off16 & 3) * 8;
            int gm = m0 + row;
            if (z) gm = (gm & ~2047) | (2047 - (gm & 2047));
            lds_cp16(As + off16 * 8, A + (size_t)gm * K + kt + kc);
            lds_cp16(Bs + off16 * 8, W + (size_t)(n0 + row) * K + kt + kc);
        }
        __syncthreads();
        bf16x8 af[4], bfr[4];
        #pragma unroll
        for (int i = 0; i < 4; ++i) af[i] = *(const bf16x8*)(As + (wm + i * 16 + fr) * 32 + fk);
        #pragma unroll
        for (int i = 0; i < 4; ++i) bfr[i] = *(const bf16x8*)(Bs + (wn + i * 16 + fr) * 32 + fk);
        #pragma unroll
        for (int i = 0; i < 4; ++i)
            #pragma unroll
            for (int j = 0; j < 4; ++j)
                acc[i][j] = __builtin_amdgcn_mfma_f32_16x16x32_bf16(af[i], bfr[j], acc[i][j], 0, 0, 0);
        __syncthreads();
    }
    #pragma unroll
    for (int i = 0; i < 4; ++i) {
        int rbase = m0 + wm + i * 16 + (lane >> 4) * 4;
        #pragma unroll
        for (int j = 0; j < 4; ++j) {
            int c = n0 + wn + j * 16 + fr;
            #pragma unroll
            for (int r = 0; r < 4; ++r) {
                u16 v = f2bf(acc[i][j][r]);
                int m = rbase + r;
                if (c < 1024) Z[(size_t)m * 1024 + c] = v;
                else if (c < 2192) XB[(size_t)m * 1184 + (c - 1024)] = v;
            }
        }
    }
}

// ---------------- generic bf16 GEMM (async LDS staging) ----------------
__global__ __launch_bounds__(256) void k_gemm2(
    const u16* __restrict__ A0, const u16* __restrict__ A1,
    const u16* __restrict__ W0, const u16* __restrict__ W1,
    u16* __restrict__ C0, u16* __restrict__ C1, int N, int K) {
    const int z = blockIdx.z;
    const u16* A = z ? A1 : A0;
    const u16* W = z ? W1 : W0;
    u16* C = z ? C1 : C0;

    __shared__ __align__(16) u16 As[128 * 32];
    __shared__ __align__(16) u16 Bs[128 * 32];

    const int t = threadIdx.x;
    const int lane = t & 63;
    const int w = t >> 6;
    const int m0 = blockIdx.y * 128;
    const int n0 = blockIdx.x * 128;
    const int wm = (w >> 1) * 64;
    const int wn = (w & 1) * 64;
    const int fr = lane & 15;
    const int fk = (lane >> 4) * 8;

    f32x4 acc[4][4];
    #pragma unroll
    for (int i = 0; i < 4; ++i)
        #pragma unroll
        for (int j = 0; j < 4; ++j) acc[i][j] = (f32x4){0.f, 0.f, 0.f, 0.f};

    for (int kt = 0; kt < K; kt += 32) {
        #pragma unroll
        for (int j = 0; j < 2; ++j) {
            int off16 = j * 256 + t;
            int row = off16 >> 2;
            int kc = (off16 & 3) * 8;
            lds_cp16(As + off16 * 8, A + (size_t)(m0 + row) * K + kt + kc);
            lds_cp16(Bs + off16 * 8, W + (size_t)(n0 + row) * K + kt + kc);
        }
        __syncthreads();
        bf16x8 af[4], bfr[4];
        #pragma unroll
        for (int i = 0; i < 4; ++i) af[i] = *(const bf16x8*)(As + (wm + i * 16 + fr) * 32 + fk);
        #pragma unroll
        for (int i = 0; i < 4; ++i) bfr[i] = *(const bf16x8*)(Bs + (wn + i * 16 + fr) * 32 + fk);
        #pragma unroll
        for (int i = 0; i < 4; ++i)
            #pragma unroll
            for (int j = 0; j < 4; ++j)
                acc[i][j] = __builtin_amdgcn_mfma_f32_16x16x32_bf16(af[i], bfr[j], acc[i][j], 0, 0, 0);
        __syncthreads();
    }
    #pragma unroll
    for (int i = 0; i < 4; ++i) {
        int rbase = m0 + wm + i * 16 + (lane >> 4) * 4;
        #pragma unroll
        for (int j = 0; j < 4; ++j) {
            int col = n0 + wn + j * 16 + fr;
            #pragma unroll
            for (int r = 0; r < 4; ++r)
                C[(size_t)(rbase + r) * N + col] = f2bf(acc[i][j][r]);
        }
    }
}

// ---------------- causal conv4 + silu, 8-wide vectorized; softplus dt; LOG-decay ----------------
// grid 8192 (dir*4096+row), block 192: t<144 -> 8 channels each; t in [144,160) -> dt head.
__global__ __launch_bounds__(192) void k_conv(
    const u16* __restrict__ xb0, const u16* __restrict__ xb1,
    const float* __restrict__ cw0, const float* __restrict__ cb0,
    const float* __restrict__ dtb0, const float* __restrict__ al0,
    const float* __restrict__ cw1, const float* __restrict__ cb1,
    const float* __restrict__ dtb1, const float* __restrict__ al1,
    u16* __restrict__ xc0, u16* __restrict__ xc1,
    float* __restrict__ dtO0, float* __restrict__ dAO0,
    float* __restrict__ dtO1, float* __restrict__ dAO1) {
    int r = blockIdx.x;
    int dir = r >> 12, row = r & 4095;
    const u16* xb = dir ? xb1 : xb0;
    const float* cw = dir ? cw1 : cw0;
    const float* cb = dir ? cb1 : cb0;
    const float* dtb = dir ? dtb1 : dtb0;
    const float* al = dir ? al1 : al0;
    u16* xc = dir ? xc1 : xc0;
    float* dtO = dir ? dtO1 : dtO0;
    float* dAO = dir ? dAO1 : dAO0;
    int bb = row >> 11, tl = row & 2047;
    int t = threadIdx.x;
    if (t < 144) {
        int col = t * 8;
        float cwa[8][4];
        #pragma unroll
        for (int j = 0; j < 8; ++j) {
            float4 c4 = *(const float4*)(cw + (col + j) * 4);
            cwa[j][0] = c4.x; cwa[j][1] = c4.y; cwa[j][2] = c4.z; cwa[j][3] = c4.w;
        }
        float acc[8];
        float4 cb0v = *(const float4*)(cb + col);
        float4 cb1v = *(const float4*)(cb + col + 4);
        acc[0] = cb0v.x; acc[1] = cb0v.y; acc[2] = cb0v.z; acc[3] = cb0v.w;
        acc[4] = cb1v.x; acc[5] = cb1v.y; acc[6] = cb1v.z; acc[7] = cb1v.w;
        #pragma unroll
        for (int i = 0; i < 4; ++i) {
            int tt = tl + i - 3;
            if (tt >= 0) {
                uint4 xv = *(const uint4*)(xb + (size_t)((bb << 11) + tt) * 1184 + col);
                const u16* xs = (const u16*)&xv;
                #pragma unroll
                for (int j = 0; j < 8; ++j) acc[j] += bf2f(xs[j]) * cwa[j][i];
            }
        }
        u16 ov[8];
        #pragma unroll
        for (int j = 0; j < 8; ++j) {
            float a = acc[j];
            ov[j] = f2bf(a / (1.f + expf(-a)));
        }
        *(uint4*)(xc + (size_t)row * 1152 + col) = *(const uint4*)ov;
    } else if (t < 160) {
        int hh = t - 144;
        float v = bf2f(xb[(size_t)row * 1184 + 1152 + hh]) + dtb[hh];
        float sp = (v > 20.f) ? v : log1pf(expf(v));  // softplus
        dtO[row * 16 + hh] = sp;
        dAO[row * 16 + hh] = -expf(al[hh]) * sp;      // LOG decay
    }
}

// ======== SSD chunked scan: L=2048 -> 32 chunks of 64, all-MFMA ========
// blk = (((dir*2+b)*16+h)*32 + c). S layout: S[blk][p*64+n] (f32).

// ---- Pass A: S_local[n][p] ----
__global__ __launch_bounds__(256) void k_ssd_state(
    const u16* __restrict__ xc0, const float* __restrict__ dt0, const float* __restrict__ ld0,
    const u16* __restrict__ xc1, const float* __restrict__ dt1, const float* __restrict__ ld1,
    float* __restrict__ S, float* __restrict__ Aprod) {
    int blk = blockIdx.x;
    int c = blk & 31, h = (blk >> 5) & 15, b = (blk >> 9) & 1, dir = blk >> 10;
    const u16* xc = dir ? xc1 : xc0;
    const float* dtp = dir ? dt1 : dt0;
    const float* ldp = dir ? ld1 : ld0;
    const int t = threadIdx.x, w = t >> 6, lane = t & 63;
    const int fr = lane & 15, fk = (lane >> 4) * 8;

    __shared__ __align__(16) u16 sBt[64 * 72];  // B^T: [n][r]
    __shared__ __align__(16) u16 sXp[64 * 72];  // X~ : [p][r]
    __shared__ float ssc[64];
    size_t row0 = (size_t)b * 2048 + c * 64;

    if (t < 64) {
        float v = ldp[(row0 + t) * 16 + h];
        float dtv = dtp[(row0 + t) * 16 + h];
        #pragma unroll
        for (int o = 1; o < 64; o <<= 1) {
            float u = __shfl_up(v, o);
            if (lane >= o) v += u;
        }
        float last = __shfl(v, 63);
        ssc[t] = dtv * expf(last - v);
        if (t == 63) Aprod[blk] = expf(v);
    }
    __syncthreads();
    for (int i = t; i < 4096; i += 256) {
        int r = i >> 6, e = i & 63;
        size_t rb = (row0 + r) * 1152;
        sBt[e * 72 + r] = xc[rb + 1024 + e];
        sXp[e * 72 + r] = f2bf(bf2f(xc[rb + h * 64 + e]) * ssc[r]);
    }
    __syncthreads();

    f32x4 acc[4];
    #pragma unroll
    for (int j = 0; j < 4; ++j) acc[j] = (f32x4){0.f, 0.f, 0.f, 0.f};
    #pragma unroll
    for (int k0 = 0; k0 < 64; k0 += 32) {
        bf16x8 a = *(const bf16x8*)(sBt + (w * 16 + fr) * 72 + k0 + fk);
        #pragma unroll
        for (int j = 0; j < 4; ++j) {
            bf16x8 bb = *(const bf16x8*)(sXp + (j * 16 + fr) * 72 + k0 + fk);
            acc[j] = __builtin_amdgcn_mfma_f32_16x16x32_bf16(a, bb, acc[j], 0, 0, 0);
        }
    }
    float* Sb = S + (size_t)blk * 4096;
    int nb = w * 16 + (lane >> 4) * 4;
    #pragma unroll
    for (int j = 0; j < 4; ++j) {
        int p = j * 16 + fr;
        *(f32x4*)(Sb + p * 64 + nb) = acc[j];
    }
}

// ---- Pass B: 64 blocks; in-place S_c -> carry-in H_c ----
__global__ __launch_bounds__(256) void k_scan_carry(float* __restrict__ S,
                                                    const float* __restrict__ Aprod) {
    int blk = blockIdx.x;
    int t = threadIdx.x;
    float h[16];
    #pragma unroll
    for (int j = 0; j < 16; ++j) h[j] = 0.f;
    for (int c = 0; c < 32; ++c) {
        float a = Aprod[blk * 32 + c];
        float* Sp = S + ((size_t)blk * 32 + c) * 4096 + t * 16;
        float4 s0 = *(float4*)(Sp + 0), s1 = *(float4*)(Sp + 4);
        float4 s2 = *(float4*)(Sp + 8), s3 = *(float4*)(Sp + 12);
        *(float4*)(Sp + 0) = make_float4(h[0], h[1], h[2], h[3]);
        *(float4*)(Sp + 4) = make_float4(h[4], h[5], h[6], h[7]);
        *(float4*)(Sp + 8) = make_float4(h[8], h[9], h[10], h[11]);
        *(float4*)(Sp + 12) = make_float4(h[12], h[13], h[14], h[15]);
        h[0] = a * h[0] + s0.x; h[1] = a * h[1] + s0.y; h[2] = a * h[2] + s0.z; h[3] = a * h[3] + s0.w;
        h[4] = a * h[4] + s1.x; h[5] = a * h[5] + s1.y; h[6] = a * h[6] + s1.z; h[7] = a * h[7] + s1.w;
        h[8] = a * h[8] + s2.x; h[9] = a * h[9] + s2.y; h[10] = a * h[10] + s2.z; h[11] = a * h[11] + s2.w;
        h[12] = a * h[12] + s3.x; h[13] = a * h[13] + s3.y; h[14] = a * h[14] + s3.z; h[15] = a * h[15] + s3.w;
    }
}

// ---- Pass C: y = (G.L)(x*dt) + exp(acum)*C*Hin + x*D via 3 MFMA GEMMs ----
__global__ __launch_bounds__(256) void k_ssd_y(
    const u16* __restrict__ xc0, const float* __restrict__ dt0, const float* __restrict__ ld0,
    const float* __restrict__ Dv0, u16* __restrict__ y0,
    const u16* __restrict__ xc1, const float* __restrict__ dt1, const float* __restrict__ ld1,
    const float* __restrict__ Dv1, u16* __restrict__ y1,
    const float* __restrict__ S) {
    int blk = blockIdx.x;
    int c = blk & 31, h = (blk >> 5) & 15, b = (blk >> 9) & 1, dir = blk >> 10;
    const u16* xc = dir ? xc1 : xc0;
    const float* dtp = dir ? dt1 : dt0;
    const float* ldp = dir ? ld1 : ld0;
    u16* y = dir ? y1 : y0;
    const float Dh = (dir ? Dv1 : Dv0)[h];
    const int t = threadIdx.x, w = t >> 6, lane = t & 63;
    const int fr = lane & 15, fk = (lane >> 4) * 8;

    __shared__ __align__(16) u16 sB[64 * 72];   // [r][n]
    __shared__ __align__(16) u16 sC[64 * 72];   // [s][n]
    __shared__ __align__(16) u16 sXp[64 * 72];  // [p][r] = x[r][p]*dt[r]
    __shared__ __align__(16) u16 sHi[64 * 72];  // [p][n] carry hi
    __shared__ __align__(16) u16 sLo[64 * 72];  // [p][n] carry lo
    __shared__ __align__(16) u16 sGl[64 * 72];  // [s][r] = G*L
    __shared__ float scl[64], sdt[64];
    size_t row0 = (size_t)b * 2048 + c * 64;

    if (t < 64) {
        float v = ldp[(row0 + t) * 16 + h];
        float dtv = dtp[(row0 + t) * 16 + h];
        #pragma unroll
        for (int o = 1; o < 64; o <<= 1) {
            float u = __shfl_up(v, o);
            if (lane >= o) v += u;
        }
        scl[t] = v;
        sdt[t] = dtv;
    }
    __syncthreads();
    for (int i = t; i < 4096; i += 256) {
        int r = i >> 6, e = i & 63;
        size_t rb = (row0 + r) * 1152;
        sB[r * 72 + e] = xc[rb + 1024 + e];
        sC[r * 72 + e] = xc[rb + 1088 + e];
        sXp[e * 72 + r] = f2bf(bf2f(xc[rb + h * 64 + e]) * sdt[r]);
        float hv = S[(size_t)blk * 4096 + i];
        u16 hi = f2bf(hv);
        sHi[r * 72 + e] = hi;                 // here r==p, e==n
        sLo[r * 72 + e] = f2bf(hv - bf2f(hi));
    }
    __syncthreads();

    f32x4 g[4], acc2[4];
    #pragma unroll
    for (int j = 0; j < 4; ++j) { g[j] = (f32x4){0.f,0.f,0.f,0.f}; acc2[j] = (f32x4){0.f,0.f,0.f,0.f}; }
    #pragma unroll
    for (int k0 = 0; k0 < 64; k0 += 32) {
        bf16x8 a = *(const bf16x8*)(sC + (w * 16 + fr) * 72 + k0 + fk);
        #pragma unroll
        for (int j = 0; j < 4; ++j) {
            bf16x8 bb = *(const bf16x8*)(sB + (j * 16 + fr) * 72 + k0 + fk);
            g[j] = __builtin_amdgcn_mfma_f32_16x16x32_bf16(a, bb, g[j], 0, 0, 0);
            bf16x8 bh = *(const bf16x8*)(sHi + (j * 16 + fr) * 72 + k0 + fk);
            acc2[j] = __builtin_amdgcn_mfma_f32_16x16x32_bf16(a, bh, acc2[j], 0, 0, 0);
            bf16x8 bl = *(const bf16x8*)(sLo + (j * 16 + fr) * 72 + k0 + fk);
            acc2[j] = __builtin_amdgcn_mfma_f32_16x16x32_bf16(a, bl, acc2[j], 0, 0, 0);
        }
    }
    #pragma unroll
    for (int j = 0; j < 4; ++j) {
        int r = j * 16 + fr;
        #pragma unroll
        for (int reg = 0; reg < 4; ++reg) {
            int s = w * 16 + (lane >> 4) * 4 + reg;
            float val = (r <= s) ? expf(scl[s] - scl[r]) * g[j][reg] : 0.f;
            sGl[s * 72 + r] = f2bf(val);
        }
    }
    __syncthreads();

    f32x4 acc1[4];
    #pragma unroll
    for (int j = 0; j < 4; ++j) acc1[j] = (f32x4){0.f, 0.f, 0.f, 0.f};
    #pragma unroll
    for (int k0 = 0; k0 < 64; k0 += 32) {
        bf16x8 a = *(const bf16x8*)(sGl + (w * 16 + fr) * 72 + k0 + fk);
        #pragma unroll
        for (int j = 0; j < 4; ++j) {
            bf16x8 bb = *(const bf16x8*)(sXp + (j * 16 + fr) * 72 + k0 + fk);
            acc1[j] = __builtin_amdgcn_mfma_f32_16x16x32_bf16(a, bb, acc1[j], 0, 0, 0);
        }
    }
    #pragma unroll
    for (int reg = 0; reg < 4; ++reg) {
        int s = w * 16 + (lane >> 4) * 4 + reg;
        float es = expf(scl[s]);
        size_t yrb = (row0 + s) * 1024 + h * 64;
        size_t xrb = (row0 + s) * 1152 + h * 64;
        #pragma unroll
        for (int j = 0; j < 4; ++j) {
            int p = j * 16 + fr;
            float xv = bf2f(xc[xrb + p]);
            y[yrb + p] = f2bf(acc1[j][reg] + es * acc2[j][reg] + xv * Dh);
        }
    }
}

// ---------------- gated RMS norm ----------------
__global__ __launch_bounds__(256) void k_gnorm(
    const u16* __restrict__ y0, const u16* __restrict__ z0,
    const float* __restrict__ gw0, u16* __restrict__ o0,
    const u16* __restrict__ y1, const u16* __restrict__ z1,
    const float* __restrict__ gw1, u16* __restrict__ o1) {
    __shared__ float red[4];
    int r = blockIdx.x;
    int dir = r >> 12, row = r & 4095;
    int t = threadIdx.x;
    const u16* y = dir ? y1 : y0;
    const u16* zp = dir ? z1 : z0;
    const float* gw = dir ? gw1 : gw0;
    u16* o = dir ? o1 : o0;
    ushort4 yv = *(const ushort4*)(y + (size_t)row * 1024 + t * 4);
    ushort4 zr = *(const ushort4*)(zp + (size_t)row * 1024 + t * 4);
    float z0f = bf2f(zr.x), z1f = bf2f(zr.y), z2f = bf2f(zr.z), z3f = bf2f(zr.w);
    float v0 = bf2f(yv.x) * (z0f / (1.f + expf(-z0f)));
    float v1 = bf2f(yv.y) * (z1f / (1.f + expf(-z1f)));
    float v2 = bf2f(yv.z) * (z2f / (1.f + expf(-z2f)));
    float v3 = bf2f(yv.w) * (z3f / (1.f + expf(-z3f)));
    float ss = block_sum_256(v0 * v0 + v1 * v1 + v2 * v2 + v3 * v3, red);
    float sc = rsqrtf(ss * (1.f / 1024.f) + 1e-5f);
    float4 gv = *(const float4*)(gw + t * 4);
    size_t ob = (size_t)row * 1024 + t * 4;
    o[ob + 0] = f2bf(v0 * sc * gv.x);
    o[ob + 1] = f2bf(v1 * sc * gv.y);
    o[ob + 2] = f2bf(v2 * sc * gv.z);
    o[ob + 3] = f2bf(v3 * sc * gv.w);
}

// ---------------- x2 = x + (fwd + flip(bwd)) * mask (f32 out) ----------------
__global__ void k_add(const float* __restrict__ x, const u16* __restrict__ of,
                      const u16* __restrict__ ob, const float* __restrict__ mask,
                      float* __restrict__ x2) {
    int i = blockIdx.x * 256 + threadIdx.x;  // 4096*512
    int row = i >> 9, d = i & 511;
    int bb = row >> 11, tl = row & 2047;
    size_t fi = (size_t)((bb << 11) + (2047 - tl)) * 512 + d;
    x2[i] = x[i] + (bf2f(of[i]) + bf2f(ob[fi])) * mask[row];
}

// ---------------- rms(x2)*norm_ffn_w -> bf16 ----------------
__global__ __launch_bounds__(256) void k_rms2(const float* __restrict__ x2,
                                              const float* __restrict__ wrms,
                                              u16* __restrict__ o) {
    __shared__ float red[4];
    int row = blockIdx.x, t = threadIdx.x;
    size_t base = (size_t)row * 512 + t * 2;
    float2 v = *(const float2*)(x2 + base);
    float ss = block_sum_256(v.x * v.x + v.y * v.y, red);
    float sc = rsqrtf(ss * (1.f / 512.f) + 1.1920929e-07f);
    float2 wv = *(const float2*)(wrms + t * 2);
    o[base] = f2bf(v.x * sc * wv.x);
    o[base + 1] = f2bf(v.y * sc * wv.y);
}

// ---------------- gelu(v + b1) -> bf16 ----------------
__global__ void k_gelu(const u16* __restrict__ v, const float* __restrict__ b1,
                       u16* __restrict__ o) {
    int i = blockIdx.x * 256 + threadIdx.x;  // 4096*2048
    int c = i & 2047;
    float x = bf2f(v[i]) + b1[c];
    float g = 0.5f * x * (1.f + erff(x * 0.70710678118654752f));
    o[i] = f2bf(g);
}

// ---------------- out = x2 + ffn2 + b2 -> f32 ----------------
__global__ void k_final(const float* __restrict__ x2, const u16* __restrict__ f2,
                        const float* __restrict__ b2, float* __restrict__ out) {
    int i = blockIdx.x * 256 + threadIdx.x;  // 4096*512
    int c = i & 511;
    out[i] = x2[i] + bf2f(f2[i]) + b2[c];
}

extern "C" void kernel_launch(void* const* d_in, const int* in_sizes, int n_in,
                              void* d_out, int out_size, void* d_ws, size_t ws_size,
                              hipStream_t stream) {
    const float* x = (const float*)d_in[0];
    const float* pe = (const float*)d_in[1];
    const float* mask = (const float*)d_in[2];
    const float* nsw = (const float*)d_in[3];
    const float* nfw = (const float*)d_in[4];
    const float* w1 = (const float*)d_in[5];
    const float* b1 = (const float*)d_in[6];
    const float* w2 = (const float*)d_in[7];
    const float* b2 = (const float*)d_in[8];
    const float* f_inw = (const float*)d_in[9];
    const float* f_cw = (const float*)d_in[10];
    const float* f_cb = (const float*)d_in[11];
    const float* f_dtb = (const float*)d_in[12];
    const float* f_al = (const float*)d_in[13];
    const float* f_D = (const float*)d_in[14];
    const float* f_gw = (const float*)d_in[15];
    const float* f_ow = (const float*)d_in[16];
    const float* b_inw = (const float*)d_in[17];
    const float* b_cw = (const float*)d_in[18];
    const float* b_cb = (const float*)d_in[19];
    const float* b_dtb = (const float*)d_in[20];
    const float* b_al = (const float*)d_in[21];
    const float* b_D = (const float*)d_in[22];
    const float* b_gw = (const float*)d_in[23];
    const float* b_ow = (const float*)d_in[24];
    float* out = (float*)d_out;

    char* ws = (char*)d_ws;
    // Activation overlays (liveness-checked), [0, 56,098,816):
    u16* Z0   = (u16*)(ws + 0);
    u16* Z1   = (u16*)(ws + 8388608);
    u16* XB0  = (u16*)(ws + 16777216);
    u16* XB1  = (u16*)(ws + 26476544);
    u16* INWF = (u16*)(ws + 36175872);
    u16* INWB = (u16*)(ws + 38535168);
    u16* SIB  = (u16*)(ws + 40894464);
    u16* XC0  = (u16*)(ws + 36175872);
    u16* XC1  = (u16*)(ws + 45613056);
    float* dtF = (float*)(ws + 55050240);
    float* dAF = (float*)(ws + 55312384);
    float* dtB = (float*)(ws + 55574528);
    float* dAB = (float*)(ws + 55836672);
    u16* Y0   = (u16*)(ws + 16777216);
    u16* Y1   = (u16*)(ws + 25165824);
    u16* YG0  = (u16*)(ws + 36175872);
    u16* YG1  = (u16*)(ws + 44564480);
    u16* OP0  = (u16*)(ws + 0);
    u16* OP1  = (u16*)(ws + 4194304);
    float* X2 = (float*)(ws + 8388608);
    u16* X2B  = (u16*)(ws + 0);
    u16* FFN1 = (u16*)(ws + 36175872);
    u16* HACT = (u16*)(ws + 16777216);
    u16* FFN2 = (u16*)(ws + 4194304);
    // Pinned bf16 weights [56,098,816, 62,390,272):
    u16* OWF = (u16*)(ws + 56098816);
    u16* OWB = (u16*)(ws + 57147392);
    u16* W1B = (u16*)(ws + 58195968);
    u16* W2B = (u16*)(ws + 60293120);
    // Chunked-scan state [62,390,272, 95,952,896):
    float* SBUF = (float*)(ws + 62390272);   // 2048 x 4096 f32 = 32 MB
    float* APR  = (float*)(ws + 95944704);   // 2048 f32

    k_cvt_pad_inw<<<2304 * 512 / 256, 256, 0, stream>>>(f_inw, INWF);
    k_cvt_pad_inw<<<2304 * 512 / 256, 256, 0, stream>>>(b_inw, INWB);
    k_cvt<<<2048, 256, 0, stream>>>(f_ow, OWF, 524288);
    k_cvt<<<2048, 256, 0, stream>>>(b_ow, OWB, 524288);
    k_cvt<<<4096, 256, 0, stream>>>(w1, W1B, 1048576);
    k_cvt<<<4096, 256, 0, stream>>>(w2, W2B, 1048576);
    k_rms_pos<<<4096, 256, 0, stream>>>(x, pe, nsw, SIB);
    k_gemm_in<<<dim3(18, 32, 2), 256, 0, stream>>>(SIB, INWF, INWB, Z0, Z1, XB0, XB1);
    k_conv<<<8192, 192, 0, stream>>>(XB0, XB1, f_cw, f_cb, f_dtb, f_al,
                                     b_cw, b_cb, b_dtb, b_al,
                                     XC0, XC1, dtF, dAF, dtB, dAB);
    k_ssd_state<<<2048, 256, 0, stream>>>(XC0, dtF, dAF, XC1, dtB, dAB, SBUF, APR);
    k_scan_carry<<<64, 256, 0, stream>>>(SBUF, APR);
    k_ssd_y<<<2048, 256, 0, stream>>>(XC0, dtF, dAF, f_D, Y0,
                                      XC1, dtB, dAB, b_D, Y1, SBUF);
    k_gnorm<<<8192, 256, 0, stream>>>(Y0, Z0, f_gw, YG0, Y1, Z1, b_gw, YG1);
    k_gemm2<<<dim3(4, 32, 2), 256, 0, stream>>>(YG0, YG1, OWF, OWB, OP0, OP1, 512, 1024);
    k_add<<<8192, 256, 0, stream>>>(x, OP0, OP1, mask, X2);
    k_rms2<<<4096, 256, 0, stream>>>(X2, nfw, X2B);
    k_gemm2<<<dim3(16, 32, 1), 256, 0, stream>>>(X2B, X2B, W1B, W1B, FFN1, FFN1, 2048, 512);
    k_gelu<<<32768, 256, 0, stream>>>(FFN1, b1, HACT);
    k_gemm2<<<dim3(4, 32, 1), 256, 0, stream>>>(HACT, HACT, W2B, W2B, FFN2, FFN2, 512, 2048);
    k_final<<<8192, 256, 0, stream>>>(X2, FFN2, b2, out);
}

// Round 10
// 369.552 us; speedup vs baseline: 5.0124x; 1.1403x over previous
//
#include <hip/hip_runtime.h>
#include <hip/hip_bf16.h>

typedef unsigned short u16;
typedef unsigned int u32;
typedef __bf16 bf16x8 __attribute__((ext_vector_type(8)));
typedef float f32x4 __attribute__((ext_vector_type(4)));

typedef __attribute__((address_space(1))) void gvoid_t;
typedef __attribute__((address_space(3))) void lvoid_t;
__device__ __forceinline__ void lds_cp16(void* lds, const void* g) {
    __builtin_amdgcn_global_load_lds((gvoid_t*)g, (lvoid_t*)lds, 16, 0, 0);
}

__device__ __forceinline__ float bf2f(u16 v) {
    u32 x = (u32)v << 16;
    return __builtin_bit_cast(float, x);
}
__device__ __forceinline__ u16 f2bf(float f) {
    return __builtin_bit_cast(u16, (__bf16)f);
}

// ---------------- block reduction (256 threads = 4 waves) ----------------
__device__ __forceinline__ float block_sum_256(float v, float* red) {
    #pragma unroll
    for (int o = 32; o > 0; o >>= 1) v += __shfl_xor(v, o);
    int w = threadIdx.x >> 6;
    if ((threadIdx.x & 63) == 0) red[w] = v;
    __syncthreads();
    return red[0] + red[1] + red[2] + red[3];
}

// ---------------- all weight conversions in one kernel ----------------
__global__ void k_cvt_all(const float* __restrict__ f_inw, const float* __restrict__ b_inw,
                          const float* __restrict__ f_ow, const float* __restrict__ b_ow,
                          const float* __restrict__ w1, const float* __restrict__ w2,
                          u16* __restrict__ INWF, u16* __restrict__ INWB,
                          u16* __restrict__ OWF, u16* __restrict__ OWB,
                          u16* __restrict__ W1B, u16* __restrict__ W2B) {
    int i = blockIdx.x * 256 + threadIdx.x;
    if (i < 1179648) { int n = i >> 9; INWF[i] = (n < 2192) ? f2bf(f_inw[i]) : (u16)0; return; }
    i -= 1179648;
    if (i < 1179648) { int n = i >> 9; INWB[i] = (n < 2192) ? f2bf(b_inw[i]) : (u16)0; return; }
    i -= 1179648;
    if (i < 524288) { OWF[i] = f2bf(f_ow[i]); return; }
    i -= 524288;
    if (i < 524288) { OWB[i] = f2bf(b_ow[i]); return; }
    i -= 524288;
    if (i < 1048576) { W1B[i] = f2bf(w1[i]); return; }
    i -= 1048576;
    if (i < 1048576) W2B[i] = f2bf(w2[i]);
}

// ---------------- si = rms(x)*w + pos_emb -> bf16 ----------------
__global__ __launch_bounds__(256) void k_rms_pos(const float* __restrict__ x,
                                                 const float* __restrict__ pe,
                                                 const float* __restrict__ wrms,
                                                 u16* __restrict__ sib) {
    __shared__ float red[4];
    int row = blockIdx.x, t = threadIdx.x;
    size_t base = (size_t)row * 512 + t * 2;
    float2 xv = *(const float2*)(x + base);
    float ss = block_sum_256(xv.x * xv.x + xv.y * xv.y, red);
    float sc = rsqrtf(ss * (1.f / 512.f) + 1.1920929e-07f);
    float2 pv = *(const float2*)(pe + base);
    float2 wv = *(const float2*)(wrms + t * 2);
    sib[base] = f2bf(xv.x * sc * wv.x + pv.x);
    sib[base + 1] = f2bf(xv.y * sc * wv.y + pv.y);
}

// ---------------- in_proj GEMM with split epilogue (async LDS staging) ----------------
__global__ __launch_bounds__(256) void k_gemm_in(
    const u16* __restrict__ A, const u16* __restrict__ W0, const u16* __restrict__ W1,
    u16* __restrict__ Z0, u16* __restrict__ Z1,
    u16* __restrict__ XB0, u16* __restrict__ XB1) {
    const int z = blockIdx.z;
    const u16* W = z ? W1 : W0;
    u16* Z = z ? Z1 : Z0;
    u16* XB = z ? XB1 : XB0;
    const int K = 512;

    __shared__ __align__(16) u16 As[128 * 32];
    __shared__ __align__(16) u16 Bs[128 * 32];

    const int t = threadIdx.x;
    const int lane = t & 63;
    const int w = t >> 6;
    const int m0 = blockIdx.y * 128;
    const int n0 = blockIdx.x * 128;
    const int wm = (w >> 1) * 64;
    const int wn = (w & 1) * 64;
    const int fr = lane & 15;
    const int fk = (lane >> 4) * 8;

    f32x4 acc[4][4];
    #pragma unroll
    for (int i = 0; i < 4; ++i)
        #pragma unroll
        for (int j = 0; j < 4; ++j) acc[i][j] = (f32x4){0.f, 0.f, 0.f, 0.f};

    for (int kt = 0; kt < K; kt += 32) {
        #pragma unroll
        for (int j = 0; j < 2; ++j) {
            int off16 = j * 256 + t;
            int row = off16 >> 2;
            int kc = (off16 & 3) * 8;
            int gm = m0 + row;
            if (z) gm = (gm & ~2047) | (2047 - (gm & 2047));
            lds_cp16(As + off16 * 8, A + (size_t)gm * K + kt + kc);
            lds_cp16(Bs + off16 * 8, W + (size_t)(n0 + row) * K + kt + kc);
        }
        __syncthreads();
        bf16x8 af[4], bfr[4];
        #pragma unroll
        for (int i = 0; i < 4; ++i) af[i] = *(const bf16x8*)(As + (wm + i * 16 + fr) * 32 + fk);
        #pragma unroll
        for (int i = 0; i < 4; ++i) bfr[i] = *(const bf16x8*)(Bs + (wn + i * 16 + fr) * 32 + fk);
        #pragma unroll
        for (int i = 0; i < 4; ++i)
            #pragma unroll
            for (int j = 0; j < 4; ++j)
                acc[i][j] = __builtin_amdgcn_mfma_f32_16x16x32_bf16(af[i], bfr[j], acc[i][j], 0, 0, 0);
        __syncthreads();
    }
    #pragma unroll
    for (int i = 0; i < 4; ++i) {
        int rbase = m0 + wm + i * 16 + (lane >> 4) * 4;
        #pragma unroll
        for (int j = 0; j < 4; ++j) {
            int c = n0 + wn + j * 16 + fr;
            #pragma unroll
            for (int r = 0; r < 4; ++r) {
                u16 v = f2bf(acc[i][j][r]);
                int m = rbase + r;
                if (c < 1024) Z[(size_t)m * 1024 + c] = v;
                else if (c < 2192) XB[(size_t)m * 1184 + (c - 1024)] = v;
            }
        }
    }
}

// ---------------- generic bf16 GEMM (async staging) with fused epilogues ----------------
// EPI 0: bf16 store; 1: gelu(acc+bias)->bf16; 2: f32 out = acc + bias + resid
template <int EPI>
__global__ __launch_bounds__(256) void k_gemm2(
    const u16* __restrict__ A0, const u16* __restrict__ A1,
    const u16* __restrict__ W0, const u16* __restrict__ W1,
    u16* __restrict__ C0, u16* __restrict__ C1, int N, int K,
    const float* __restrict__ bias, const float* __restrict__ resid,
    float* __restrict__ outf) {
    const int z = blockIdx.z;
    const u16* A = z ? A1 : A0;
    const u16* W = z ? W1 : W0;
    u16* C = z ? C1 : C0;

    __shared__ __align__(16) u16 As[128 * 32];
    __shared__ __align__(16) u16 Bs[128 * 32];

    const int t = threadIdx.x;
    const int lane = t & 63;
    const int w = t >> 6;
    const int m0 = blockIdx.y * 128;
    const int n0 = blockIdx.x * 128;
    const int wm = (w >> 1) * 64;
    const int wn = (w & 1) * 64;
    const int fr = lane & 15;
    const int fk = (lane >> 4) * 8;

    f32x4 acc[4][4];
    #pragma unroll
    for (int i = 0; i < 4; ++i)
        #pragma unroll
        for (int j = 0; j < 4; ++j) acc[i][j] = (f32x4){0.f, 0.f, 0.f, 0.f};

    for (int kt = 0; kt < K; kt += 32) {
        #pragma unroll
        for (int j = 0; j < 2; ++j) {
            int off16 = j * 256 + t;
            int row = off16 >> 2;
            int kc = (off16 & 3) * 8;
            lds_cp16(As + off16 * 8, A + (size_t)(m0 + row) * K + kt + kc);
            lds_cp16(Bs + off16 * 8, W + (size_t)(n0 + row) * K + kt + kc);
        }
        __syncthreads();
        bf16x8 af[4], bfr[4];
        #pragma unroll
        for (int i = 0; i < 4; ++i) af[i] = *(const bf16x8*)(As + (wm + i * 16 + fr) * 32 + fk);
        #pragma unroll
        for (int i = 0; i < 4; ++i) bfr[i] = *(const bf16x8*)(Bs + (wn + i * 16 + fr) * 32 + fk);
        #pragma unroll
        for (int i = 0; i < 4; ++i)
            #pragma unroll
            for (int j = 0; j < 4; ++j)
                acc[i][j] = __builtin_amdgcn_mfma_f32_16x16x32_bf16(af[i], bfr[j], acc[i][j], 0, 0, 0);
        __syncthreads();
    }
    #pragma unroll
    for (int i = 0; i < 4; ++i) {
        int rbase = m0 + wm + i * 16 + (lane >> 4) * 4;
        #pragma unroll
        for (int j = 0; j < 4; ++j) {
            int col = n0 + wn + j * 16 + fr;
            #pragma unroll
            for (int r = 0; r < 4; ++r) {
                int m = rbase + r;
                float v = acc[i][j][r];
                if (EPI == 0) {
                    C[(size_t)m * N + col] = f2bf(v);
                } else if (EPI == 1) {
                    float xg = v + bias[col];
                    C[(size_t)m * N + col] = f2bf(0.5f * xg * (1.f + erff(xg * 0.70710678118654752f)));
                } else {
                    outf[(size_t)m * N + col] = v + bias[col] + resid[(size_t)m * N + col];
                }
            }
        }
    }
}

// ---------------- causal conv4 + silu, 8 rows/block sliding window ----------------
// grid 1024 (dir*512+rg), block 160: t<144 -> 8 channels x 8 rows; t in [144,160) -> dt head x 8 rows.
__global__ __launch_bounds__(160) void k_conv(
    const u16* __restrict__ xb0, const u16* __restrict__ xb1,
    const float* __restrict__ cw0, const float* __restrict__ cb0,
    const float* __restrict__ dtb0, const float* __restrict__ al0,
    const float* __restrict__ cw1, const float* __restrict__ cb1,
    const float* __restrict__ dtb1, const float* __restrict__ al1,
    u16* __restrict__ xc0, u16* __restrict__ xc1,
    float* __restrict__ dtO0, float* __restrict__ dAO0,
    float* __restrict__ dtO1, float* __restrict__ dAO1) {
    int g = blockIdx.x;
    int dir = g >> 9;
    int row0 = (g & 511) * 8;          // dir-local, 8 consecutive rows, same batch
    const u16* xb = dir ? xb1 : xb0;
    const float* cw = dir ? cw1 : cw0;
    const float* cb = dir ? cb1 : cb0;
    const float* dtb = dir ? dtb1 : dtb0;
    const float* al = dir ? al1 : al0;
    u16* xc = dir ? xc1 : xc0;
    float* dtO = dir ? dtO1 : dtO0;
    float* dAO = dir ? dAO1 : dAO0;
    int tl0 = row0 & 2047;
    int rbatch = row0 - tl0;           // batch base row
    int t = threadIdx.x;
    if (t < 144) {
        int col = t * 8;
        float cwa[8][4];
        #pragma unroll
        for (int j = 0; j < 8; ++j) {
            float4 c4 = *(const float4*)(cw + (col + j) * 4);
            cwa[j][0] = c4.x; cwa[j][1] = c4.y; cwa[j][2] = c4.z; cwa[j][3] = c4.w;
        }
        float cbv[8];
        float4 cb0v = *(const float4*)(cb + col);
        float4 cb1v = *(const float4*)(cb + col + 4);
        cbv[0] = cb0v.x; cbv[1] = cb0v.y; cbv[2] = cb0v.z; cbv[3] = cb0v.w;
        cbv[4] = cb1v.x; cbv[5] = cb1v.y; cbv[6] = cb1v.z; cbv[7] = cb1v.w;
        uint4 win[4];
        win[0] = win[1] = win[2] = make_uint4(0, 0, 0, 0);
        #pragma unroll
        for (int i = 0; i < 3; ++i) {
            int tt = tl0 - 3 + i;
            if (tt >= 0) win[i] = *(const uint4*)(xb + (size_t)(rbatch + tt) * 1184 + col);
        }
        for (int s = 0; s < 8; ++s) {
            win[3] = *(const uint4*)(xb + (size_t)(rbatch + tl0 + s) * 1184 + col);
            const u16* w0 = (const u16*)&win[0];
            const u16* w1 = (const u16*)&win[1];
            const u16* w2 = (const u16*)&win[2];
            const u16* w3 = (const u16*)&win[3];
            u16 ov[8];
            #pragma unroll
            for (int j = 0; j < 8; ++j) {
                float a = cbv[j] + bf2f(w0[j]) * cwa[j][0] + bf2f(w1[j]) * cwa[j][1]
                        + bf2f(w2[j]) * cwa[j][2] + bf2f(w3[j]) * cwa[j][3];
                ov[j] = f2bf(a / (1.f + expf(-a)));
            }
            *(uint4*)(xc + (size_t)(row0 + s) * 1152 + col) = *(const uint4*)ov;
            win[0] = win[1]; win[1] = win[2]; win[2] = win[3];
        }
    } else if (t < 160) {
        int hh = t - 144;
        float nal = -expf(al[hh]);
        float dtbv = dtb[hh];
        for (int s = 0; s < 8; ++s) {
            int row = row0 + s;
            float v = bf2f(xb[(size_t)row * 1184 + 1152 + hh]) + dtbv;
            float sp = (v > 20.f) ? v : log1pf(expf(v));  // softplus
            dtO[row * 16 + hh] = sp;
            dAO[row * 16 + hh] = nal * sp;                // LOG decay
        }
    }
}

// ======== SSD chunked scan: L=2048 -> 32 chunks of 64, all-MFMA ========
// blk = (((dir*2+b)*16+h)*32 + c). S layout: S[blk][p*64+n] (f32).

// ---- Pass A: S_local[n][p] ----
__global__ __launch_bounds__(256) void k_ssd_state(
    const u16* __restrict__ xc0, const float* __restrict__ dt0, const float* __restrict__ ld0,
    const u16* __restrict__ xc1, const float* __restrict__ dt1, const float* __restrict__ ld1,
    float* __restrict__ S, float* __restrict__ Aprod) {
    int blk = blockIdx.x;
    int c = blk & 31, h = (blk >> 5) & 15, b = (blk >> 9) & 1, dir = blk >> 10;
    const u16* xc = dir ? xc1 : xc0;
    const float* dtp = dir ? dt1 : dt0;
    const float* ldp = dir ? ld1 : ld0;
    const int t = threadIdx.x, w = t >> 6, lane = t & 63;
    const int fr = lane & 15, fk = (lane >> 4) * 8;

    __shared__ __align__(16) u16 sBt[64 * 72];  // B^T: [n][r]
    __shared__ __align__(16) u16 sXp[64 * 72];  // X~ : [p][r]
    __shared__ float ssc[64];
    size_t row0 = (size_t)b * 2048 + c * 64;

    if (t < 64) {
        float v = ldp[(row0 + t) * 16 + h];
        float dtv = dtp[(row0 + t) * 16 + h];
        #pragma unroll
        for (int o = 1; o < 64; o <<= 1) {
            float u = __shfl_up(v, o);
            if (lane >= o) v += u;
        }
        float last = __shfl(v, 63);
        ssc[t] = dtv * expf(last - v);
        if (t == 63) Aprod[blk] = expf(v);
    }
    __syncthreads();
    #pragma unroll
    for (int i2 = t; i2 < 512; i2 += 256) {
        int r = i2 >> 3, e8 = (i2 & 7) * 8;
        size_t rb = (row0 + r) * 1152;
        uint4 bv = *(const uint4*)(xc + rb + 1024 + e8);
        uint4 xv = *(const uint4*)(xc + rb + h * 64 + e8);
        const u16* bs = (const u16*)&bv;
        const u16* xs = (const u16*)&xv;
        float sc = ssc[r];
        #pragma unroll
        for (int j = 0; j < 8; ++j) {
            sBt[(e8 + j) * 72 + r] = bs[j];
            sXp[(e8 + j) * 72 + r] = f2bf(bf2f(xs[j]) * sc);
        }
    }
    __syncthreads();

    f32x4 acc[4];
    #pragma unroll
    for (int j = 0; j < 4; ++j) acc[j] = (f32x4){0.f, 0.f, 0.f, 0.f};
    #pragma unroll
    for (int k0 = 0; k0 < 64; k0 += 32) {
        bf16x8 a = *(const bf16x8*)(sBt + (w * 16 + fr) * 72 + k0 + fk);
        #pragma unroll
        for (int j = 0; j < 4; ++j) {
            bf16x8 bb = *(const bf16x8*)(sXp + (j * 16 + fr) * 72 + k0 + fk);
            acc[j] = __builtin_amdgcn_mfma_f32_16x16x32_bf16(a, bb, acc[j], 0, 0, 0);
        }
    }
    float* Sb = S + (size_t)blk * 4096;
    int nb = w * 16 + (lane >> 4) * 4;
    #pragma unroll
    for (int j = 0; j < 4; ++j) {
        int p = j * 16 + fr;
        *(f32x4*)(Sb + p * 64 + nb) = acc[j];
    }
}

// ---- Pass B: 64 blocks; in-place S_c -> carry-in H_c ----
__global__ __launch_bounds__(256) void k_scan_carry(float* __restrict__ S,
                                                    const float* __restrict__ Aprod) {
    int blk = blockIdx.x;
    int t = threadIdx.x;
    float h[16];
    #pragma unroll
    for (int j = 0; j < 16; ++j) h[j] = 0.f;
    for (int c = 0; c < 32; ++c) {
        float a = Aprod[blk * 32 + c];
        float* Sp = S + ((size_t)blk * 32 + c) * 4096 + t * 16;
        float4 s0 = *(float4*)(Sp + 0), s1 = *(float4*)(Sp + 4);
        float4 s2 = *(float4*)(Sp + 8), s3 = *(float4*)(Sp + 12);
        *(float4*)(Sp + 0) = make_float4(h[0], h[1], h[2], h[3]);
        *(float4*)(Sp + 4) = make_float4(h[4], h[5], h[6], h[7]);
        *(float4*)(Sp + 8) = make_float4(h[8], h[9], h[10], h[11]);
        *(float4*)(Sp + 12) = make_float4(h[12], h[13], h[14], h[15]);
        h[0] = a * h[0] + s0.x; h[1] = a * h[1] + s0.y; h[2] = a * h[2] + s0.z; h[3] = a * h[3] + s0.w;
        h[4] = a * h[4] + s1.x; h[5] = a * h[5] + s1.y; h[6] = a * h[6] + s1.z; h[7] = a * h[7] + s1.w;
        h[8] = a * h[8] + s2.x; h[9] = a * h[9] + s2.y; h[10] = a * h[10] + s2.z; h[11] = a * h[11] + s2.w;
        h[12] = a * h[12] + s3.x; h[13] = a * h[13] + s3.y; h[14] = a * h[14] + s3.z; h[15] = a * h[15] + s3.w;
    }
}

// ---- Pass C: y = (G.L)(x*dt) + exp(acum)*C*Hin + x*D via 3 MFMA GEMMs ----
__global__ __launch_bounds__(256) void k_ssd_y(
    const u16* __restrict__ xc0, const float* __restrict__ dt0, const float* __restrict__ ld0,
    const float* __restrict__ Dv0, u16* __restrict__ y0,
    const u16* __restrict__ xc1, const float* __restrict__ dt1, const float* __restrict__ ld1,
    const float* __restrict__ Dv1, u16* __restrict__ y1,
    const float* __restrict__ S) {
    int blk = blockIdx.x;
    int c = blk & 31, h = (blk >> 5) & 15, b = (blk >> 9) & 1, dir = blk >> 10;
    const u16* xc = dir ? xc1 : xc0;
    const float* dtp = dir ? dt1 : dt0;
    const float* ldp = dir ? ld1 : ld0;
    u16* y = dir ? y1 : y0;
    const float Dh = (dir ? Dv1 : Dv0)[h];
    const int t = threadIdx.x, w = t >> 6, lane = t & 63;
    const int fr = lane & 15, fk = (lane >> 4) * 8;

    __shared__ __align__(16) u16 sB[64 * 72];   // [r][n]
    __shared__ __align__(16) u16 sC[64 * 72];   // [s][n]
    __shared__ __align__(16) u16 sXp[64 * 72];  // [p][r] = x[r][p]*dt[r]
    __shared__ __align__(16) u16 sHi[64 * 72];  // [p][n] carry hi
    __shared__ __align__(16) u16 sLo[64 * 72];  // [p][n] carry lo
    __shared__ __align__(16) u16 sGl[64 * 72];  // [s][r] = G*L
    __shared__ float scl[64], sdt[64];
    size_t row0 = (size_t)b * 2048 + c * 64;

    if (t < 64) {
        float v = ldp[(row0 + t) * 16 + h];
        float dtv = dtp[(row0 + t) * 16 + h];
        #pragma unroll
        for (int o = 1; o < 64; o <<= 1) {
            float u = __shfl_up(v, o);
            if (lane >= o) v += u;
        }
        scl[t] = v;
        sdt[t] = dtv;
    }
    __syncthreads();
    #pragma unroll
    for (int i2 = t; i2 < 512; i2 += 256) {
        int r = i2 >> 3, e8 = (i2 & 7) * 8;
        size_t rb = (row0 + r) * 1152;
        *(uint4*)(sB + r * 72 + e8) = *(const uint4*)(xc + rb + 1024 + e8);
        *(uint4*)(sC + r * 72 + e8) = *(const uint4*)(xc + rb + 1088 + e8);
        uint4 xv = *(const uint4*)(xc + rb + h * 64 + e8);
        const u16* xs = (const u16*)&xv;
        float dtv = sdt[r];
        #pragma unroll
        for (int j = 0; j < 8; ++j) sXp[(e8 + j) * 72 + r] = f2bf(bf2f(xs[j]) * dtv);
    }
    #pragma unroll
    for (int i4 = t; i4 < 1024; i4 += 256) {
        int p = i4 >> 4, n4 = (i4 & 15) * 4;
        float4 hv = *(const float4*)(S + (size_t)blk * 4096 + p * 64 + n4);
        ushort4 hi4, lo4;
        hi4.x = f2bf(hv.x); lo4.x = f2bf(hv.x - bf2f(hi4.x));
        hi4.y = f2bf(hv.y); lo4.y = f2bf(hv.y - bf2f(hi4.y));
        hi4.z = f2bf(hv.z); lo4.z = f2bf(hv.z - bf2f(hi4.z));
        hi4.w = f2bf(hv.w); lo4.w = f2bf(hv.w - bf2f(hi4.w));
        *(ushort4*)(sHi + p * 72 + n4) = hi4;
        *(ushort4*)(sLo + p * 72 + n4) = lo4;
    }
    __syncthreads();

    f32x4 g[4], acc2[4];
    #pragma unroll
    for (int j = 0; j < 4; ++j) { g[j] = (f32x4){0.f,0.f,0.f,0.f}; acc2[j] = (f32x4){0.f,0.f,0.f,0.f}; }
    #pragma unroll
    for (int k0 = 0; k0 < 64; k0 += 32) {
        bf16x8 a = *(const bf16x8*)(sC + (w * 16 + fr) * 72 + k0 + fk);
        #pragma unroll
        for (int j = 0; j < 4; ++j) {
            bf16x8 bb = *(const bf16x8*)(sB + (j * 16 + fr) * 72 + k0 + fk);
            g[j] = __builtin_amdgcn_mfma_f32_16x16x32_bf16(a, bb, g[j], 0, 0, 0);
            bf16x8 bh = *(const bf16x8*)(sHi + (j * 16 + fr) * 72 + k0 + fk);
            acc2[j] = __builtin_amdgcn_mfma_f32_16x16x32_bf16(a, bh, acc2[j], 0, 0, 0);
            bf16x8 bl = *(const bf16x8*)(sLo + (j * 16 + fr) * 72 + k0 + fk);
            acc2[j] = __builtin_amdgcn_mfma_f32_16x16x32_bf16(a, bl, acc2[j], 0, 0, 0);
        }
    }
    #pragma unroll
    for (int j = 0; j < 4; ++j) {
        int r = j * 16 + fr;
        #pragma unroll
        for (int reg = 0; reg < 4; ++reg) {
            int s = w * 16 + (lane >> 4) * 4 + reg;
            float val = (r <= s) ? expf(scl[s] - scl[r]) * g[j][reg] : 0.f;
            sGl[s * 72 + r] = f2bf(val);
        }
    }
    __syncthreads();

    f32x4 acc1[4];
    #pragma unroll
    for (int j = 0; j < 4; ++j) acc1[j] = (f32x4){0.f, 0.f, 0.f, 0.f};
    #pragma unroll
    for (int k0 = 0; k0 < 64; k0 += 32) {
        bf16x8 a = *(const bf16x8*)(sGl + (w * 16 + fr) * 72 + k0 + fk);
        #pragma unroll
        for (int j = 0; j < 4; ++j) {
            bf16x8 bb = *(const bf16x8*)(sXp + (j * 16 + fr) * 72 + k0 + fk);
            acc1[j] = __builtin_amdgcn_mfma_f32_16x16x32_bf16(a, bb, acc1[j], 0, 0, 0);
        }
    }
    #pragma unroll
    for (int reg = 0; reg < 4; ++reg) {
        int s = w * 16 + (lane >> 4) * 4 + reg;
        float es = expf(scl[s]);
        size_t yrb = (row0 + s) * 1024 + h * 64;
        size_t xrb = (row0 + s) * 1152 + h * 64;
        #pragma unroll
        for (int j = 0; j < 4; ++j) {
            int p = j * 16 + fr;
            float xv = bf2f(xc[xrb + p]);
            y[yrb + p] = f2bf(acc1[j][reg] + es * acc2[j][reg] + xv * Dh);
        }
    }
}

// ---------------- gated RMS norm ----------------
__global__ __launch_bounds__(256) void k_gnorm(
    const u16* __restrict__ y0, const u16* __restrict__ z0,
    const float* __restrict__ gw0, u16* __restrict__ o0,
    const u16* __restrict__ y1, const u16* __restrict__ z1,
    const float* __restrict__ gw1, u16* __restrict__ o1) {
    __shared__ float red[4];
    int r = blockIdx.x;
    int dir = r >> 12, row = r & 4095;
    int t = threadIdx.x;
    const u16* y = dir ? y1 : y0;
    const u16* zp = dir ? z1 : z0;
    const float* gw = dir ? gw1 : gw0;
    u16* o = dir ? o1 : o0;
    ushort4 yv = *(const ushort4*)(y + (size_t)row * 1024 + t * 4);
    ushort4 zr = *(const ushort4*)(zp + (size_t)row * 1024 + t * 4);
    float z0f = bf2f(zr.x), z1f = bf2f(zr.y), z2f = bf2f(zr.z), z3f = bf2f(zr.w);
    float v0 = bf2f(yv.x) * (z0f / (1.f + expf(-z0f)));
    float v1 = bf2f(yv.y) * (z1f / (1.f + expf(-z1f)));
    float v2 = bf2f(yv.z) * (z2f / (1.f + expf(-z2f)));
    float v3 = bf2f(yv.w) * (z3f / (1.f + expf(-z3f)));
    float ss = block_sum_256(v0 * v0 + v1 * v1 + v2 * v2 + v3 * v3, red);
    float sc = rsqrtf(ss * (1.f / 1024.f) + 1e-5f);
    float4 gv = *(const float4*)(gw + t * 4);
    size_t ob = (size_t)row * 1024 + t * 4;
    o[ob + 0] = f2bf(v0 * sc * gv.x);
    o[ob + 1] = f2bf(v1 * sc * gv.y);
    o[ob + 2] = f2bf(v2 * sc * gv.z);
    o[ob + 3] = f2bf(v3 * sc * gv.w);
}

// ---------------- fused: x2 = x + (fwd+flip(bwd))*mask; rms(x2)*nfw -> bf16 ----------------
__global__ __launch_bounds__(256) void k_add_rms(
    const float* __restrict__ x, const u16* __restrict__ of,
    const u16* __restrict__ ob, const float* __restrict__ mask,
    const float* __restrict__ wrms, float* __restrict__ x2, u16* __restrict__ o) {
    __shared__ float red[4];
    int row = blockIdx.x, t = threadIdx.x;
    int bb = row >> 11, tl = row & 2047;
    size_t fb = (size_t)((bb << 11) + (2047 - tl)) * 512;
    float m = mask[row];
    size_t base = (size_t)row * 512 + t * 2;
    size_t fo = fb + t * 2;
    float2 xv = *(const float2*)(x + base);
    float v0 = xv.x + (bf2f(of[base]) + bf2f(ob[fo])) * m;
    float v1 = xv.y + (bf2f(of[base + 1]) + bf2f(ob[fo + 1])) * m;
    x2[base] = v0;
    x2[base + 1] = v1;
    float ss = block_sum_256(v0 * v0 + v1 * v1, red);
    float sc = rsqrtf(ss * (1.f / 512.f) + 1.1920929e-07f);
    float2 wv = *(const float2*)(wrms + t * 2);
    o[base] = f2bf(v0 * sc * wv.x);
    o[base + 1] = f2bf(v1 * sc * wv.y);
}

extern "C" void kernel_launch(void* const* d_in, const int* in_sizes, int n_in,
                              void* d_out, int out_size, void* d_ws, size_t ws_size,
                              hipStream_t stream) {
    const float* x = (const float*)d_in[0];
    const float* pe = (const float*)d_in[1];
    const float* mask = (const float*)d_in[2];
    const float* nsw = (const float*)d_in[3];
    const float* nfw = (const float*)d_in[4];
    const float* w1 = (const float*)d_in[5];
    const float* b1 = (const float*)d_in[6];
    const float* w2 = (const float*)d_in[7];
    const float* b2 = (const float*)d_in[8];
    const float* f_inw = (const float*)d_in[9];
    const float* f_cw = (const float*)d_in[10];
    const float* f_cb = (const float*)d_in[11];
    const float* f_dtb = (const float*)d_in[12];
    const float* f_al = (const float*)d_in[13];
    const float* f_D = (const float*)d_in[14];
    const float* f_gw = (const float*)d_in[15];
    const float* f_ow = (const float*)d_in[16];
    const float* b_inw = (const float*)d_in[17];
    const float* b_cw = (const float*)d_in[18];
    const float* b_cb = (const float*)d_in[19];
    const float* b_dtb = (const float*)d_in[20];
    const float* b_al = (const float*)d_in[21];
    const float* b_D = (const float*)d_in[22];
    const float* b_gw = (const float*)d_in[23];
    const float* b_ow = (const float*)d_in[24];
    float* out = (float*)d_out;

    char* ws = (char*)d_ws;
    u16* Z0   = (u16*)(ws + 0);
    u16* Z1   = (u16*)(ws + 8388608);
    u16* XB0  = (u16*)(ws + 16777216);
    u16* XB1  = (u16*)(ws + 26476544);
    u16* INWF = (u16*)(ws + 36175872);
    u16* INWB = (u16*)(ws + 38535168);
    u16* SIB  = (u16*)(ws + 40894464);
    u16* XC0  = (u16*)(ws + 36175872);
    u16* XC1  = (u16*)(ws + 45613056);
    float* dtF = (float*)(ws + 55050240);
    float* dAF = (float*)(ws + 55312384);
    float* dtB = (float*)(ws + 55574528);
    float* dAB = (float*)(ws + 55836672);
    u16* Y0   = (u16*)(ws + 16777216);
    u16* Y1   = (u16*)(ws + 25165824);
    u16* YG0  = (u16*)(ws + 36175872);
    u16* YG1  = (u16*)(ws + 44564480);
    u16* OP0  = (u16*)(ws + 0);
    u16* OP1  = (u16*)(ws + 4194304);
    float* X2 = (float*)(ws + 8388608);
    u16* X2B  = (u16*)(ws + 0);
    u16* HACT = (u16*)(ws + 16777216);
    u16* OWF = (u16*)(ws + 56098816);
    u16* OWB = (u16*)(ws + 57147392);
    u16* W1B = (u16*)(ws + 58195968);
    u16* W2B = (u16*)(ws + 60293120);
    float* SBUF = (float*)(ws + 62390272);   // 2048 x 4096 f32 = 32 MB
    float* APR  = (float*)(ws + 95944704);   // 2048 f32

    k_cvt_all<<<21504, 256, 0, stream>>>(f_inw, b_inw, f_ow, b_ow, w1, w2,
                                         INWF, INWB, OWF, OWB, W1B, W2B);
    k_rms_pos<<<4096, 256, 0, stream>>>(x, pe, nsw, SIB);
    k_gemm_in<<<dim3(18, 32, 2), 256, 0, stream>>>(SIB, INWF, INWB, Z0, Z1, XB0, XB1);
    k_conv<<<1024, 160, 0, stream>>>(XB0, XB1, f_cw, f_cb, f_dtb, f_al,
                                     b_cw, b_cb, b_dtb, b_al,
                                     XC0, XC1, dtF, dAF, dtB, dAB);
    k_ssd_state<<<2048, 256, 0, stream>>>(XC0, dtF, dAF, XC1, dtB, dAB, SBUF, APR);
    k_scan_carry<<<64, 256, 0, stream>>>(SBUF, APR);
    k_ssd_y<<<2048, 256, 0, stream>>>(XC0, dtF, dAF, f_D, Y0,
                                      XC1, dtB, dAB, b_D, Y1, SBUF);
    k_gnorm<<<8192, 256, 0, stream>>>(Y0, Z0, f_gw, YG0, Y1, Z1, b_gw, YG1);
    k_gemm2<0><<<dim3(4, 32, 2), 256, 0, stream>>>(YG0, YG1, OWF, OWB, OP0, OP1, 512, 1024,
                                                   nullptr, nullptr, nullptr);
    k_add_rms<<<4096, 256, 0, stream>>>(x, OP0, OP1, mask, nfw, X2, X2B);
    k_gemm2<1><<<dim3(16, 32, 1), 256, 0, stream>>>(X2B, X2B, W1B, W1B, HACT, HACT, 2048, 512,
                                                    b1, nullptr, nullptr);
    k_gemm2<2><<<dim3(4, 32, 1), 256, 0, stream>>>(HACT, HACT, W2B, W2B, OP0, OP1, 512, 2048,
                                                   b2, X2, out);
}

// Round 11
// 353.075 us; speedup vs baseline: 5.2463x; 1.0467x over previous
//
#include <hip/hip_runtime.h>
#include <hip/hip_bf16.h>

typedef unsigned short u16;
typedef unsigned int u32;
typedef __bf16 bf16x8 __attribute__((ext_vector_type(8)));
typedef float f32x4 __attribute__((ext_vector_type(4)));

typedef __attribute__((address_space(1))) void gvoid_t;
typedef __attribute__((address_space(3))) void lvoid_t;
__device__ __forceinline__ void lds_cp16(void* lds, const void* g) {
    __builtin_amdgcn_global_load_lds((gvoid_t*)g, (lvoid_t*)lds, 16, 0, 0);
}

__device__ __forceinline__ float bf2f(u16 v) {
    u32 x = (u32)v << 16;
    return __builtin_bit_cast(float, x);
}
__device__ __forceinline__ u16 f2bf(float f) {
    return __builtin_bit_cast(u16, (__bf16)f);
}

// ---------------- block reduction (256 threads = 4 waves) ----------------
__device__ __forceinline__ float block_sum_256(float v, float* red) {
    #pragma unroll
    for (int o = 32; o > 0; o >>= 1) v += __shfl_xor(v, o);
    int w = threadIdx.x >> 6;
    if ((threadIdx.x & 63) == 0) red[w] = v;
    __syncthreads();
    return red[0] + red[1] + red[2] + red[3];
}

// ---------------- all weight conversions in one kernel ----------------
__global__ void k_cvt_all(const float* __restrict__ f_inw, const float* __restrict__ b_inw,
                          const float* __restrict__ f_ow, const float* __restrict__ b_ow,
                          const float* __restrict__ w1, const float* __restrict__ w2,
                          u16* __restrict__ INWF, u16* __restrict__ INWB,
                          u16* __restrict__ OWF, u16* __restrict__ OWB,
                          u16* __restrict__ W1B, u16* __restrict__ W2B) {
    int i = blockIdx.x * 256 + threadIdx.x;
    if (i < 1179648) { int n = i >> 9; INWF[i] = (n < 2192) ? f2bf(f_inw[i]) : (u16)0; return; }
    i -= 1179648;
    if (i < 1179648) { int n = i >> 9; INWB[i] = (n < 2192) ? f2bf(b_inw[i]) : (u16)0; return; }
    i -= 1179648;
    if (i < 524288) { OWF[i] = f2bf(f_ow[i]); return; }
    i -= 524288;
    if (i < 524288) { OWB[i] = f2bf(b_ow[i]); return; }
    i -= 524288;
    if (i < 1048576) { W1B[i] = f2bf(w1[i]); return; }
    i -= 1048576;
    if (i < 1048576) W2B[i] = f2bf(w2[i]);
}

// ---------------- si = rms(x)*w + pos_emb -> bf16 ----------------
__global__ __launch_bounds__(256) void k_rms_pos(const float* __restrict__ x,
                                                 const float* __restrict__ pe,
                                                 const float* __restrict__ wrms,
                                                 u16* __restrict__ sib) {
    __shared__ float red[4];
    int row = blockIdx.x, t = threadIdx.x;
    size_t base = (size_t)row * 512 + t * 2;
    float2 xv = *(const float2*)(x + base);
    float ss = block_sum_256(xv.x * xv.x + xv.y * xv.y, red);
    float sc = rsqrtf(ss * (1.f / 512.f) + 1.1920929e-07f);
    float2 pv = *(const float2*)(pe + base);
    float2 wv = *(const float2*)(wrms + t * 2);
    sib[base] = f2bf(xv.x * sc * wv.x + pv.x);
    sib[base + 1] = f2bf(xv.y * sc * wv.y + pv.y);
}

// ---------------- in_proj GEMM with split epilogue (async LDS staging) ----------------
__global__ __launch_bounds__(256) void k_gemm_in(
    const u16* __restrict__ A, const u16* __restrict__ W0, const u16* __restrict__ W1,
    u16* __restrict__ Z0, u16* __restrict__ Z1,
    u16* __restrict__ XB0, u16* __restrict__ XB1) {
    const int z = blockIdx.z;
    const u16* W = z ? W1 : W0;
    u16* Z = z ? Z1 : Z0;
    u16* XB = z ? XB1 : XB0;
    const int K = 512;

    __shared__ __align__(16) u16 As[128 * 32];
    __shared__ __align__(16) u16 Bs[128 * 32];

    const int t = threadIdx.x;
    const int lane = t & 63;
    const int w = t >> 6;
    const int m0 = blockIdx.y * 128;
    const int n0 = blockIdx.x * 128;
    const int wm = (w >> 1) * 64;
    const int wn = (w & 1) * 64;
    const int fr = lane & 15;
    const int fk = (lane >> 4) * 8;

    f32x4 acc[4][4];
    #pragma unroll
    for (int i = 0; i < 4; ++i)
        #pragma unroll
        for (int j = 0; j < 4; ++j) acc[i][j] = (f32x4){0.f, 0.f, 0.f, 0.f};

    for (int kt = 0; kt < K; kt += 32) {
        #pragma unroll
        for (int j = 0; j < 2; ++j) {
            int off16 = j * 256 + t;
            int row = off16 >> 2;
            int kc = (off16 & 3) * 8;
            int gm = m0 + row;
            if (z) gm = (gm & ~2047) | (2047 - (gm & 2047));
            lds_cp16(As + off16 * 8, A + (size_t)gm * K + kt + kc);
            lds_cp16(Bs + off16 * 8, W + (size_t)(n0 + row) * K + kt + kc);
        }
        __syncthreads();
        bf16x8 af[4], bfr[4];
        #pragma unroll
        for (int i = 0; i < 4; ++i) af[i] = *(const bf16x8*)(As + (wm + i * 16 + fr) * 32 + fk);
        #pragma unroll
        for (int i = 0; i < 4; ++i) bfr[i] = *(const bf16x8*)(Bs + (wn + i * 16 + fr) * 32 + fk);
        #pragma unroll
        for (int i = 0; i < 4; ++i)
            #pragma unroll
            for (int j = 0; j < 4; ++j)
                acc[i][j] = __builtin_amdgcn_mfma_f32_16x16x32_bf16(af[i], bfr[j], acc[i][j], 0, 0, 0);
        __syncthreads();
    }
    #pragma unroll
    for (int i = 0; i < 4; ++i) {
        int rbase = m0 + wm + i * 16 + (lane >> 4) * 4;
        #pragma unroll
        for (int j = 0; j < 4; ++j) {
            int c = n0 + wn + j * 16 + fr;
            #pragma unroll
            for (int r = 0; r < 4; ++r) {
                u16 v = f2bf(acc[i][j][r]);
                int m = rbase + r;
                if (c < 1024) Z[(size_t)m * 1024 + c] = v;
                else if (c < 2192) XB[(size_t)m * 1184 + (c - 1024)] = v;
            }
        }
    }
}

// ---------------- 64x64-tile GEMM (high-occupancy, async staging) ----------------
// EPI 0: bf16 store (z=dir); 1: gelu(acc+bias)->bf16 (z=dir); 3: split-K, z=k-half,
// atomicAdd f32 into outf (pre-initialized with bias+resid).
template <int EPI>
__global__ __launch_bounds__(256) void k_gemm64(
    const u16* __restrict__ A0, const u16* __restrict__ A1,
    const u16* __restrict__ W0, const u16* __restrict__ W1,
    u16* __restrict__ C0, u16* __restrict__ C1, int N, int K,
    const float* __restrict__ bias, float* __restrict__ outf) {
    const int z = blockIdx.z;
    const u16* A = (EPI == 3) ? A0 : (z ? A1 : A0);
    const u16* W = (EPI == 3) ? W0 : (z ? W1 : W0);
    u16* C = z ? C1 : C0;
    int kbeg = 0, kend = K;
    if (EPI == 3) { kbeg = z * (K >> 1); kend = kbeg + (K >> 1); }

    __shared__ __align__(16) u16 As[64 * 32];
    __shared__ __align__(16) u16 Bs[64 * 32];

    const int t = threadIdx.x;
    const int lane = t & 63;
    const int w = t >> 6;
    const int m0 = blockIdx.y * 64;
    const int n0 = blockIdx.x * 64;
    const int wm = (w >> 1) * 32;
    const int wn = (w & 1) * 32;
    const int fr = lane & 15;
    const int fk = (lane >> 4) * 8;

    f32x4 acc[2][2];
    #pragma unroll
    for (int i = 0; i < 2; ++i)
        #pragma unroll
        for (int j = 0; j < 2; ++j) acc[i][j] = (f32x4){0.f, 0.f, 0.f, 0.f};

    const int srow = t >> 2;          // 0..63
    const int skc = (t & 3) * 8;
    for (int kt = kbeg; kt < kend; kt += 32) {
        lds_cp16(As + t * 8, A + (size_t)(m0 + srow) * K + kt + skc);
        lds_cp16(Bs + t * 8, W + (size_t)(n0 + srow) * K + kt + skc);
        __syncthreads();
        bf16x8 af[2], bfr[2];
        #pragma unroll
        for (int i = 0; i < 2; ++i) af[i] = *(const bf16x8*)(As + (wm + i * 16 + fr) * 32 + fk);
        #pragma unroll
        for (int j = 0; j < 2; ++j) bfr[j] = *(const bf16x8*)(Bs + (wn + j * 16 + fr) * 32 + fk);
        #pragma unroll
        for (int i = 0; i < 2; ++i)
            #pragma unroll
            for (int j = 0; j < 2; ++j)
                acc[i][j] = __builtin_amdgcn_mfma_f32_16x16x32_bf16(af[i], bfr[j], acc[i][j], 0, 0, 0);
        __syncthreads();
    }
    #pragma unroll
    for (int i = 0; i < 2; ++i) {
        int rbase = m0 + wm + i * 16 + (lane >> 4) * 4;
        #pragma unroll
        for (int j = 0; j < 2; ++j) {
            int col = n0 + wn + j * 16 + fr;
            #pragma unroll
            for (int r = 0; r < 4; ++r) {
                int m = rbase + r;
                float v = acc[i][j][r];
                if (EPI == 0) {
                    C[(size_t)m * N + col] = f2bf(v);
                } else if (EPI == 1) {
                    float xg = v + bias[col];
                    C[(size_t)m * N + col] = f2bf(0.5f * xg * (1.f + erff(xg * 0.70710678118654752f)));
                } else {
                    atomicAdd(outf + (size_t)m * N + col, v);
                }
            }
        }
    }
}

// ---------------- causal conv4 + silu, 8 rows/block sliding window ----------------
__global__ __launch_bounds__(160) void k_conv(
    const u16* __restrict__ xb0, const u16* __restrict__ xb1,
    const float* __restrict__ cw0, const float* __restrict__ cb0,
    const float* __restrict__ dtb0, const float* __restrict__ al0,
    const float* __restrict__ cw1, const float* __restrict__ cb1,
    const float* __restrict__ dtb1, const float* __restrict__ al1,
    u16* __restrict__ xc0, u16* __restrict__ xc1,
    float* __restrict__ dtO0, float* __restrict__ dAO0,
    float* __restrict__ dtO1, float* __restrict__ dAO1) {
    int g = blockIdx.x;
    int dir = g >> 9;
    int row0 = (g & 511) * 8;
    const u16* xb = dir ? xb1 : xb0;
    const float* cw = dir ? cw1 : cw0;
    const float* cb = dir ? cb1 : cb0;
    const float* dtb = dir ? dtb1 : dtb0;
    const float* al = dir ? al1 : al0;
    u16* xc = dir ? xc1 : xc0;
    float* dtO = dir ? dtO1 : dtO0;
    float* dAO = dir ? dAO1 : dAO0;
    int tl0 = row0 & 2047;
    int rbatch = row0 - tl0;
    int t = threadIdx.x;
    if (t < 144) {
        int col = t * 8;
        float cwa[8][4];
        #pragma unroll
        for (int j = 0; j < 8; ++j) {
            float4 c4 = *(const float4*)(cw + (col + j) * 4);
            cwa[j][0] = c4.x; cwa[j][1] = c4.y; cwa[j][2] = c4.z; cwa[j][3] = c4.w;
        }
        float cbv[8];
        float4 cb0v = *(const float4*)(cb + col);
        float4 cb1v = *(const float4*)(cb + col + 4);
        cbv[0] = cb0v.x; cbv[1] = cb0v.y; cbv[2] = cb0v.z; cbv[3] = cb0v.w;
        cbv[4] = cb1v.x; cbv[5] = cb1v.y; cbv[6] = cb1v.z; cbv[7] = cb1v.w;
        uint4 win[4];
        win[0] = win[1] = win[2] = make_uint4(0, 0, 0, 0);
        #pragma unroll
        for (int i = 0; i < 3; ++i) {
            int tt = tl0 - 3 + i;
            if (tt >= 0) win[i] = *(const uint4*)(xb + (size_t)(rbatch + tt) * 1184 + col);
        }
        for (int s = 0; s < 8; ++s) {
            win[3] = *(const uint4*)(xb + (size_t)(rbatch + tl0 + s) * 1184 + col);
            const u16* w0 = (const u16*)&win[0];
            const u16* w1 = (const u16*)&win[1];
            const u16* w2 = (const u16*)&win[2];
            const u16* w3 = (const u16*)&win[3];
            u16 ov[8];
            #pragma unroll
            for (int j = 0; j < 8; ++j) {
                float a = cbv[j] + bf2f(w0[j]) * cwa[j][0] + bf2f(w1[j]) * cwa[j][1]
                        + bf2f(w2[j]) * cwa[j][2] + bf2f(w3[j]) * cwa[j][3];
                ov[j] = f2bf(a / (1.f + expf(-a)));
            }
            *(uint4*)(xc + (size_t)(row0 + s) * 1152 + col) = *(const uint4*)ov;
            win[0] = win[1]; win[1] = win[2]; win[2] = win[3];
        }
    } else if (t < 160) {
        int hh = t - 144;
        float nal = -expf(al[hh]);
        float dtbv = dtb[hh];
        for (int s = 0; s < 8; ++s) {
            int row = row0 + s;
            float v = bf2f(xb[(size_t)row * 1184 + 1152 + hh]) + dtbv;
            float sp = (v > 20.f) ? v : log1pf(expf(v));
            dtO[row * 16 + hh] = sp;
            dAO[row * 16 + hh] = nal * sp;
        }
    }
}

// ======== SSD chunked scan ========
__global__ __launch_bounds__(256) void k_ssd_state(
    const u16* __restrict__ xc0, const float* __restrict__ dt0, const float* __restrict__ ld0,
    const u16* __restrict__ xc1, const float* __restrict__ dt1, const float* __restrict__ ld1,
    float* __restrict__ S, float* __restrict__ Aprod) {
    int blk = blockIdx.x;
    int c = blk & 31, h = (blk >> 5) & 15, b = (blk >> 9) & 1, dir = blk >> 10;
    const u16* xc = dir ? xc1 : xc0;
    const float* dtp = dir ? dt1 : dt0;
    const float* ldp = dir ? ld1 : ld0;
    const int t = threadIdx.x, w = t >> 6, lane = t & 63;
    const int fr = lane & 15, fk = (lane >> 4) * 8;

    __shared__ __align__(16) u16 sBt[64 * 72];
    __shared__ __align__(16) u16 sXp[64 * 72];
    __shared__ float ssc[64];
    size_t row0 = (size_t)b * 2048 + c * 64;

    if (t < 64) {
        float v = ldp[(row0 + t) * 16 + h];
        float dtv = dtp[(row0 + t) * 16 + h];
        #pragma unroll
        for (int o = 1; o < 64; o <<= 1) {
            float u = __shfl_up(v, o);
            if (lane >= o) v += u;
        }
        float last = __shfl(v, 63);
        ssc[t] = dtv * expf(last - v);
        if (t == 63) Aprod[blk] = expf(v);
    }
    __syncthreads();
    #pragma unroll
    for (int i2 = t; i2 < 512; i2 += 256) {
        int r = i2 >> 3, e8 = (i2 & 7) * 8;
        size_t rb = (row0 + r) * 1152;
        uint4 bv = *(const uint4*)(xc + rb + 1024 + e8);
        uint4 xv = *(const uint4*)(xc + rb + h * 64 + e8);
        const u16* bs = (const u16*)&bv;
        const u16* xs = (const u16*)&xv;
        float sc = ssc[r];
        #pragma unroll
        for (int j = 0; j < 8; ++j) {
            sBt[(e8 + j) * 72 + r] = bs[j];
            sXp[(e8 + j) * 72 + r] = f2bf(bf2f(xs[j]) * sc);
        }
    }
    __syncthreads();

    f32x4 acc[4];
    #pragma unroll
    for (int j = 0; j < 4; ++j) acc[j] = (f32x4){0.f, 0.f, 0.f, 0.f};
    #pragma unroll
    for (int k0 = 0; k0 < 64; k0 += 32) {
        bf16x8 a = *(const bf16x8*)(sBt + (w * 16 + fr) * 72 + k0 + fk);
        #pragma unroll
        for (int j = 0; j < 4; ++j) {
            bf16x8 bb = *(const bf16x8*)(sXp + (j * 16 + fr) * 72 + k0 + fk);
            acc[j] = __builtin_amdgcn_mfma_f32_16x16x32_bf16(a, bb, acc[j], 0, 0, 0);
        }
    }
    float* Sb = S + (size_t)blk * 4096;
    int nb = w * 16 + (lane >> 4) * 4;
    #pragma unroll
    for (int j = 0; j < 4; ++j) {
        int p = j * 16 + fr;
        *(f32x4*)(Sb + p * 64 + nb) = acc[j];
    }
}

__global__ __launch_bounds__(256) void k_scan_carry(float* __restrict__ S,
                                                    const float* __restrict__ Aprod) {
    int blk = blockIdx.x;
    int t = threadIdx.x;
    float h[16];
    #pragma unroll
    for (int j = 0; j < 16; ++j) h[j] = 0.f;
    for (int c = 0; c < 32; ++c) {
        float a = Aprod[blk * 32 + c];
        float* Sp = S + ((size_t)blk * 32 + c) * 4096 + t * 16;
        float4 s0 = *(float4*)(Sp + 0), s1 = *(float4*)(Sp + 4);
        float4 s2 = *(float4*)(Sp + 8), s3 = *(float4*)(Sp + 12);
        *(float4*)(Sp + 0) = make_float4(h[0], h[1], h[2], h[3]);
        *(float4*)(Sp + 4) = make_float4(h[4], h[5], h[6], h[7]);
        *(float4*)(Sp + 8) = make_float4(h[8], h[9], h[10], h[11]);
        *(float4*)(Sp + 12) = make_float4(h[12], h[13], h[14], h[15]);
        h[0] = a * h[0] + s0.x; h[1] = a * h[1] + s0.y; h[2] = a * h[2] + s0.z; h[3] = a * h[3] + s0.w;
        h[4] = a * h[4] + s1.x; h[5] = a * h[5] + s1.y; h[6] = a * h[6] + s1.z; h[7] = a * h[7] + s1.w;
        h[8] = a * h[8] + s2.x; h[9] = a * h[9] + s2.y; h[10] = a * h[10] + s2.z; h[11] = a * h[11] + s2.w;
        h[12] = a * h[12] + s3.x; h[13] = a * h[13] + s3.y; h[14] = a * h[14] + s3.z; h[15] = a * h[15] + s3.w;
    }
}

__global__ __launch_bounds__(256) void k_ssd_y(
    const u16* __restrict__ xc0, const float* __restrict__ dt0, const float* __restrict__ ld0,
    const float* __restrict__ Dv0, u16* __restrict__ y0,
    const u16* __restrict__ xc1, const float* __restrict__ dt1, const float* __restrict__ ld1,
    const float* __restrict__ Dv1, u16* __restrict__ y1,
    const float* __restrict__ S) {
    int blk = blockIdx.x;
    int c = blk & 31, h = (blk >> 5) & 15, b = (blk >> 9) & 1, dir = blk >> 10;
    const u16* xc = dir ? xc1 : xc0;
    const float* dtp = dir ? dt1 : dt0;
    const float* ldp = dir ? ld1 : ld0;
    u16* y = dir ? y1 : y0;
    const float Dh = (dir ? Dv1 : Dv0)[h];
    const int t = threadIdx.x, w = t >> 6, lane = t & 63;
    const int fr = lane & 15, fk = (lane >> 4) * 8;

    __shared__ __align__(16) u16 sB[64 * 72];
    __shared__ __align__(16) u16 sC[64 * 72];
    __shared__ __align__(16) u16 sXp[64 * 72];
    __shared__ __align__(16) u16 sHi[64 * 72];
    __shared__ __align__(16) u16 sLo[64 * 72];
    __shared__ __align__(16) u16 sGl[64 * 72];
    __shared__ float scl[64], sdt[64];
    size_t row0 = (size_t)b * 2048 + c * 64;

    if (t < 64) {
        float v = ldp[(row0 + t) * 16 + h];
        float dtv = dtp[(row0 + t) * 16 + h];
        #pragma unroll
        for (int o = 1; o < 64; o <<= 1) {
            float u = __shfl_up(v, o);
            if (lane >= o) v += u;
        }
        scl[t] = v;
        sdt[t] = dtv;
    }
    __syncthreads();
    #pragma unroll
    for (int i2 = t; i2 < 512; i2 += 256) {
        int r = i2 >> 3, e8 = (i2 & 7) * 8;
        size_t rb = (row0 + r) * 1152;
        *(uint4*)(sB + r * 72 + e8) = *(const uint4*)(xc + rb + 1024 + e8);
        *(uint4*)(sC + r * 72 + e8) = *(const uint4*)(xc + rb + 1088 + e8);
        uint4 xv = *(const uint4*)(xc + rb + h * 64 + e8);
        const u16* xs = (const u16*)&xv;
        float dtv = sdt[r];
        #pragma unroll
        for (int j = 0; j < 8; ++j) sXp[(e8 + j) * 72 + r] = f2bf(bf2f(xs[j]) * dtv);
    }
    #pragma unroll
    for (int i4 = t; i4 < 1024; i4 += 256) {
        int p = i4 >> 4, n4 = (i4 & 15) * 4;
        float4 hv = *(const float4*)(S + (size_t)blk * 4096 + p * 64 + n4);
        ushort4 hi4, lo4;
        hi4.x = f2bf(hv.x); lo4.x = f2bf(hv.x - bf2f(hi4.x));
        hi4.y = f2bf(hv.y); lo4.y = f2bf(hv.y - bf2f(hi4.y));
        hi4.z = f2bf(hv.z); lo4.z = f2bf(hv.z - bf2f(hi4.z));
        hi4.w = f2bf(hv.w); lo4.w = f2bf(hv.w - bf2f(hi4.w));
        *(ushort4*)(sHi + p * 72 + n4) = hi4;
        *(ushort4*)(sLo + p * 72 + n4) = lo4;
    }
    __syncthreads();

    f32x4 g[4], acc2[4];
    #pragma unroll
    for (int j = 0; j < 4; ++j) { g[j] = (f32x4){0.f,0.f,0.f,0.f}; acc2[j] = (f32x4){0.f,0.f,0.f,0.f}; }
    #pragma unroll
    for (int k0 = 0; k0 < 64; k0 += 32) {
        bf16x8 a = *(const bf16x8*)(sC + (w * 16 + fr) * 72 + k0 + fk);
        #pragma unroll
        for (int j = 0; j < 4; ++j) {
            bf16x8 bb = *(const bf16x8*)(sB + (j * 16 + fr) * 72 + k0 + fk);
            g[j] = __builtin_amdgcn_mfma_f32_16x16x32_bf16(a, bb, g[j], 0, 0, 0);
            bf16x8 bh = *(const bf16x8*)(sHi + (j * 16 + fr) * 72 + k0 + fk);
            acc2[j] = __builtin_amdgcn_mfma_f32_16x16x32_bf16(a, bh, acc2[j], 0, 0, 0);
            bf16x8 bl = *(const bf16x8*)(sLo + (j * 16 + fr) * 72 + k0 + fk);
            acc2[j] = __builtin_amdgcn_mfma_f32_16x16x32_bf16(a, bl, acc2[j], 0, 0, 0);
        }
    }
    #pragma unroll
    for (int j = 0; j < 4; ++j) {
        int r = j * 16 + fr;
        #pragma unroll
        for (int reg = 0; reg < 4; ++reg) {
            int s = w * 16 + (lane >> 4) * 4 + reg;
            float val = (r <= s) ? expf(scl[s] - scl[r]) * g[j][reg] : 0.f;
            sGl[s * 72 + r] = f2bf(val);
        }
    }
    __syncthreads();

    f32x4 acc1[4];
    #pragma unroll
    for (int j = 0; j < 4; ++j) acc1[j] = (f32x4){0.f, 0.f, 0.f, 0.f};
    #pragma unroll
    for (int k0 = 0; k0 < 64; k0 += 32) {
        bf16x8 a = *(const bf16x8*)(sGl + (w * 16 + fr) * 72 + k0 + fk);
        #pragma unroll
        for (int j = 0; j < 4; ++j) {
            bf16x8 bb = *(const bf16x8*)(sXp + (j * 16 + fr) * 72 + k0 + fk);
            acc1[j] = __builtin_amdgcn_mfma_f32_16x16x32_bf16(a, bb, acc1[j], 0, 0, 0);
        }
    }
    #pragma unroll
    for (int reg = 0; reg < 4; ++reg) {
        int s = w * 16 + (lane >> 4) * 4 + reg;
        float es = expf(scl[s]);
        size_t yrb = (row0 + s) * 1024 + h * 64;
        size_t xrb = (row0 + s) * 1152 + h * 64;
        #pragma unroll
        for (int j = 0; j < 4; ++j) {
            int p = j * 16 + fr;
            float xv = bf2f(xc[xrb + p]);
            y[yrb + p] = f2bf(acc1[j][reg] + es * acc2[j][reg] + xv * Dh);
        }
    }
}

// ---------------- gated RMS norm ----------------
__global__ __launch_bounds__(256) void k_gnorm(
    const u16* __restrict__ y0, const u16* __restrict__ z0,
    const float* __restrict__ gw0, u16* __restrict__ o0,
    const u16* __restrict__ y1, const u16* __restrict__ z1,
    const float* __restrict__ gw1, u16* __restrict__ o1) {
    __shared__ float red[4];
    int r = blockIdx.x;
    int dir = r >> 12, row = r & 4095;
    int t = threadIdx.x;
    const u16* y = dir ? y1 : y0;
    const u16* zp = dir ? z1 : z0;
    const float* gw = dir ? gw1 : gw0;
    u16* o = dir ? o1 : o0;
    ushort4 yv = *(const ushort4*)(y + (size_t)row * 1024 + t * 4);
    ushort4 zr = *(const ushort4*)(zp + (size_t)row * 1024 + t * 4);
    float z0f = bf2f(zr.x), z1f = bf2f(zr.y), z2f = bf2f(zr.z), z3f = bf2f(zr.w);
    float v0 = bf2f(yv.x) * (z0f / (1.f + expf(-z0f)));
    float v1 = bf2f(yv.y) * (z1f / (1.f + expf(-z1f)));
    float v2 = bf2f(yv.z) * (z2f / (1.f + expf(-z2f)));
    float v3 = bf2f(yv.w) * (z3f / (1.f + expf(-z3f)));
    float ss = block_sum_256(v0 * v0 + v1 * v1 + v2 * v2 + v3 * v3, red);
    float sc = rsqrtf(ss * (1.f / 1024.f) + 1e-5f);
    float4 gv = *(const float4*)(gw + t * 4);
    size_t ob = (size_t)row * 1024 + t * 4;
    o[ob + 0] = f2bf(v0 * sc * gv.x);
    o[ob + 1] = f2bf(v1 * sc * gv.y);
    o[ob + 2] = f2bf(v2 * sc * gv.z);
    o[ob + 3] = f2bf(v3 * sc * gv.w);
}

// ---- fused: x2 = x + (fwd+flip(bwd))*mask; rms(x2)*nfw -> bf16; out init = x2 + b2 ----
__global__ __launch_bounds__(256) void k_add_rms(
    const float* __restrict__ x, const u16* __restrict__ of,
    const u16* __restrict__ ob, const float* __restrict__ mask,
    const float* __restrict__ wrms, const float* __restrict__ b2,
    float* __restrict__ x2, u16* __restrict__ o, float* __restrict__ outf) {
    __shared__ float red[4];
    int row = blockIdx.x, t = threadIdx.x;
    int bb = row >> 11, tl = row & 2047;
    size_t fb = (size_t)((bb << 11) + (2047 - tl)) * 512;
    float m = mask[row];
    size_t base = (size_t)row * 512 + t * 2;
    size_t fo = fb + t * 2;
    float2 xv = *(const float2*)(x + base);
    float v0 = xv.x + (bf2f(of[base]) + bf2f(ob[fo])) * m;
    float v1 = xv.y + (bf2f(of[base + 1]) + bf2f(ob[fo + 1])) * m;
    x2[base] = v0;
    x2[base + 1] = v1;
    float2 b2v = *(const float2*)(b2 + t * 2);
    outf[base] = v0 + b2v.x;
    outf[base + 1] = v1 + b2v.y;
    float ss = block_sum_256(v0 * v0 + v1 * v1, red);
    float sc = rsqrtf(ss * (1.f / 512.f) + 1.1920929e-07f);
    float2 wv = *(const float2*)(wrms + t * 2);
    o[base] = f2bf(v0 * sc * wv.x);
    o[base + 1] = f2bf(v1 * sc * wv.y);
}

extern "C" void kernel_launch(void* const* d_in, const int* in_sizes, int n_in,
                              void* d_out, int out_size, void* d_ws, size_t ws_size,
                              hipStream_t stream) {
    const float* x = (const float*)d_in[0];
    const float* pe = (const float*)d_in[1];
    const float* mask = (const float*)d_in[2];
    const float* nsw = (const float*)d_in[3];
    const float* nfw = (const float*)d_in[4];
    const float* w1 = (const float*)d_in[5];
    const float* b1 = (const float*)d_in[6];
    const float* w2 = (const float*)d_in[7];
    const float* b2 = (const float*)d_in[8];
    const float* f_inw = (const float*)d_in[9];
    const float* f_cw = (const float*)d_in[10];
    const float* f_cb = (const float*)d_in[11];
    const float* f_dtb = (const float*)d_in[12];
    const float* f_al = (const float*)d_in[13];
    const float* f_D = (const float*)d_in[14];
    const float* f_gw = (const float*)d_in[15];
    const float* f_ow = (const float*)d_in[16];
    const float* b_inw = (const float*)d_in[17];
    const float* b_cw = (const float*)d_in[18];
    const float* b_cb = (const float*)d_in[19];
    const float* b_dtb = (const float*)d_in[20];
    const float* b_al = (const float*)d_in[21];
    const float* b_D = (const float*)d_in[22];
    const float* b_gw = (const float*)d_in[23];
    const float* b_ow = (const float*)d_in[24];
    float* out = (float*)d_out;

    char* ws = (char*)d_ws;
    u16* Z0   = (u16*)(ws + 0);
    u16* Z1   = (u16*)(ws + 8388608);
    u16* XB0  = (u16*)(ws + 16777216);
    u16* XB1  = (u16*)(ws + 26476544);
    u16* INWF = (u16*)(ws + 36175872);
    u16* INWB = (u16*)(ws + 38535168);
    u16* SIB  = (u16*)(ws + 40894464);
    u16* XC0  = (u16*)(ws + 36175872);
    u16* XC1  = (u16*)(ws + 45613056);
    float* dtF = (float*)(ws + 55050240);
    float* dAF = (float*)(ws + 55312384);
    float* dtB = (float*)(ws + 55574528);
    float* dAB = (float*)(ws + 55836672);
    u16* Y0   = (u16*)(ws + 16777216);
    u16* Y1   = (u16*)(ws + 25165824);
    u16* YG0  = (u16*)(ws + 36175872);
    u16* YG1  = (u16*)(ws + 44564480);
    u16* OP0  = (u16*)(ws + 0);
    u16* OP1  = (u16*)(ws + 4194304);
    float* X2 = (float*)(ws + 8388608);
    u16* X2B  = (u16*)(ws + 0);
    u16* HACT = (u16*)(ws + 16777216);
    u16* OWF = (u16*)(ws + 56098816);
    u16* OWB = (u16*)(ws + 57147392);
    u16* W1B = (u16*)(ws + 58195968);
    u16* W2B = (u16*)(ws + 60293120);
    float* SBUF = (float*)(ws + 62390272);
    float* APR  = (float*)(ws + 95944704);

    k_cvt_all<<<21504, 256, 0, stream>>>(f_inw, b_inw, f_ow, b_ow, w1, w2,
                                         INWF, INWB, OWF, OWB, W1B, W2B);
    k_rms_pos<<<4096, 256, 0, stream>>>(x, pe, nsw, SIB);
    k_gemm_in<<<dim3(18, 32, 2), 256, 0, stream>>>(SIB, INWF, INWB, Z0, Z1, XB0, XB1);
    k_conv<<<1024, 160, 0, stream>>>(XB0, XB1, f_cw, f_cb, f_dtb, f_al,
                                     b_cw, b_cb, b_dtb, b_al,
                                     XC0, XC1, dtF, dAF, dtB, dAB);
    k_ssd_state<<<2048, 256, 0, stream>>>(XC0, dtF, dAF, XC1, dtB, dAB, SBUF, APR);
    k_scan_carry<<<64, 256, 0, stream>>>(SBUF, APR);
    k_ssd_y<<<2048, 256, 0, stream>>>(XC0, dtF, dAF, f_D, Y0,
                                      XC1, dtB, dAB, b_D, Y1, SBUF);
    k_gnorm<<<8192, 256, 0, stream>>>(Y0, Z0, f_gw, YG0, Y1, Z1, b_gw, YG1);
    k_gemm64<0><<<dim3(8, 64, 2), 256, 0, stream>>>(YG0, YG1, OWF, OWB, OP0, OP1, 512, 1024,
                                                    nullptr, nullptr);
    k_add_rms<<<4096, 256, 0, stream>>>(x, OP0, OP1, mask, nfw, b2, X2, X2B, out);
    k_gemm64<1><<<dim3(32, 64, 1), 256, 0, stream>>>(X2B, X2B, W1B, W1B, HACT, HACT, 2048, 512,
                                                     b1, nullptr);
    k_gemm64<3><<<dim3(8, 64, 2), 256, 0, stream>>>(HACT, HACT, W2B, W2B, nullptr, nullptr,
                                                    512, 2048, nullptr, out);
}

// Round 12
// 344.337 us; speedup vs baseline: 5.3794x; 1.0254x over previous
//
#include <hip/hip_runtime.h>
#include <hip/hip_bf16.h>

typedef unsigned short u16;
typedef unsigned int u32;
typedef __bf16 bf16x8 __attribute__((ext_vector_type(8)));
typedef float f32x4 __attribute__((ext_vector_type(4)));

typedef __attribute__((address_space(1))) void gvoid_t;
typedef __attribute__((address_space(3))) void lvoid_t;
__device__ __forceinline__ void lds_cp16(void* lds, const void* g) {
    __builtin_amdgcn_global_load_lds((gvoid_t*)g, (lvoid_t*)lds, 16, 0, 0);
}

__device__ __forceinline__ float bf2f(u16 v) {
    u32 x = (u32)v << 16;
    return __builtin_bit_cast(float, x);
}
__device__ __forceinline__ u16 f2bf(float f) {
    return __builtin_bit_cast(u16, (__bf16)f);
}

// ---------------- block reduction (256 threads = 4 waves) ----------------
__device__ __forceinline__ float block_sum_256(float v, float* red) {
    #pragma unroll
    for (int o = 32; o > 0; o >>= 1) v += __shfl_xor(v, o);
    int w = threadIdx.x >> 6;
    if ((threadIdx.x & 63) == 0) red[w] = v;
    __syncthreads();
    return red[0] + red[1] + red[2] + red[3];
}

// ---------------- fused: weight conversions + rms_pos (one launch) ----------------
// blocks [0, 21504): cvt; blocks [21504, 25600): rms_pos row = blk - 21504.
__global__ __launch_bounds__(256) void k_prep(
    const float* __restrict__ f_inw, const float* __restrict__ b_inw,
    const float* __restrict__ f_ow, const float* __restrict__ b_ow,
    const float* __restrict__ w1, const float* __restrict__ w2,
    u16* __restrict__ INWF, u16* __restrict__ INWB,
    u16* __restrict__ OWF, u16* __restrict__ OWB,
    u16* __restrict__ W1B, u16* __restrict__ W2B,
    const float* __restrict__ x, const float* __restrict__ pe,
    const float* __restrict__ wrms, u16* __restrict__ sib) {
    if (blockIdx.x < 21504) {
        int i = blockIdx.x * 256 + threadIdx.x;
        if (i < 1179648) { int n = i >> 9; INWF[i] = (n < 2192) ? f2bf(f_inw[i]) : (u16)0; return; }
        i -= 1179648;
        if (i < 1179648) { int n = i >> 9; INWB[i] = (n < 2192) ? f2bf(b_inw[i]) : (u16)0; return; }
        i -= 1179648;
        if (i < 524288) { OWF[i] = f2bf(f_ow[i]); return; }
        i -= 524288;
        if (i < 524288) { OWB[i] = f2bf(b_ow[i]); return; }
        i -= 524288;
        if (i < 1048576) { W1B[i] = f2bf(w1[i]); return; }
        i -= 1048576;
        if (i < 1048576) W2B[i] = f2bf(w2[i]);
        return;
    }
    __shared__ float red[4];
    int row = blockIdx.x - 21504, t = threadIdx.x;
    size_t base = (size_t)row * 512 + t * 2;
    float2 xv = *(const float2*)(x + base);
    float ss = block_sum_256(xv.x * xv.x + xv.y * xv.y, red);
    float sc = rsqrtf(ss * (1.f / 512.f) + 1.1920929e-07f);
    float2 pv = *(const float2*)(pe + base);
    float2 wv = *(const float2*)(wrms + t * 2);
    sib[base] = f2bf(xv.x * sc * wv.x + pv.x);
    sib[base + 1] = f2bf(xv.y * sc * wv.y + pv.y);
}

// ---------------- in_proj GEMM, BK=64 (async LDS staging) ----------------
__global__ __launch_bounds__(256) void k_gemm_in(
    const u16* __restrict__ A, const u16* __restrict__ W0, const u16* __restrict__ W1,
    u16* __restrict__ Z0, u16* __restrict__ Z1,
    u16* __restrict__ XB0, u16* __restrict__ XB1) {
    const int z = blockIdx.z;
    const u16* W = z ? W1 : W0;
    u16* Z = z ? Z1 : Z0;
    u16* XB = z ? XB1 : XB0;
    const int K = 512;

    __shared__ __align__(16) u16 As[128 * 64];
    __shared__ __align__(16) u16 Bs[128 * 64];

    const int t = threadIdx.x;
    const int lane = t & 63;
    const int w = t >> 6;
    const int m0 = blockIdx.y * 128;
    const int n0 = blockIdx.x * 128;
    const int wm = (w >> 1) * 64;
    const int wn = (w & 1) * 64;
    const int fr = lane & 15;
    const int fk = (lane >> 4) * 8;

    f32x4 acc[4][4];
    #pragma unroll
    for (int i = 0; i < 4; ++i)
        #pragma unroll
        for (int j = 0; j < 4; ++j) acc[i][j] = (f32x4){0.f, 0.f, 0.f, 0.f};

    for (int kt = 0; kt < K; kt += 64) {
        #pragma unroll
        for (int j = 0; j < 4; ++j) {
            int off16 = j * 256 + t;        // 0..1023
            int row = off16 >> 3;           // 0..127
            int kc = (off16 & 7) * 8;
            int gm = m0 + row;
            if (z) gm = (gm & ~2047) | (2047 - (gm & 2047));
            lds_cp16(As + off16 * 8, A + (size_t)gm * K + kt + kc);
            lds_cp16(Bs + off16 * 8, W + (size_t)(n0 + row) * K + kt + kc);
        }
        __syncthreads();
        #pragma unroll
        for (int k0 = 0; k0 < 64; k0 += 32) {
            bf16x8 af[4], bfr[4];
            #pragma unroll
            for (int i = 0; i < 4; ++i) af[i] = *(const bf16x8*)(As + (wm + i * 16 + fr) * 64 + k0 + fk);
            #pragma unroll
            for (int i = 0; i < 4; ++i) bfr[i] = *(const bf16x8*)(Bs + (wn + i * 16 + fr) * 64 + k0 + fk);
            #pragma unroll
            for (int i = 0; i < 4; ++i)
                #pragma unroll
                for (int j = 0; j < 4; ++j)
                    acc[i][j] = __builtin_amdgcn_mfma_f32_16x16x32_bf16(af[i], bfr[j], acc[i][j], 0, 0, 0);
        }
        __syncthreads();
    }
    #pragma unroll
    for (int i = 0; i < 4; ++i) {
        int rbase = m0 + wm + i * 16 + (lane >> 4) * 4;
        #pragma unroll
        for (int j = 0; j < 4; ++j) {
            int c = n0 + wn + j * 16 + fr;
            #pragma unroll
            for (int r = 0; r < 4; ++r) {
                u16 v = f2bf(acc[i][j][r]);
                int m = rbase + r;
                if (c < 1024) Z[(size_t)m * 1024 + c] = v;
                else if (c < 2192) XB[(size_t)m * 1184 + (c - 1024)] = v;
            }
        }
    }
}

// ---------------- 64x64-tile GEMM (high-occupancy, async staging) ----------------
// EPI 0: bf16 store (z=dir); 1: gelu(acc+bias)->bf16; 3: split-K atomicAdd f32.
template <int EPI>
__global__ __launch_bounds__(256) void k_gemm64(
    const u16* __restrict__ A0, const u16* __restrict__ A1,
    const u16* __restrict__ W0, const u16* __restrict__ W1,
    u16* __restrict__ C0, u16* __restrict__ C1, int N, int K,
    const float* __restrict__ bias, float* __restrict__ outf) {
    const int z = blockIdx.z;
    const u16* A = (EPI == 3) ? A0 : (z ? A1 : A0);
    const u16* W = (EPI == 3) ? W0 : (z ? W1 : W0);
    u16* C = z ? C1 : C0;
    int kbeg = 0, kend = K;
    if (EPI == 3) { kbeg = z * (K >> 1); kend = kbeg + (K >> 1); }

    __shared__ __align__(16) u16 As[64 * 32];
    __shared__ __align__(16) u16 Bs[64 * 32];

    const int t = threadIdx.x;
    const int lane = t & 63;
    const int w = t >> 6;
    const int m0 = blockIdx.y * 64;
    const int n0 = blockIdx.x * 64;
    const int wm = (w >> 1) * 32;
    const int wn = (w & 1) * 32;
    const int fr = lane & 15;
    const int fk = (lane >> 4) * 8;

    f32x4 acc[2][2];
    #pragma unroll
    for (int i = 0; i < 2; ++i)
        #pragma unroll
        for (int j = 0; j < 2; ++j) acc[i][j] = (f32x4){0.f, 0.f, 0.f, 0.f};

    const int srow = t >> 2;
    const int skc = (t & 3) * 8;
    for (int kt = kbeg; kt < kend; kt += 32) {
        lds_cp16(As + t * 8, A + (size_t)(m0 + srow) * K + kt + skc);
        lds_cp16(Bs + t * 8, W + (size_t)(n0 + srow) * K + kt + skc);
        __syncthreads();
        bf16x8 af[2], bfr[2];
        #pragma unroll
        for (int i = 0; i < 2; ++i) af[i] = *(const bf16x8*)(As + (wm + i * 16 + fr) * 32 + fk);
        #pragma unroll
        for (int j = 0; j < 2; ++j) bfr[j] = *(const bf16x8*)(Bs + (wn + j * 16 + fr) * 32 + fk);
        #pragma unroll
        for (int i = 0; i < 2; ++i)
            #pragma unroll
            for (int j = 0; j < 2; ++j)
                acc[i][j] = __builtin_amdgcn_mfma_f32_16x16x32_bf16(af[i], bfr[j], acc[i][j], 0, 0, 0);
        __syncthreads();
    }
    #pragma unroll
    for (int i = 0; i < 2; ++i) {
        int rbase = m0 + wm + i * 16 + (lane >> 4) * 4;
        #pragma unroll
        for (int j = 0; j < 2; ++j) {
            int col = n0 + wn + j * 16 + fr;
            #pragma unroll
            for (int r = 0; r < 4; ++r) {
                int m = rbase + r;
                float v = acc[i][j][r];
                if (EPI == 0) {
                    C[(size_t)m * N + col] = f2bf(v);
                } else if (EPI == 1) {
                    float xg = v + bias[col];
                    C[(size_t)m * N + col] = f2bf(0.5f * xg * (1.f + erff(xg * 0.70710678118654752f)));
                } else {
                    atomicAdd(outf + (size_t)m * N + col, v);
                }
            }
        }
    }
}

// ---------------- causal conv4 + silu, 8 rows/block sliding window ----------------
__global__ __launch_bounds__(160) void k_conv(
    const u16* __restrict__ xb0, const u16* __restrict__ xb1,
    const float* __restrict__ cw0, const float* __restrict__ cb0,
    const float* __restrict__ dtb0, const float* __restrict__ al0,
    const float* __restrict__ cw1, const float* __restrict__ cb1,
    const float* __restrict__ dtb1, const float* __restrict__ al1,
    u16* __restrict__ xc0, u16* __restrict__ xc1,
    float* __restrict__ dtO0, float* __restrict__ dAO0,
    float* __restrict__ dtO1, float* __restrict__ dAO1) {
    int g = blockIdx.x;
    int dir = g >> 9;
    int row0 = (g & 511) * 8;
    const u16* xb = dir ? xb1 : xb0;
    const float* cw = dir ? cw1 : cw0;
    const float* cb = dir ? cb1 : cb0;
    const float* dtb = dir ? dtb1 : dtb0;
    const float* al = dir ? al1 : al0;
    u16* xc = dir ? xc1 : xc0;
    float* dtO = dir ? dtO1 : dtO0;
    float* dAO = dir ? dAO1 : dAO0;
    int tl0 = row0 & 2047;
    int rbatch = row0 - tl0;
    int t = threadIdx.x;
    if (t < 144) {
        int col = t * 8;
        float cwa[8][4];
        #pragma unroll
        for (int j = 0; j < 8; ++j) {
            float4 c4 = *(const float4*)(cw + (col + j) * 4);
            cwa[j][0] = c4.x; cwa[j][1] = c4.y; cwa[j][2] = c4.z; cwa[j][3] = c4.w;
        }
        float cbv[8];
        float4 cb0v = *(const float4*)(cb + col);
        float4 cb1v = *(const float4*)(cb + col + 4);
        cbv[0] = cb0v.x; cbv[1] = cb0v.y; cbv[2] = cb0v.z; cbv[3] = cb0v.w;
        cbv[4] = cb1v.x; cbv[5] = cb1v.y; cbv[6] = cb1v.z; cbv[7] = cb1v.w;
        uint4 win[4];
        win[0] = win[1] = win[2] = make_uint4(0, 0, 0, 0);
        #pragma unroll
        for (int i = 0; i < 3; ++i) {
            int tt = tl0 - 3 + i;
            if (tt >= 0) win[i] = *(const uint4*)(xb + (size_t)(rbatch + tt) * 1184 + col);
        }
        for (int s = 0; s < 8; ++s) {
            win[3] = *(const uint4*)(xb + (size_t)(rbatch + tl0 + s) * 1184 + col);
            const u16* w0 = (const u16*)&win[0];
            const u16* w1 = (const u16*)&win[1];
            const u16* w2 = (const u16*)&win[2];
            const u16* w3 = (const u16*)&win[3];
            u16 ov[8];
            #pragma unroll
            for (int j = 0; j < 8; ++j) {
                float a = cbv[j] + bf2f(w0[j]) * cwa[j][0] + bf2f(w1[j]) * cwa[j][1]
                        + bf2f(w2[j]) * cwa[j][2] + bf2f(w3[j]) * cwa[j][3];
                ov[j] = f2bf(a / (1.f + expf(-a)));
            }
            *(uint4*)(xc + (size_t)(row0 + s) * 1152 + col) = *(const uint4*)ov;
            win[0] = win[1]; win[1] = win[2]; win[2] = win[3];
        }
    } else if (t < 160) {
        int hh = t - 144;
        float nal = -expf(al[hh]);
        float dtbv = dtb[hh];
        for (int s = 0; s < 8; ++s) {
            int row = row0 + s;
            float v = bf2f(xb[(size_t)row * 1184 + 1152 + hh]) + dtbv;
            float sp = (v > 20.f) ? v : log1pf(expf(v));
            dtO[row * 16 + hh] = sp;
            dAO[row * 16 + hh] = nal * sp;
        }
    }
}

// ======== SSD chunked scan ========
__global__ __launch_bounds__(256) void k_ssd_state(
    const u16* __restrict__ xc0, const float* __restrict__ dt0, const float* __restrict__ ld0,
    const u16* __restrict__ xc1, const float* __restrict__ dt1, const float* __restrict__ ld1,
    float* __restrict__ S, float* __restrict__ Aprod) {
    int blk = blockIdx.x;
    int c = blk & 31, h = (blk >> 5) & 15, b = (blk >> 9) & 1, dir = blk >> 10;
    const u16* xc = dir ? xc1 : xc0;
    const float* dtp = dir ? dt1 : dt0;
    const float* ldp = dir ? ld1 : ld0;
    const int t = threadIdx.x, w = t >> 6, lane = t & 63;
    const int fr = lane & 15, fk = (lane >> 4) * 8;

    __shared__ __align__(16) u16 sBt[64 * 72];
    __shared__ __align__(16) u16 sXp[64 * 72];
    __shared__ float ssc[64];
    size_t row0 = (size_t)b * 2048 + c * 64;

    if (t < 64) {
        float v = ldp[(row0 + t) * 16 + h];
        float dtv = dtp[(row0 + t) * 16 + h];
        #pragma unroll
        for (int o = 1; o < 64; o <<= 1) {
            float u = __shfl_up(v, o);
            if (lane >= o) v += u;
        }
        float last = __shfl(v, 63);
        ssc[t] = dtv * expf(last - v);
        if (t == 63) Aprod[blk] = expf(v);
    }
    __syncthreads();
    #pragma unroll
    for (int i2 = t; i2 < 512; i2 += 256) {
        int r = i2 >> 3, e8 = (i2 & 7) * 8;
        size_t rb = (row0 + r) * 1152;
        uint4 bv = *(const uint4*)(xc + rb + 1024 + e8);
        uint4 xv = *(const uint4*)(xc + rb + h * 64 + e8);
        const u16* bs = (const u16*)&bv;
        const u16* xs = (const u16*)&xv;
        float sc = ssc[r];
        #pragma unroll
        for (int j = 0; j < 8; ++j) {
            sBt[(e8 + j) * 72 + r] = bs[j];
            sXp[(e8 + j) * 72 + r] = f2bf(bf2f(xs[j]) * sc);
        }
    }
    __syncthreads();

    f32x4 acc[4];
    #pragma unroll
    for (int j = 0; j < 4; ++j) acc[j] = (f32x4){0.f, 0.f, 0.f, 0.f};
    #pragma unroll
    for (int k0 = 0; k0 < 64; k0 += 32) {
        bf16x8 a = *(const bf16x8*)(sBt + (w * 16 + fr) * 72 + k0 + fk);
        #pragma unroll
        for (int j = 0; j < 4; ++j) {
            bf16x8 bb = *(const bf16x8*)(sXp + (j * 16 + fr) * 72 + k0 + fk);
            acc[j] = __builtin_amdgcn_mfma_f32_16x16x32_bf16(a, bb, acc[j], 0, 0, 0);
        }
    }
    float* Sb = S + (size_t)blk * 4096;
    int nb = w * 16 + (lane >> 4) * 4;
    #pragma unroll
    for (int j = 0; j < 4; ++j) {
        int p = j * 16 + fr;
        *(f32x4*)(Sb + p * 64 + nb) = acc[j];
    }
}

// ---- Pass B: fully-parallel carry. grid 1024 = 64 blk-groups x 16; 1 element/thread ----
__global__ __launch_bounds__(256) void k_scan_carry(float* __restrict__ S,
                                                    const float* __restrict__ Aprod) {
    int g = blockIdx.x;
    int blk = g >> 4;
    int e = (g & 15) * 256 + threadIdx.x;   // 0..4095
    size_t base = (size_t)blk * 32 * 4096 + e;
    float sv[32];
    #pragma unroll
    for (int c = 0; c < 32; ++c) sv[c] = S[base + (size_t)c * 4096];
    float ap[32];
    #pragma unroll
    for (int c = 0; c < 32; ++c) ap[c] = Aprod[blk * 32 + c];
    float h = 0.f;
    #pragma unroll
    for (int c = 0; c < 32; ++c) {
        S[base + (size_t)c * 4096] = h;
        h = ap[c] * h + sv[c];
    }
}

__global__ __launch_bounds__(256) void k_ssd_y(
    const u16* __restrict__ xc0, const float* __restrict__ dt0, const float* __restrict__ ld0,
    const float* __restrict__ Dv0, u16* __restrict__ y0,
    const u16* __restrict__ xc1, const float* __restrict__ dt1, const float* __restrict__ ld1,
    const float* __restrict__ Dv1, u16* __restrict__ y1,
    const float* __restrict__ S) {
    int blk = blockIdx.x;
    int c = blk & 31, h = (blk >> 5) & 15, b = (blk >> 9) & 1, dir = blk >> 10;
    const u16* xc = dir ? xc1 : xc0;
    const float* dtp = dir ? dt1 : dt0;
    const float* ldp = dir ? ld1 : ld0;
    u16* y = dir ? y1 : y0;
    const float Dh = (dir ? Dv1 : Dv0)[h];
    const int t = threadIdx.x, w = t >> 6, lane = t & 63;
    const int fr = lane & 15, fk = (lane >> 4) * 8;

    __shared__ __align__(16) u16 sB[64 * 72];
    __shared__ __align__(16) u16 sC[64 * 72];
    __shared__ __align__(16) u16 sXp[64 * 72];
    __shared__ __align__(16) u16 sHi[64 * 72];
    __shared__ __align__(16) u16 sLo[64 * 72];
    __shared__ __align__(16) u16 sGl[64 * 72];
    __shared__ float scl[64], sdt[64];
    size_t row0 = (size_t)b * 2048 + c * 64;

    if (t < 64) {
        float v = ldp[(row0 + t) * 16 + h];
        float dtv = dtp[(row0 + t) * 16 + h];
        #pragma unroll
        for (int o = 1; o < 64; o <<= 1) {
            float u = __shfl_up(v, o);
            if (lane >= o) v += u;
        }
        scl[t] = v;
        sdt[t] = dtv;
    }
    __syncthreads();
    #pragma unroll
    for (int i2 = t; i2 < 512; i2 += 256) {
        int r = i2 >> 3, e8 = (i2 & 7) * 8;
        size_t rb = (row0 + r) * 1152;
        *(uint4*)(sB + r * 72 + e8) = *(const uint4*)(xc + rb + 1024 + e8);
        *(uint4*)(sC + r * 72 + e8) = *(const uint4*)(xc + rb + 1088 + e8);
        uint4 xv = *(const uint4*)(xc + rb + h * 64 + e8);
        const u16* xs = (const u16*)&xv;
        float dtv = sdt[r];
        #pragma unroll
        for (int j = 0; j < 8; ++j) sXp[(e8 + j) * 72 + r] = f2bf(bf2f(xs[j]) * dtv);
    }
    #pragma unroll
    for (int i4 = t; i4 < 1024; i4 += 256) {
        int p = i4 >> 4, n4 = (i4 & 15) * 4;
        float4 hv = *(const float4*)(S + (size_t)blk * 4096 + p * 64 + n4);
        ushort4 hi4, lo4;
        hi4.x = f2bf(hv.x); lo4.x = f2bf(hv.x - bf2f(hi4.x));
        hi4.y = f2bf(hv.y); lo4.y = f2bf(hv.y - bf2f(hi4.y));
        hi4.z = f2bf(hv.z); lo4.z = f2bf(hv.z - bf2f(hi4.z));
        hi4.w = f2bf(hv.w); lo4.w = f2bf(hv.w - bf2f(hi4.w));
        *(ushort4*)(sHi + p * 72 + n4) = hi4;
        *(ushort4*)(sLo + p * 72 + n4) = lo4;
    }
    __syncthreads();

    f32x4 g[4], acc2[4];
    #pragma unroll
    for (int j = 0; j < 4; ++j) { g[j] = (f32x4){0.f,0.f,0.f,0.f}; acc2[j] = (f32x4){0.f,0.f,0.f,0.f}; }
    #pragma unroll
    for (int k0 = 0; k0 < 64; k0 += 32) {
        bf16x8 a = *(const bf16x8*)(sC + (w * 16 + fr) * 72 + k0 + fk);
        #pragma unroll
        for (int j = 0; j < 4; ++j) {
            bf16x8 bb = *(const bf16x8*)(sB + (j * 16 + fr) * 72 + k0 + fk);
            g[j] = __builtin_amdgcn_mfma_f32_16x16x32_bf16(a, bb, g[j], 0, 0, 0);
            bf16x8 bh = *(const bf16x8*)(sHi + (j * 16 + fr) * 72 + k0 + fk);
            acc2[j] = __builtin_amdgcn_mfma_f32_16x16x32_bf16(a, bh, acc2[j], 0, 0, 0);
            bf16x8 bl = *(const bf16x8*)(sLo + (j * 16 + fr) * 72 + k0 + fk);
            acc2[j] = __builtin_amdgcn_mfma_f32_16x16x32_bf16(a, bl, acc2[j], 0, 0, 0);
        }
    }
    #pragma unroll
    for (int j = 0; j < 4; ++j) {
        int r = j * 16 + fr;
        #pragma unroll
        for (int reg = 0; reg < 4; ++reg) {
            int s = w * 16 + (lane >> 4) * 4 + reg;
            float val = (r <= s) ? expf(scl[s] - scl[r]) * g[j][reg] : 0.f;
            sGl[s * 72 + r] = f2bf(val);
        }
    }
    __syncthreads();

    f32x4 acc1[4];
    #pragma unroll
    for (int j = 0; j < 4; ++j) acc1[j] = (f32x4){0.f, 0.f, 0.f, 0.f};
    #pragma unroll
    for (int k0 = 0; k0 < 64; k0 += 32) {
        bf16x8 a = *(const bf16x8*)(sGl + (w * 16 + fr) * 72 + k0 + fk);
        #pragma unroll
        for (int j = 0; j < 4; ++j) {
            bf16x8 bb = *(const bf16x8*)(sXp + (j * 16 + fr) * 72 + k0 + fk);
            acc1[j] = __builtin_amdgcn_mfma_f32_16x16x32_bf16(a, bb, acc1[j], 0, 0, 0);
        }
    }
    #pragma unroll
    for (int reg = 0; reg < 4; ++reg) {
        int s = w * 16 + (lane >> 4) * 4 + reg;
        float es = expf(scl[s]);
        size_t yrb = (row0 + s) * 1024 + h * 64;
        size_t xrb = (row0 + s) * 1152 + h * 64;
        #pragma unroll
        for (int j = 0; j < 4; ++j) {
            int p = j * 16 + fr;
            float xv = bf2f(xc[xrb + p]);
            y[yrb + p] = f2bf(acc1[j][reg] + es * acc2[j][reg] + xv * Dh);
        }
    }
}

// ---------------- gated RMS norm ----------------
__global__ __launch_bounds__(256) void k_gnorm(
    const u16* __restrict__ y0, const u16* __restrict__ z0,
    const float* __restrict__ gw0, u16* __restrict__ o0,
    const u16* __restrict__ y1, const u16* __restrict__ z1,
    const float* __restrict__ gw1, u16* __restrict__ o1) {
    __shared__ float red[4];
    int r = blockIdx.x;
    int dir = r >> 12, row = r & 4095;
    int t = threadIdx.x;
    const u16* y = dir ? y1 : y0;
    const u16* zp = dir ? z1 : z0;
    const float* gw = dir ? gw1 : gw0;
    u16* o = dir ? o1 : o0;
    ushort4 yv = *(const ushort4*)(y + (size_t)row * 1024 + t * 4);
    ushort4 zr = *(const ushort4*)(zp + (size_t)row * 1024 + t * 4);
    float z0f = bf2f(zr.x), z1f = bf2f(zr.y), z2f = bf2f(zr.z), z3f = bf2f(zr.w);
    float v0 = bf2f(yv.x) * (z0f / (1.f + expf(-z0f)));
    float v1 = bf2f(yv.y) * (z1f / (1.f + expf(-z1f)));
    float v2 = bf2f(yv.z) * (z2f / (1.f + expf(-z2f)));
    float v3 = bf2f(yv.w) * (z3f / (1.f + expf(-z3f)));
    float ss = block_sum_256(v0 * v0 + v1 * v1 + v2 * v2 + v3 * v3, red);
    float sc = rsqrtf(ss * (1.f / 1024.f) + 1e-5f);
    float4 gv = *(const float4*)(gw + t * 4);
    size_t ob = (size_t)row * 1024 + t * 4;
    o[ob + 0] = f2bf(v0 * sc * gv.x);
    o[ob + 1] = f2bf(v1 * sc * gv.y);
    o[ob + 2] = f2bf(v2 * sc * gv.z);
    o[ob + 3] = f2bf(v3 * sc * gv.w);
}

// ---- fused: x2 = x + (fwd+flip(bwd))*mask; rms(x2)*nfw -> bf16; out init = x2 + b2 ----
__global__ __launch_bounds__(256) void k_add_rms(
    const float* __restrict__ x, const u16* __restrict__ of,
    const u16* __restrict__ ob, const float* __restrict__ mask,
    const float* __restrict__ wrms, const float* __restrict__ b2,
    float* __restrict__ x2, u16* __restrict__ o, float* __restrict__ outf) {
    __shared__ float red[4];
    int row = blockIdx.x, t = threadIdx.x;
    int bb = row >> 11, tl = row & 2047;
    size_t fb = (size_t)((bb << 11) + (2047 - tl)) * 512;
    float m = mask[row];
    size_t base = (size_t)row * 512 + t * 2;
    size_t fo = fb + t * 2;
    float2 xv = *(const float2*)(x + base);
    float v0 = xv.x + (bf2f(of[base]) + bf2f(ob[fo])) * m;
    float v1 = xv.y + (bf2f(of[base + 1]) + bf2f(ob[fo + 1])) * m;
    x2[base] = v0;
    x2[base + 1] = v1;
    float2 b2v = *(const float2*)(b2 + t * 2);
    outf[base] = v0 + b2v.x;
    outf[base + 1] = v1 + b2v.y;
    float ss = block_sum_256(v0 * v0 + v1 * v1, red);
    float sc = rsqrtf(ss * (1.f / 512.f) + 1.1920929e-07f);
    float2 wv = *(const float2*)(wrms + t * 2);
    o[base] = f2bf(v0 * sc * wv.x);
    o[base + 1] = f2bf(v1 * sc * wv.y);
}

extern "C" void kernel_launch(void* const* d_in, const int* in_sizes, int n_in,
                              void* d_out, int out_size, void* d_ws, size_t ws_size,
                              hipStream_t stream) {
    const float* x = (const float*)d_in[0];
    const float* pe = (const float*)d_in[1];
    const float* mask = (const float*)d_in[2];
    const float* nsw = (const float*)d_in[3];
    const float* nfw = (const float*)d_in[4];
    const float* w1 = (const float*)d_in[5];
    const float* b1 = (const float*)d_in[6];
    const float* w2 = (const float*)d_in[7];
    const float* b2 = (const float*)d_in[8];
    const float* f_inw = (const float*)d_in[9];
    const float* f_cw = (const float*)d_in[10];
    const float* f_cb = (const float*)d_in[11];
    const float* f_dtb = (const float*)d_in[12];
    const float* f_al = (const float*)d_in[13];
    const float* f_D = (const float*)d_in[14];
    const float* f_gw = (const float*)d_in[15];
    const float* f_ow = (const float*)d_in[16];
    const float* b_inw = (const float*)d_in[17];
    const float* b_cw = (const float*)d_in[18];
    const float* b_cb = (const float*)d_in[19];
    const float* b_dtb = (const float*)d_in[20];
    const float* b_al = (const float*)d_in[21];
    const float* b_D = (const float*)d_in[22];
    const float* b_gw = (const float*)d_in[23];
    const float* b_ow = (const float*)d_in[24];
    float* out = (float*)d_out;

    char* ws = (char*)d_ws;
    u16* Z0   = (u16*)(ws + 0);
    u16* Z1   = (u16*)(ws + 8388608);
    u16* XB0  = (u16*)(ws + 16777216);
    u16* XB1  = (u16*)(ws + 26476544);
    u16* INWF = (u16*)(ws + 36175872);
    u16* INWB = (u16*)(ws + 38535168);
    u16* SIB  = (u16*)(ws + 40894464);
    u16* XC0  = (u16*)(ws + 36175872);
    u16* XC1  = (u16*)(ws + 45613056);
    float* dtF = (float*)(ws + 55050240);
    float* dAF = (float*)(ws + 55312384);
    float* dtB = (float*)(ws + 55574528);
    float* dAB = (float*)(ws + 55836672);
    u16* Y0   = (u16*)(ws + 16777216);
    u16* Y1   = (u16*)(ws + 25165824);
    u16* YG0  = (u16*)(ws + 36175872);
    u16* YG1  = (u16*)(ws + 44564480);
    u16* OP0  = (u16*)(ws + 0);
    u16* OP1  = (u16*)(ws + 4194304);
    float* X2 = (float*)(ws + 8388608);
    u16* X2B  = (u16*)(ws + 0);
    u16* HACT = (u16*)(ws + 16777216);
    u16* OWF = (u16*)(ws + 56098816);
    u16* OWB = (u16*)(ws + 57147392);
    u16* W1B = (u16*)(ws + 58195968);
    u16* W2B = (u16*)(ws + 60293120);
    float* SBUF = (float*)(ws + 62390272);
    float* APR  = (float*)(ws + 95944704);

    k_prep<<<25600, 256, 0, stream>>>(f_inw, b_inw, f_ow, b_ow, w1, w2,
                                      INWF, INWB, OWF, OWB, W1B, W2B,
                                      x, pe, nsw, SIB);
    k_gemm_in<<<dim3(18, 32, 2), 256, 0, stream>>>(SIB, INWF, INWB, Z0, Z1, XB0, XB1);
    k_conv<<<1024, 160, 0, stream>>>(XB0, XB1, f_cw, f_cb, f_dtb, f_al,
                                     b_cw, b_cb, b_dtb, b_al,
                                     XC0, XC1, dtF, dAF, dtB, dAB);
    k_ssd_state<<<2048, 256, 0, stream>>>(XC0, dtF, dAF, XC1, dtB, dAB, SBUF, APR);
    k_scan_carry<<<1024, 256, 0, stream>>>(SBUF, APR);
    k_ssd_y<<<2048, 256, 0, stream>>>(XC0, dtF, dAF, f_D, Y0,
                                      XC1, dtB, dAB, b_D, Y1, SBUF);
    k_gnorm<<<8192, 256, 0, stream>>>(Y0, Z0, f_gw, YG0, Y1, Z1, b_gw, YG1);
    k_gemm64<0><<<dim3(8, 64, 2), 256, 0, stream>>>(YG0, YG1, OWF, OWB, OP0, OP1, 512, 1024,
                                                    nullptr, nullptr);
    k_add_rms<<<4096, 256, 0, stream>>>(x, OP0, OP1, mask, nfw, b2, X2, X2B, out);
    k_gemm64<1><<<dim3(32, 64, 1), 256, 0, stream>>>(X2B, X2B, W1B, W1B, HACT, HACT, 2048, 512,
                                                     b1, nullptr);
    k_gemm64<3><<<dim3(8, 64, 2), 256, 0, stream>>>(HACT, HACT, W2B, W2B, nullptr, nullptr,
                                                    512, 2048, nullptr, out);
}

// Round 13
// 331.519 us; speedup vs baseline: 5.5874x; 1.0387x over previous
//
#include <hip/hip_runtime.h>
#include <hip/hip_bf16.h>

typedef unsigned short u16;
typedef unsigned int u32;
typedef __bf16 bf16x8 __attribute__((ext_vector_type(8)));
typedef float f32x4 __attribute__((ext_vector_type(4)));

typedef __attribute__((address_space(1))) void gvoid_t;
typedef __attribute__((address_space(3))) void lvoid_t;
__device__ __forceinline__ void lds_cp16(void* lds, const void* g) {
    __builtin_amdgcn_global_load_lds((gvoid_t*)g, (lvoid_t*)lds, 16, 0, 0);
}

__device__ __forceinline__ float bf2f(u16 v) {
    u32 x = (u32)v << 16;
    return __builtin_bit_cast(float, x);
}
__device__ __forceinline__ u16 f2bf(float f) {
    return __builtin_bit_cast(u16, (__bf16)f);
}

// ---------------- block reduction (256 threads = 4 waves) ----------------
__device__ __forceinline__ float block_sum_256(float v, float* red) {
    #pragma unroll
    for (int o = 32; o > 0; o >>= 1) v += __shfl_xor(v, o);
    int w = threadIdx.x >> 6;
    if ((threadIdx.x & 63) == 0) red[w] = v;
    __syncthreads();
    return red[0] + red[1] + red[2] + red[3];
}

// ---------------- fused: weight conversions + rms_pos (one launch) ----------------
__global__ __launch_bounds__(256) void k_prep(
    const float* __restrict__ f_inw, const float* __restrict__ b_inw,
    const float* __restrict__ f_ow, const float* __restrict__ b_ow,
    const float* __restrict__ w1, const float* __restrict__ w2,
    u16* __restrict__ INWF, u16* __restrict__ INWB,
    u16* __restrict__ OWF, u16* __restrict__ OWB,
    u16* __restrict__ W1B, u16* __restrict__ W2B,
    const float* __restrict__ x, const float* __restrict__ pe,
    const float* __restrict__ wrms, u16* __restrict__ sib) {
    if (blockIdx.x < 21504) {
        int i = blockIdx.x * 256 + threadIdx.x;
        if (i < 1179648) { int n = i >> 9; INWF[i] = (n < 2192) ? f2bf(f_inw[i]) : (u16)0; return; }
        i -= 1179648;
        if (i < 1179648) { int n = i >> 9; INWB[i] = (n < 2192) ? f2bf(b_inw[i]) : (u16)0; return; }
        i -= 1179648;
        if (i < 524288) { OWF[i] = f2bf(f_ow[i]); return; }
        i -= 524288;
        if (i < 524288) { OWB[i] = f2bf(b_ow[i]); return; }
        i -= 524288;
        if (i < 1048576) { W1B[i] = f2bf(w1[i]); return; }
        i -= 1048576;
        if (i < 1048576) W2B[i] = f2bf(w2[i]);
        return;
    }
    __shared__ float red[4];
    int row = blockIdx.x - 21504, t = threadIdx.x;
    size_t base = (size_t)row * 512 + t * 2;
    float2 xv = *(const float2*)(x + base);
    float ss = block_sum_256(xv.x * xv.x + xv.y * xv.y, red);
    float sc = rsqrtf(ss * (1.f / 512.f) + 1.1920929e-07f);
    float2 pv = *(const float2*)(pe + base);
    float2 wv = *(const float2*)(wrms + t * 2);
    sib[base] = f2bf(xv.x * sc * wv.x + pv.x);
    sib[base + 1] = f2bf(xv.y * sc * wv.y + pv.y);
}

// ---------------- in_proj GEMM, BK=32 (async LDS staging; reverted from BK=64) ----------------
__global__ __launch_bounds__(256) void k_gemm_in(
    const u16* __restrict__ A, const u16* __restrict__ W0, const u16* __restrict__ W1,
    u16* __restrict__ Z0, u16* __restrict__ Z1,
    u16* __restrict__ XB0, u16* __restrict__ XB1) {
    const int z = blockIdx.z;
    const u16* W = z ? W1 : W0;
    u16* Z = z ? Z1 : Z0;
    u16* XB = z ? XB1 : XB0;
    const int K = 512;

    __shared__ __align__(16) u16 As[128 * 32];
    __shared__ __align__(16) u16 Bs[128 * 32];

    const int t = threadIdx.x;
    const int lane = t & 63;
    const int w = t >> 6;
    const int m0 = blockIdx.y * 128;
    const int n0 = blockIdx.x * 128;
    const int wm = (w >> 1) * 64;
    const int wn = (w & 1) * 64;
    const int fr = lane & 15;
    const int fk = (lane >> 4) * 8;

    f32x4 acc[4][4];
    #pragma unroll
    for (int i = 0; i < 4; ++i)
        #pragma unroll
        for (int j = 0; j < 4; ++j) acc[i][j] = (f32x4){0.f, 0.f, 0.f, 0.f};

    for (int kt = 0; kt < K; kt += 32) {
        #pragma unroll
        for (int j = 0; j < 2; ++j) {
            int off16 = j * 256 + t;
            int row = off16 >> 2;
            int kc = (off16 & 3) * 8;
            int gm = m0 + row;
            if (z) gm = (gm & ~2047) | (2047 - (gm & 2047));
            lds_cp16(As + off16 * 8, A + (size_t)gm * K + kt + kc);
            lds_cp16(Bs + off16 * 8, W + (size_t)(n0 + row) * K + kt + kc);
        }
        __syncthreads();
        bf16x8 af[4], bfr[4];
        #pragma unroll
        for (int i = 0; i < 4; ++i) af[i] = *(const bf16x8*)(As + (wm + i * 16 + fr) * 32 + fk);
        #pragma unroll
        for (int i = 0; i < 4; ++i) bfr[i] = *(const bf16x8*)(Bs + (wn + i * 16 + fr) * 32 + fk);
        #pragma unroll
        for (int i = 0; i < 4; ++i)
            #pragma unroll
            for (int j = 0; j < 4; ++j)
                acc[i][j] = __builtin_amdgcn_mfma_f32_16x16x32_bf16(af[i], bfr[j], acc[i][j], 0, 0, 0);
        __syncthreads();
    }
    #pragma unroll
    for (int i = 0; i < 4; ++i) {
        int rbase = m0 + wm + i * 16 + (lane >> 4) * 4;
        #pragma unroll
        for (int j = 0; j < 4; ++j) {
            int c = n0 + wn + j * 16 + fr;
            #pragma unroll
            for (int r = 0; r < 4; ++r) {
                u16 v = f2bf(acc[i][j][r]);
                int m = rbase + r;
                if (c < 1024) Z[(size_t)m * 1024 + c] = v;
                else if (c < 2192) XB[(size_t)m * 1184 + (c - 1024)] = v;
            }
        }
    }
}

// ---------------- 64x64-tile GEMM (high-occupancy, async staging) ----------------
// EPI 0: bf16 store (z=dir); 1: gelu(acc+bias)->bf16; 2: f32 out = acc + bias + resid.
template <int EPI>
__global__ __launch_bounds__(256) void k_gemm64(
    const u16* __restrict__ A0, const u16* __restrict__ A1,
    const u16* __restrict__ W0, const u16* __restrict__ W1,
    u16* __restrict__ C0, u16* __restrict__ C1, int N, int K,
    const float* __restrict__ bias, const float* __restrict__ resid,
    float* __restrict__ outf) {
    const int z = blockIdx.z;
    const u16* A = z ? A1 : A0;
    const u16* W = z ? W1 : W0;
    u16* C = z ? C1 : C0;

    __shared__ __align__(16) u16 As[64 * 32];
    __shared__ __align__(16) u16 Bs[64 * 32];

    const int t = threadIdx.x;
    const int lane = t & 63;
    const int w = t >> 6;
    const int m0 = blockIdx.y * 64;
    const int n0 = blockIdx.x * 64;
    const int wm = (w >> 1) * 32;
    const int wn = (w & 1) * 32;
    const int fr = lane & 15;
    const int fk = (lane >> 4) * 8;

    f32x4 acc[2][2];
    #pragma unroll
    for (int i = 0; i < 2; ++i)
        #pragma unroll
        for (int j = 0; j < 2; ++j) acc[i][j] = (f32x4){0.f, 0.f, 0.f, 0.f};

    const int srow = t >> 2;
    const int skc = (t & 3) * 8;
    for (int kt = 0; kt < K; kt += 32) {
        lds_cp16(As + t * 8, A + (size_t)(m0 + srow) * K + kt + skc);
        lds_cp16(Bs + t * 8, W + (size_t)(n0 + srow) * K + kt + skc);
        __syncthreads();
        bf16x8 af[2], bfr[2];
        #pragma unroll
        for (int i = 0; i < 2; ++i) af[i] = *(const bf16x8*)(As + (wm + i * 16 + fr) * 32 + fk);
        #pragma unroll
        for (int j = 0; j < 2; ++j) bfr[j] = *(const bf16x8*)(Bs + (wn + j * 16 + fr) * 32 + fk);
        #pragma unroll
        for (int i = 0; i < 2; ++i)
            #pragma unroll
            for (int j = 0; j < 2; ++j)
                acc[i][j] = __builtin_amdgcn_mfma_f32_16x16x32_bf16(af[i], bfr[j], acc[i][j], 0, 0, 0);
        __syncthreads();
    }
    #pragma unroll
    for (int i = 0; i < 2; ++i) {
        int rbase = m0 + wm + i * 16 + (lane >> 4) * 4;
        #pragma unroll
        for (int j = 0; j < 2; ++j) {
            int col = n0 + wn + j * 16 + fr;
            #pragma unroll
            for (int r = 0; r < 4; ++r) {
                int m = rbase + r;
                float v = acc[i][j][r];
                if (EPI == 0) {
                    C[(size_t)m * N + col] = f2bf(v);
                } else if (EPI == 1) {
                    float xg = v + bias[col];
                    C[(size_t)m * N + col] = f2bf(0.5f * xg * (1.f + erff(xg * 0.70710678118654752f)));
                } else {
                    outf[(size_t)m * N + col] = v + bias[col] + resid[(size_t)m * N + col];
                }
            }
        }
    }
}

// ---------------- causal conv4 + silu, 8 rows/block sliding window ----------------
__global__ __launch_bounds__(160) void k_conv(
    const u16* __restrict__ xb0, const u16* __restrict__ xb1,
    const float* __restrict__ cw0, const float* __restrict__ cb0,
    const float* __restrict__ dtb0, const float* __restrict__ al0,
    const float* __restrict__ cw1, const float* __restrict__ cb1,
    const float* __restrict__ dtb1, const float* __restrict__ al1,
    u16* __restrict__ xc0, u16* __restrict__ xc1,
    float* __restrict__ dtO0, float* __restrict__ dAO0,
    float* __restrict__ dtO1, float* __restrict__ dAO1) {
    int g = blockIdx.x;
    int dir = g >> 9;
    int row0 = (g & 511) * 8;
    const u16* xb = dir ? xb1 : xb0;
    const float* cw = dir ? cw1 : cw0;
    const float* cb = dir ? cb1 : cb0;
    const float* dtb = dir ? dtb1 : dtb0;
    const float* al = dir ? al1 : al0;
    u16* xc = dir ? xc1 : xc0;
    float* dtO = dir ? dtO1 : dtO0;
    float* dAO = dir ? dAO1 : dAO0;
    int tl0 = row0 & 2047;
    int rbatch = row0 - tl0;
    int t = threadIdx.x;
    if (t < 144) {
        int col = t * 8;
        float cwa[8][4];
        #pragma unroll
        for (int j = 0; j < 8; ++j) {
            float4 c4 = *(const float4*)(cw + (col + j) * 4);
            cwa[j][0] = c4.x; cwa[j][1] = c4.y; cwa[j][2] = c4.z; cwa[j][3] = c4.w;
        }
        float cbv[8];
        float4 cb0v = *(const float4*)(cb + col);
        float4 cb1v = *(const float4*)(cb + col + 4);
        cbv[0] = cb0v.x; cbv[1] = cb0v.y; cbv[2] = cb0v.z; cbv[3] = cb0v.w;
        cbv[4] = cb1v.x; cbv[5] = cb1v.y; cbv[6] = cb1v.z; cbv[7] = cb1v.w;
        uint4 win[4];
        win[0] = win[1] = win[2] = make_uint4(0, 0, 0, 0);
        #pragma unroll
        for (int i = 0; i < 3; ++i) {
            int tt = tl0 - 3 + i;
            if (tt >= 0) win[i] = *(const uint4*)(xb + (size_t)(rbatch + tt) * 1184 + col);
        }
        for (int s = 0; s < 8; ++s) {
            win[3] = *(const uint4*)(xb + (size_t)(rbatch + tl0 + s) * 1184 + col);
            const u16* w0 = (const u16*)&win[0];
            const u16* w1 = (const u16*)&win[1];
            const u16* w2 = (const u16*)&win[2];
            const u16* w3 = (const u16*)&win[3];
            u16 ov[8];
            #pragma unroll
            for (int j = 0; j < 8; ++j) {
                float a = cbv[j] + bf2f(w0[j]) * cwa[j][0] + bf2f(w1[j]) * cwa[j][1]
                        + bf2f(w2[j]) * cwa[j][2] + bf2f(w3[j]) * cwa[j][3];
                ov[j] = f2bf(a / (1.f + expf(-a)));
            }
            *(uint4*)(xc + (size_t)(row0 + s) * 1152 + col) = *(const uint4*)ov;
            win[0] = win[1]; win[1] = win[2]; win[2] = win[3];
        }
    } else if (t < 160) {
        int hh = t - 144;
        float nal = -expf(al[hh]);
        float dtbv = dtb[hh];
        for (int s = 0; s < 8; ++s) {
            int row = row0 + s;
            float v = bf2f(xb[(size_t)row * 1184 + 1152 + hh]) + dtbv;
            float sp = (v > 20.f) ? v : log1pf(expf(v));
            dtO[row * 16 + hh] = sp;
            dAO[row * 16 + hh] = nal * sp;
        }
    }
}

// ======== SSD chunked scan ========
__global__ __launch_bounds__(256) void k_ssd_state(
    const u16* __restrict__ xc0, const float* __restrict__ dt0, const float* __restrict__ ld0,
    const u16* __restrict__ xc1, const float* __restrict__ dt1, const float* __restrict__ ld1,
    float* __restrict__ S, float* __restrict__ Aprod) {
    int blk = blockIdx.x;
    int c = blk & 31, h = (blk >> 5) & 15, b = (blk >> 9) & 1, dir = blk >> 10;
    const u16* xc = dir ? xc1 : xc0;
    const float* dtp = dir ? dt1 : dt0;
    const float* ldp = dir ? ld1 : ld0;
    const int t = threadIdx.x, w = t >> 6, lane = t & 63;
    const int fr = lane & 15, fk = (lane >> 4) * 8;

    __shared__ __align__(16) u16 sBt[64 * 72];
    __shared__ __align__(16) u16 sXp[64 * 72];
    __shared__ float ssc[64];
    size_t row0 = (size_t)b * 2048 + c * 64;

    if (t < 64) {
        float v = ldp[(row0 + t) * 16 + h];
        float dtv = dtp[(row0 + t) * 16 + h];
        #pragma unroll
        for (int o = 1; o < 64; o <<= 1) {
            float u = __shfl_up(v, o);
            if (lane >= o) v += u;
        }
        float last = __shfl(v, 63);
        ssc[t] = dtv * expf(last - v);
        if (t == 63) Aprod[blk] = expf(v);
    }
    __syncthreads();
    #pragma unroll
    for (int i2 = t; i2 < 512; i2 += 256) {
        int r = i2 >> 3, e8 = (i2 & 7) * 8;
        size_t rb = (row0 + r) * 1152;
        uint4 bv = *(const uint4*)(xc + rb + 1024 + e8);
        uint4 xv = *(const uint4*)(xc + rb + h * 64 + e8);
        const u16* bs = (const u16*)&bv;
        const u16* xs = (const u16*)&xv;
        float sc = ssc[r];
        #pragma unroll
        for (int j = 0; j < 8; ++j) {
            sBt[(e8 + j) * 72 + r] = bs[j];
            sXp[(e8 + j) * 72 + r] = f2bf(bf2f(xs[j]) * sc);
        }
    }
    __syncthreads();

    f32x4 acc[4];
    #pragma unroll
    for (int j = 0; j < 4; ++j) acc[j] = (f32x4){0.f, 0.f, 0.f, 0.f};
    #pragma unroll
    for (int k0 = 0; k0 < 64; k0 += 32) {
        bf16x8 a = *(const bf16x8*)(sBt + (w * 16 + fr) * 72 + k0 + fk);
        #pragma unroll
        for (int j = 0; j < 4; ++j) {
            bf16x8 bb = *(const bf16x8*)(sXp + (j * 16 + fr) * 72 + k0 + fk);
            acc[j] = __builtin_amdgcn_mfma_f32_16x16x32_bf16(a, bb, acc[j], 0, 0, 0);
        }
    }
    float* Sb = S + (size_t)blk * 4096;
    int nb = w * 16 + (lane >> 4) * 4;
    #pragma unroll
    for (int j = 0; j < 4; ++j) {
        int p = j * 16 + fr;
        *(f32x4*)(Sb + p * 64 + nb) = acc[j];
    }
}

// ---- Pass B: fully-parallel carry. grid 1024 = 64 blk-groups x 16; 1 element/thread ----
__global__ __launch_bounds__(256) void k_scan_carry(float* __restrict__ S,
                                                    const float* __restrict__ Aprod) {
    int g = blockIdx.x;
    int blk = g >> 4;
    int e = (g & 15) * 256 + threadIdx.x;
    size_t base = (size_t)blk * 32 * 4096 + e;
    float sv[32];
    #pragma unroll
    for (int c = 0; c < 32; ++c) sv[c] = S[base + (size_t)c * 4096];
    float ap[32];
    #pragma unroll
    for (int c = 0; c < 32; ++c) ap[c] = Aprod[blk * 32 + c];
    float h = 0.f;
    #pragma unroll
    for (int c = 0; c < 32; ++c) {
        S[base + (size_t)c * 4096] = h;
        h = ap[c] * h + sv[c];
    }
}

__global__ __launch_bounds__(256) void k_ssd_y(
    const u16* __restrict__ xc0, const float* __restrict__ dt0, const float* __restrict__ ld0,
    const float* __restrict__ Dv0, u16* __restrict__ y0,
    const u16* __restrict__ xc1, const float* __restrict__ dt1, const float* __restrict__ ld1,
    const float* __restrict__ Dv1, u16* __restrict__ y1,
    const float* __restrict__ S) {
    int blk = blockIdx.x;
    int c = blk & 31, h = (blk >> 5) & 15, b = (blk >> 9) & 1, dir = blk >> 10;
    const u16* xc = dir ? xc1 : xc0;
    const float* dtp = dir ? dt1 : dt0;
    const float* ldp = dir ? ld1 : ld0;
    u16* y = dir ? y1 : y0;
    const float Dh = (dir ? Dv1 : Dv0)[h];
    const int t = threadIdx.x, w = t >> 6, lane = t & 63;
    const int fr = lane & 15, fk = (lane >> 4) * 8;

    __shared__ __align__(16) u16 sB[64 * 72];
    __shared__ __align__(16) u16 sC[64 * 72];
    __shared__ __align__(16) u16 sXp[64 * 72];
    __shared__ __align__(16) u16 sHi[64 * 72];
    __shared__ __align__(16) u16 sLo[64 * 72];
    __shared__ __align__(16) u16 sGl[64 * 72];
    __shared__ float scl[64], sdt[64];
    size_t row0 = (size_t)b * 2048 + c * 64;

    if (t < 64) {
        float v = ldp[(row0 + t) * 16 + h];
        float dtv = dtp[(row0 + t) * 16 + h];
        #pragma unroll
        for (int o = 1; o < 64; o <<= 1) {
            float u = __shfl_up(v, o);
            if (lane >= o) v += u;
        }
        scl[t] = v;
        sdt[t] = dtv;
    }
    __syncthreads();
    #pragma unroll
    for (int i2 = t; i2 < 512; i2 += 256) {
        int r = i2 >> 3, e8 = (i2 & 7) * 8;
        size_t rb = (row0 + r) * 1152;
        *(uint4*)(sB + r * 72 + e8) = *(const uint4*)(xc + rb + 1024 + e8);
        *(uint4*)(sC + r * 72 + e8) = *(const uint4*)(xc + rb + 1088 + e8);
        uint4 xv = *(const uint4*)(xc + rb + h * 64 + e8);
        const u16* xs = (const u16*)&xv;
        float dtv = sdt[r];
        #pragma unroll
        for (int j = 0; j < 8; ++j) sXp[(e8 + j) * 72 + r] = f2bf(bf2f(xs[j]) * dtv);
    }
    #pragma unroll
    for (int i4 = t; i4 < 1024; i4 += 256) {
        int p = i4 >> 4, n4 = (i4 & 15) * 4;
        float4 hv = *(const float4*)(S + (size_t)blk * 4096 + p * 64 + n4);
        ushort4 hi4, lo4;
        hi4.x = f2bf(hv.x); lo4.x = f2bf(hv.x - bf2f(hi4.x));
        hi4.y = f2bf(hv.y); lo4.y = f2bf(hv.y - bf2f(hi4.y));
        hi4.z = f2bf(hv.z); lo4.z = f2bf(hv.z - bf2f(hi4.z));
        hi4.w = f2bf(hv.w); lo4.w = f2bf(hv.w - bf2f(hi4.w));
        *(ushort4*)(sHi + p * 72 + n4) = hi4;
        *(ushort4*)(sLo + p * 72 + n4) = lo4;
    }
    __syncthreads();

    f32x4 g[4], acc2[4];
    #pragma unroll
    for (int j = 0; j < 4; ++j) { g[j] = (f32x4){0.f,0.f,0.f,0.f}; acc2[j] = (f32x4){0.f,0.f,0.f,0.f}; }
    #pragma unroll
    for (int k0 = 0; k0 < 64; k0 += 32) {
        bf16x8 a = *(const bf16x8*)(sC + (w * 16 + fr) * 72 + k0 + fk);
        #pragma unroll
        for (int j = 0; j < 4; ++j) {
            bf16x8 bb = *(const bf16x8*)(sB + (j * 16 + fr) * 72 + k0 + fk);
            g[j] = __builtin_amdgcn_mfma_f32_16x16x32_bf16(a, bb, g[j], 0, 0, 0);
            bf16x8 bh = *(const bf16x8*)(sHi + (j * 16 + fr) * 72 + k0 + fk);
            acc2[j] = __builtin_amdgcn_mfma_f32_16x16x32_bf16(a, bh, acc2[j], 0, 0, 0);
            bf16x8 bl = *(const bf16x8*)(sLo + (j * 16 + fr) * 72 + k0 + fk);
            acc2[j] = __builtin_amdgcn_mfma_f32_16x16x32_bf16(a, bl, acc2[j], 0, 0, 0);
        }
    }
    #pragma unroll
    for (int j = 0; j < 4; ++j) {
        int r = j * 16 + fr;
        #pragma unroll
        for (int reg = 0; reg < 4; ++reg) {
            int s = w * 16 + (lane >> 4) * 4 + reg;
            float val = (r <= s) ? expf(scl[s] - scl[r]) * g[j][reg] : 0.f;
            sGl[s * 72 + r] = f2bf(val);
        }
    }
    __syncthreads();

    f32x4 acc1[4];
    #pragma unroll
    for (int j = 0; j < 4; ++j) acc1[j] = (f32x4){0.f, 0.f, 0.f, 0.f};
    #pragma unroll
    for (int k0 = 0; k0 < 64; k0 += 32) {
        bf16x8 a = *(const bf16x8*)(sGl + (w * 16 + fr) * 72 + k0 + fk);
        #pragma unroll
        for (int j = 0; j < 4; ++j) {
            bf16x8 bb = *(const bf16x8*)(sXp + (j * 16 + fr) * 72 + k0 + fk);
            acc1[j] = __builtin_amdgcn_mfma_f32_16x16x32_bf16(a, bb, acc1[j], 0, 0, 0);
        }
    }
    #pragma unroll
    for (int reg = 0; reg < 4; ++reg) {
        int s = w * 16 + (lane >> 4) * 4 + reg;
        float es = expf(scl[s]);
        size_t yrb = (row0 + s) * 1024 + h * 64;
        size_t xrb = (row0 + s) * 1152 + h * 64;
        #pragma unroll
        for (int j = 0; j < 4; ++j) {
            int p = j * 16 + fr;
            float xv = bf2f(xc[xrb + p]);
            y[yrb + p] = f2bf(acc1[j][reg] + es * acc2[j][reg] + xv * Dh);
        }
    }
}

// ---------------- gated RMS norm ----------------
__global__ __launch_bounds__(256) void k_gnorm(
    const u16* __restrict__ y0, const u16* __restrict__ z0,
    const float* __restrict__ gw0, u16* __restrict__ o0,
    const u16* __restrict__ y1, const u16* __restrict__ z1,
    const float* __restrict__ gw1, u16* __restrict__ o1) {
    __shared__ float red[4];
    int r = blockIdx.x;
    int dir = r >> 12, row = r & 4095;
    int t = threadIdx.x;
    const u16* y = dir ? y1 : y0;
    const u16* zp = dir ? z1 : z0;
    const float* gw = dir ? gw1 : gw0;
    u16* o = dir ? o1 : o0;
    ushort4 yv = *(const ushort4*)(y + (size_t)row * 1024 + t * 4);
    ushort4 zr = *(const ushort4*)(zp + (size_t)row * 1024 + t * 4);
    float z0f = bf2f(zr.x), z1f = bf2f(zr.y), z2f = bf2f(zr.z), z3f = bf2f(zr.w);
    float v0 = bf2f(yv.x) * (z0f / (1.f + expf(-z0f)));
    float v1 = bf2f(yv.y) * (z1f / (1.f + expf(-z1f)));
    float v2 = bf2f(yv.z) * (z2f / (1.f + expf(-z2f)));
    float v3 = bf2f(yv.w) * (z3f / (1.f + expf(-z3f)));
    float ss = block_sum_256(v0 * v0 + v1 * v1 + v2 * v2 + v3 * v3, red);
    float sc = rsqrtf(ss * (1.f / 1024.f) + 1e-5f);
    float4 gv = *(const float4*)(gw + t * 4);
    size_t ob = (size_t)row * 1024 + t * 4;
    o[ob + 0] = f2bf(v0 * sc * gv.x);
    o[ob + 1] = f2bf(v1 * sc * gv.y);
    o[ob + 2] = f2bf(v2 * sc * gv.z);
    o[ob + 3] = f2bf(v3 * sc * gv.w);
}

// ---- fused: x2 = x + (fwd+flip(bwd))*mask; rms(x2)*nfw -> bf16 ----
__global__ __launch_bounds__(256) void k_add_rms(
    const float* __restrict__ x, const u16* __restrict__ of,
    const u16* __restrict__ ob, const float* __restrict__ mask,
    const float* __restrict__ wrms,
    float* __restrict__ x2, u16* __restrict__ o) {
    __shared__ float red[4];
    int row = blockIdx.x, t = threadIdx.x;
    int bb = row >> 11, tl = row & 2047;
    size_t fb = (size_t)((bb << 11) + (2047 - tl)) * 512;
    float m = mask[row];
    size_t base = (size_t)row * 512 + t * 2;
    size_t fo = fb + t * 2;
    float2 xv = *(const float2*)(x + base);
    float v0 = xv.x + (bf2f(of[base]) + bf2f(ob[fo])) * m;
    float v1 = xv.y + (bf2f(of[base + 1]) + bf2f(ob[fo + 1])) * m;
    x2[base] = v0;
    x2[base + 1] = v1;
    float ss = block_sum_256(v0 * v0 + v1 * v1, red);
    float sc = rsqrtf(ss * (1.f / 512.f) + 1.1920929e-07f);
    float2 wv = *(const float2*)(wrms + t * 2);
    o[base] = f2bf(v0 * sc * wv.x);
    o[base + 1] = f2bf(v1 * sc * wv.y);
}

extern "C" void kernel_launch(void* const* d_in, const int* in_sizes, int n_in,
                              void* d_out, int out_size, void* d_ws, size_t ws_size,
                              hipStream_t stream) {
    const float* x = (const float*)d_in[0];
    const float* pe = (const float*)d_in[1];
    const float* mask = (const float*)d_in[2];
    const float* nsw = (const float*)d_in[3];
    const float* nfw = (const float*)d_in[4];
    const float* w1 = (const float*)d_in[5];
    const float* b1 = (const float*)d_in[6];
    const float* w2 = (const float*)d_in[7];
    const float* b2 = (const float*)d_in[8];
    const float* f_inw = (const float*)d_in[9];
    const float* f_cw = (const float*)d_in[10];
    const float* f_cb = (const float*)d_in[11];
    const float* f_dtb = (const float*)d_in[12];
    const float* f_al = (const float*)d_in[13];
    const float* f_D = (const float*)d_in[14];
    const float* f_gw = (const float*)d_in[15];
    const float* f_ow = (const float*)d_in[16];
    const float* b_inw = (const float*)d_in[17];
    const float* b_cw = (const float*)d_in[18];
    const float* b_cb = (const float*)d_in[19];
    const float* b_dtb = (const float*)d_in[20];
    const float* b_al = (const float*)d_in[21];
    const float* b_D = (const float*)d_in[22];
    const float* b_gw = (const float*)d_in[23];
    const float* b_ow = (const float*)d_in[24];
    float* out = (float*)d_out;

    char* ws = (char*)d_ws;
    u16* Z0   = (u16*)(ws + 0);
    u16* Z1   = (u16*)(ws + 8388608);
    u16* XB0  = (u16*)(ws + 16777216);
    u16* XB1  = (u16*)(ws + 26476544);
    u16* INWF = (u16*)(ws + 36175872);
    u16* INWB = (u16*)(ws + 38535168);
    u16* SIB  = (u16*)(ws + 40894464);
    u16* XC0  = (u16*)(ws + 36175872);
    u16* XC1  = (u16*)(ws + 45613056);
    float* dtF = (float*)(ws + 55050240);
    float* dAF = (float*)(ws + 55312384);
    float* dtB = (float*)(ws + 55574528);
    float* dAB = (float*)(ws + 55836672);
    u16* Y0   = (u16*)(ws + 16777216);
    u16* Y1   = (u16*)(ws + 25165824);
    u16* YG0  = (u16*)(ws + 36175872);
    u16* YG1  = (u16*)(ws + 44564480);
    u16* OP0  = (u16*)(ws + 0);
    u16* OP1  = (u16*)(ws + 4194304);
    float* X2 = (float*)(ws + 8388608);
    u16* X2B  = (u16*)(ws + 0);
    u16* HACT = (u16*)(ws + 16777216);
    u16* OWF = (u16*)(ws + 56098816);
    u16* OWB = (u16*)(ws + 57147392);
    u16* W1B = (u16*)(ws + 58195968);
    u16* W2B = (u16*)(ws + 60293120);
    float* SBUF = (float*)(ws + 62390272);
    float* APR  = (float*)(ws + 95944704);

    k_prep<<<25600, 256, 0, stream>>>(f_inw, b_inw, f_ow, b_ow, w1, w2,
                                      INWF, INWB, OWF, OWB, W1B, W2B,
                                      x, pe, nsw, SIB);
    k_gemm_in<<<dim3(18, 32, 2), 256, 0, stream>>>(SIB, INWF, INWB, Z0, Z1, XB0, XB1);
    k_conv<<<1024, 160, 0, stream>>>(XB0, XB1, f_cw, f_cb, f_dtb, f_al,
                                     b_cw, b_cb, b_dtb, b_al,
                                     XC0, XC1, dtF, dAF, dtB, dAB);
    k_ssd_state<<<2048, 256, 0, stream>>>(XC0, dtF, dAF, XC1, dtB, dAB, SBUF, APR);
    k_scan_carry<<<1024, 256, 0, stream>>>(SBUF, APR);
    k_ssd_y<<<2048, 256, 0, stream>>>(XC0, dtF, dAF, f_D, Y0,
                                      XC1, dtB, dAB, b_D, Y1, SBUF);
    k_gnorm<<<8192, 256, 0, stream>>>(Y0, Z0, f_gw, YG0, Y1, Z1, b_gw, YG1);
    k_gemm64<0><<<dim3(8, 64, 2), 256, 0, stream>>>(YG0, YG1, OWF, OWB, OP0, OP1, 512, 1024,
                                                    nullptr, nullptr, nullptr);
    k_add_rms<<<4096, 256, 0, stream>>>(x, OP0, OP1, mask, nfw, X2, X2B);
    k_gemm64<1><<<dim3(32, 64, 1), 256, 0, stream>>>(X2B, X2B, W1B, W1B, HACT, HACT, 2048, 512,
                                                     b1, nullptr, nullptr);
    k_gemm64<2><<<dim3(8, 64, 1), 256, 0, stream>>>(HACT, HACT, W2B, W2B, nullptr, nullptr,
                                                    512, 2048, b2, X2, out);
}